// Round 1
// baseline (5517.379 us; speedup 1.0000x reference)
//
#include <hip/hip_runtime.h>
#include <math.h>

#define DM 512
#define DSTATE 64
#define HD 64
#define DI 1024
#define NH 16
#define CONVD 1152
#define DIP 2192
#define CHK 128
#define NCH 16
#define BSZ 2
#define SEQL 2048
#define BL (BSZ*SEQL)
#define NLAYER 12
#define EPSF 1e-5f

// ---------------- embed + nerf positional encoding ----------------
__global__ void embed_kernel(const float* __restrict__ x, const float* __restrict__ W,
                             float* __restrict__ h) {
    int tok = blockIdx.x;
    float xe[3];
#pragma unroll
    for (int e = 0; e < 3; e++) {
        float v = x[tok * 3 + e];
        xe[e] = (v == -100.0f) ? 0.0f : v;
    }
    for (int d = threadIdx.x; d < DM; d += blockDim.x) {
        float pe = 0.0f;
        if (d < 510) {
            int e = d / 170, r = d % 170;
            int is_sin = (r < 85);
            int k = is_sin ? r : r - 85;
            float ang = xe[e] * ldexpf(1.0f, k);   // exact in fp32
            double dv = is_sin ? sin((double)ang) : cos((double)ang);
            pe = (float)dv;
        }
        float acc = pe;
#pragma unroll
        for (int e = 0; e < 3; e++) acc += xe[e] * W[e * DM + d];
        h[(size_t)tok * DM + d] = acc;
    }
}

// ---------------- rmsnorm (width = 512) ----------------
__global__ __launch_bounds__(256) void rmsnorm512_kernel(const float* __restrict__ in,
                                                         const float* __restrict__ w,
                                                         float* __restrict__ out) {
    int tok = blockIdx.x;
    const float* row = in + (size_t)tok * DM;
    float v0 = row[threadIdx.x];
    float v1 = row[threadIdx.x + 256];
    float ss = v0 * v0 + v1 * v1;
    for (int o = 32; o; o >>= 1) ss += __shfl_down(ss, o);
    __shared__ float sbuf[4];
    if ((threadIdx.x & 63) == 0) sbuf[threadIdx.x >> 6] = ss;
    __syncthreads();
    if (threadIdx.x == 0) {
        float s = sbuf[0] + sbuf[1] + sbuf[2] + sbuf[3];
        sbuf[0] = rsqrtf(s / (float)DM + EPSF);
    }
    __syncthreads();
    float rs = sbuf[0];
    float* orow = out + (size_t)tok * DM;
    orow[threadIdx.x] = v0 * rs * w[threadIdx.x];
    orow[threadIdx.x + 256] = v1 * rs * w[threadIdx.x + 256];
}

// ---------------- gate (silu(z)) + rmsnorm (width = 1024), in-place on y --------
__global__ __launch_bounds__(256) void gatenorm_kernel(float* __restrict__ y,
                                                       const float* __restrict__ zx,
                                                       const float* __restrict__ gw) {
    int tok = blockIdx.x;
    const float* zrow = zx + (size_t)tok * DIP;
    float* yrow = y + (size_t)tok * DI;
    float v[4];
    float ss = 0.0f;
#pragma unroll
    for (int k = 0; k < 4; k++) {
        int d = threadIdx.x + k * 256;
        float z = zrow[d];
        float s = z / (1.0f + __expf(-z));
        float val = yrow[d] * s;
        v[k] = val;
        ss += val * val;
    }
    for (int o = 32; o; o >>= 1) ss += __shfl_down(ss, o);
    __shared__ float sbuf[4];
    if ((threadIdx.x & 63) == 0) sbuf[threadIdx.x >> 6] = ss;
    __syncthreads();
    if (threadIdx.x == 0) {
        float s = sbuf[0] + sbuf[1] + sbuf[2] + sbuf[3];
        sbuf[0] = rsqrtf(s / (float)DI + EPSF);
    }
    __syncthreads();
    float rs = sbuf[0];
#pragma unroll
    for (int k = 0; k < 4; k++) {
        int d = threadIdx.x + k * 256;
        yrow[d] = v[k] * rs * gw[d];
    }
}

// ---------------- generic fp32 GEMM: C[M,N] (+)= A[M,K] * B[K,N] ----------------
// BM=128, BN=64, BK=16, 256 threads, 8x4 micro-tile.
template <bool ACC>
__global__ __launch_bounds__(256) void gemm_kernel(const float* __restrict__ A,
                                                   const float* __restrict__ B,
                                                   float* __restrict__ C,
                                                   int M, int N, int K) {
    __shared__ float As[16][129];
    __shared__ float Bs[16][64];
    int bm = blockIdx.y * 128, bn = blockIdx.x * 64;
    int tid = threadIdx.x;
    int tx = tid & 15, ty = tid >> 4;
    float acc[8][4] = {};
    for (int k0 = 0; k0 < K; k0 += 16) {
#pragma unroll
        for (int t = 0; t < 8; t++) {
            int idx = tid + t * 256;
            int m = idx >> 4, kk = idx & 15;
            As[kk][m] = A[(size_t)(bm + m) * K + k0 + kk];
        }
#pragma unroll
        for (int t = 0; t < 4; t++) {
            int idx = tid + t * 256;
            int kk = idx >> 6, n = idx & 63;
            int gn = bn + n;
            Bs[kk][n] = (gn < N) ? B[(size_t)(k0 + kk) * N + gn] : 0.0f;
        }
        __syncthreads();
#pragma unroll
        for (int kk = 0; kk < 16; kk++) {
            float a[8], b[4];
#pragma unroll
            for (int i = 0; i < 8; i++) a[i] = As[kk][ty * 8 + i];
#pragma unroll
            for (int j = 0; j < 4; j++) b[j] = Bs[kk][tx * 4 + j];
#pragma unroll
            for (int i = 0; i < 8; i++)
#pragma unroll
                for (int j = 0; j < 4; j++) acc[i][j] += a[i] * b[j];
        }
        __syncthreads();
    }
#pragma unroll
    for (int i = 0; i < 8; i++) {
        int m = bm + ty * 8 + i;
#pragma unroll
        for (int j = 0; j < 4; j++) {
            int n = bn + tx * 4 + j;
            if (n < N) {
                size_t off = (size_t)m * N + n;
                C[off] = ACC ? C[off] + acc[i][j] : acc[i][j];
            }
        }
    }
}

// ---------------- causal depthwise conv (d=4) + bias + silu ----------------
__global__ void conv_kernel(const float* __restrict__ zx, const float* __restrict__ cw,
                            const float* __restrict__ cb, float* __restrict__ xc) {
    int gid = blockIdx.x * 256 + threadIdx.x;
    if (gid >= BL * CONVD) return;
    int c = gid % CONVD;
    int lg = gid / CONVD;       // b*SEQL + l
    int l = lg % SEQL;
    float acc = cb[c];
#pragma unroll
    for (int k = 0; k < 4; k++) {
        int ll = l + k - 3;
        if (ll >= 0) acc += zx[(size_t)(lg + k - 3) * DIP + DI + c] * cw[c * 4 + k];
    }
    xc[(size_t)gid] = acc / (1.0f + __expf(-acc));
}

// ---------------- dt softplus + within-chunk cumsum + dstate/dec ----------------
// one block per (b*NCH+c, h); 128 threads
__global__ void dtscan_kernel(const float* __restrict__ zx, const float* __restrict__ dt_bias,
                              const float* __restrict__ A_log, float* __restrict__ dtbuf,
                              float* __restrict__ acum, float* __restrict__ dsbuf,
                              float* __restrict__ decbuf) {
    int bch = blockIdx.x;           // (b*NCH + c) * NH + h
    int bc = bch >> 4, hh = bch & 15;
    int j = threadIdx.x;
    int row = bc * CHK + j;         // == b*SEQL + c*CHK + j
    float raw = zx[(size_t)row * DIP + DI + CONVD + hh] + dt_bias[hh];
    float dt = raw > 0.0f ? raw + log1pf(__expf(-raw)) : log1pf(__expf(raw));
    float A = -__expf(A_log[hh]);
    float a = dt * A;
    int lane = j & 63;
    float v = a;
#pragma unroll
    for (int o = 1; o < 64; o <<= 1) {
        float u = __shfl_up(v, o);
        if (lane >= o) v += u;
    }
    __shared__ float wsum, stot;
    if (j == 63) wsum = v;
    __syncthreads();
    float ac = (j >= 64) ? v + wsum : v;
    if (j == 127) stot = ac;
    __syncthreads();
    float asum = stot;
    size_t base = (size_t)bch * CHK;
    dtbuf[base + j] = dt;
    acum[base + j] = ac;
    dsbuf[base + j] = __expf(asum - ac) * dt;
    if (j == 0) decbuf[bch] = __expf(asum);
}

// ---------------- scores[i,j] = sum_n Cm[i,n]*Bm[j,n], per (b,c) ----------------
// grid (2, B*NCH): blockIdx.x selects 64-row half
__global__ __launch_bounds__(256) void scores_kernel(const float* __restrict__ xc,
                                                     float* __restrict__ scores) {
    __shared__ float Cs[64][65];
    __shared__ float Bs[128][65];
    int bc = blockIdx.y;
    int i0 = blockIdx.x * 64;
    int tid = threadIdx.x;
#pragma unroll
    for (int t = 0; t < 16; t++) {
        int idx = tid + t * 256;
        int i = idx >> 6, n = idx & 63;
        Cs[i][n] = xc[(size_t)(bc * CHK + i0 + i) * CONVD + DI + DSTATE + n];
    }
#pragma unroll
    for (int t = 0; t < 32; t++) {
        int idx = tid + t * 256;
        int jj = idx >> 6, n = idx & 63;
        Bs[jj][n] = xc[(size_t)(bc * CHK + jj) * CONVD + DI + n];
    }
    __syncthreads();
    int tx = tid & 15, ty = tid >> 4;
    float acc[4][8] = {};
    for (int n = 0; n < 64; n++) {
        float a[4], b[8];
#pragma unroll
        for (int ii = 0; ii < 4; ii++) a[ii] = Cs[ty * 4 + ii][n];
#pragma unroll
        for (int jj = 0; jj < 8; jj++) b[jj] = Bs[tx * 8 + jj][n];
#pragma unroll
        for (int ii = 0; ii < 4; ii++)
#pragma unroll
            for (int jj = 0; jj < 8; jj++) acc[ii][jj] += a[ii] * b[jj];
    }
    float* out = scores + (size_t)bc * CHK * CHK;
#pragma unroll
    for (int ii = 0; ii < 4; ii++) {
        int i = i0 + ty * 4 + ii;
#pragma unroll
        for (int jj = 0; jj < 8; jj++) out[(size_t)i * CHK + tx * 8 + jj] = acc[ii][jj];
    }
}

// ---------------- y_diag: y[i,p] = sum_{j<=i} scores[i,j]*exp(ac_i-ac_j)*dt_j*xh[j,p] ---
// grid (NH, B*NCH)
__global__ __launch_bounds__(256) void ydiag_kernel(const float* __restrict__ xc,
                                                    const float* __restrict__ scores,
                                                    const float* __restrict__ acum,
                                                    const float* __restrict__ dtbuf,
                                                    float* __restrict__ y) {
    __shared__ float xs[128][68];
    __shared__ float sAc[128];
    __shared__ float sDt[128];
    int hh = blockIdx.x, bc = blockIdx.y, tid = threadIdx.x;
    int bch = bc * NH + hh;
#pragma unroll
    for (int t = 0; t < 32; t++) {
        int idx = tid + t * 256;
        int j = idx >> 6, p = idx & 63;
        xs[j][p] = xc[(size_t)(bc * CHK + j) * CONVD + hh * HD + p];
    }
    if (tid < 128) {
        sAc[tid] = acum[(size_t)bch * CHK + tid];
        sDt[tid] = dtbuf[(size_t)bch * CHK + tid];
    }
    __syncthreads();
    int i = tid >> 1, ph = (tid & 1) * 32;
    const float* srow = scores + (size_t)bc * CHK * CHK + (size_t)i * CHK;
    float4 acc[8] = {};
    float aci = sAc[i];
    for (int j = 0; j <= i; j++) {
        float m = srow[j] * __expf(aci - sAc[j]) * sDt[j];
#pragma unroll
        for (int q = 0; q < 8; q++) {
            const float4 xv = *(const float4*)&xs[j][ph + q * 4];
            acc[q].x += m * xv.x; acc[q].y += m * xv.y;
            acc[q].z += m * xv.z; acc[q].w += m * xv.w;
        }
    }
    float* yrow = y + (size_t)(bc * CHK + i) * DI + hh * HD + ph;
#pragma unroll
    for (int q = 0; q < 8; q++) *(float4*)&yrow[q * 4] = acc[q];
}

// ---------------- chunk states S[p,n] = sum_j dstate[j]*xh[j,p]*Bm[j,n] ----------------
// grid (NH, B*NCH)
__global__ __launch_bounds__(256) void state_kernel(const float* __restrict__ xc,
                                                    const float* __restrict__ dsbuf,
                                                    float* __restrict__ S) {
    __shared__ float xs[128][64];
    __shared__ float Bs[128][64];
    int hh = blockIdx.x, bc = blockIdx.y, tid = threadIdx.x;
    int bch = bc * NH + hh;
#pragma unroll
    for (int t = 0; t < 32; t++) {
        int idx = tid + t * 256;
        int j = idx >> 6, p = idx & 63;
        xs[j][p] = xc[(size_t)(bc * CHK + j) * CONVD + hh * HD + p];
        Bs[j][p] = xc[(size_t)(bc * CHK + j) * CONVD + DI + p];
    }
    __syncthreads();
    int p = tid >> 2, nq = (tid & 3) * 16;
    const float* ds = dsbuf + (size_t)bch * CHK;
    float4 acc[4] = {};
    for (int j = 0; j < 128; j++) {
        float t = ds[j] * xs[j][p];
#pragma unroll
        for (int q = 0; q < 4; q++) {
            const float4 bv = *(const float4*)&Bs[j][nq + q * 4];
            acc[q].x += t * bv.x; acc[q].y += t * bv.y;
            acc[q].z += t * bv.z; acc[q].w += t * bv.w;
        }
    }
    float* out = S + (size_t)bch * (HD * DSTATE) + p * DSTATE + nq;
#pragma unroll
    for (int q = 0; q < 4; q++) *(float4*)&out[q * 4] = acc[q];
}

// ---------------- sequential scan over chunks ----------------
__global__ void scan_kernel(const float* __restrict__ S, const float* __restrict__ decbuf,
                            float* __restrict__ hs) {
    int g = blockIdx.x * 256 + threadIdx.x;  // 2*16*64*64 = 131072
    int n = g & 63, p = (g >> 6) & 63, hh = (g >> 12) & 15, b = g >> 16;
    float state = 0.0f;
#pragma unroll
    for (int c = 0; c < NCH; c++) {
        int bch = (b * NCH + c) * NH + hh;
        size_t idx = (size_t)bch * 4096 + p * 64 + n;
        hs[idx] = state;
        state = state * decbuf[bch] + S[idx];
    }
}

// ---------------- y_off: y[i,p] += exp(ac_i)*sum_n Cm[i,n]*hs[p,n]  (+ D*xh) ------
// grid (NH, B*NCH)
__global__ __launch_bounds__(256) void yoff_kernel(const float* __restrict__ xc,
                                                   const float* __restrict__ hs,
                                                   const float* __restrict__ acum,
                                                   const float* __restrict__ Dp,
                                                   float* __restrict__ y) {
    __shared__ float Cs[128][65];
    __shared__ float Ht[64][68];   // Ht[n][p]
    __shared__ float sAc[128];
    int hh = blockIdx.x, bc = blockIdx.y, tid = threadIdx.x;
    int bch = bc * NH + hh;
#pragma unroll
    for (int t = 0; t < 32; t++) {
        int idx = tid + t * 256;
        int i2 = idx >> 6, n = idx & 63;
        Cs[i2][n] = xc[(size_t)(bc * CHK + i2) * CONVD + DI + DSTATE + n];
    }
#pragma unroll
    for (int t = 0; t < 16; t++) {
        int idx = tid + t * 256;
        int p = idx >> 6, n = idx & 63;
        Ht[n][p] = hs[(size_t)bch * 4096 + p * 64 + n];
    }
    if (tid < 128) sAc[tid] = acum[(size_t)bch * CHK + tid];
    __syncthreads();
    int i = tid >> 1, ph = (tid & 1) * 32;
    float4 acc[8] = {};
    for (int n = 0; n < 64; n++) {
        float cv = Cs[i][n];
#pragma unroll
        for (int q = 0; q < 8; q++) {
            const float4 hv = *(const float4*)&Ht[n][ph + q * 4];
            acc[q].x += cv * hv.x; acc[q].y += cv * hv.y;
            acc[q].z += cv * hv.z; acc[q].w += cv * hv.w;
        }
    }
    float e = __expf(sAc[i]);
    float Dh = Dp[hh];
    size_t xoff = (size_t)(bc * CHK + i) * CONVD + hh * HD + ph;
    float* yrow = y + (size_t)(bc * CHK + i) * DI + hh * HD + ph;
#pragma unroll
    for (int q = 0; q < 8; q++) {
        float4 yv = *(float4*)&yrow[q * 4];
        const float4 xv = *(const float4*)&xc[xoff + q * 4];
        yv.x += e * acc[q].x + Dh * xv.x;
        yv.y += e * acc[q].y + Dh * xv.y;
        yv.z += e * acc[q].z + Dh * xv.z;
        yv.w += e * acc[q].w + Dh * xv.w;
        *(float4*)&yrow[q * 4] = yv;
    }
}

// ---------------- head: out[tok, j] = xn[tok,:] @ head_w[:, j] + head_b[j] --------
__global__ void head_kernel(const float* __restrict__ xn, const float* __restrict__ hw,
                            const float* __restrict__ hb, float* __restrict__ out) {
    int tok = blockIdx.x, tid = threadIdx.x;
    int jj = tid >> 3, part = tid & 7;
    float s = 0.0f;
    if (jj < 30) {
        const float* row = xn + (size_t)tok * DM;
        for (int k = part * 64; k < part * 64 + 64; k++) s += row[k] * hw[(size_t)k * 30 + jj];
    }
    s += __shfl_xor(s, 1);
    s += __shfl_xor(s, 2);
    s += __shfl_xor(s, 4);
    if (part == 0 && jj < 30) out[(size_t)tok * 30 + jj] = s + hb[jj];
}

extern "C" void kernel_launch(void* const* d_in, const int* in_sizes, int n_in,
                              void* d_out, int out_size, void* d_ws, size_t ws_size,
                              hipStream_t stream) {
    const float* x        = (const float*)d_in[0];
    const float* W_embed  = (const float*)d_in[1];
    const float* rms_w    = (const float*)d_in[2];
    const float* in_w     = (const float*)d_in[3];
    const float* conv_w   = (const float*)d_in[4];
    const float* conv_b   = (const float*)d_in[5];
    const float* dt_bias  = (const float*)d_in[6];
    const float* A_log    = (const float*)d_in[7];
    const float* D_param  = (const float*)d_in[8];
    const float* gnorm_w  = (const float*)d_in[9];
    const float* out_w    = (const float*)d_in[10];
    const float* fnorm_w  = (const float*)d_in[11];
    const float* head_w   = (const float*)d_in[12];
    const float* head_b   = (const float*)d_in[13];
    float* out = (float*)d_out;

    float* ws = (float*)d_ws;
    // workspace layout (floats)
    size_t off = 0;
    float* h_buf  = ws + off; off += (size_t)BL * DM;        // 2,097,152
    float* xn_buf = ws + off; off += (size_t)BL * DM;        // 2,097,152
    float* zx_buf = ws + off; off += (size_t)BL * DIP;       // 8,978,432
    float* xc_buf = ws + off; off += (size_t)BL * CONVD;     // 4,718,592
    float* y_buf  = ws + off; off += (size_t)BL * DI;        // 4,194,304
    float* sc_buf = ws + off; off += (size_t)BSZ * NCH * CHK * CHK;   // 524,288
    float* S_buf  = ws + off; off += (size_t)BSZ * NCH * NH * HD * DSTATE; // 2,097,152
    float* hs_buf = ws + off; off += (size_t)BSZ * NCH * NH * HD * DSTATE; // 2,097,152
    float* dt_buf = ws + off; off += (size_t)BSZ * NCH * NH * CHK;    // 65,536
    float* ac_buf = ws + off; off += (size_t)BSZ * NCH * NH * CHK;    // 65,536
    float* ds_buf = ws + off; off += (size_t)BSZ * NCH * NH * CHK;    // 65,536
    float* dec_buf = ws + off; off += (size_t)BSZ * NCH * NH;         // 512

    embed_kernel<<<BL, 256, 0, stream>>>(x, W_embed, h_buf);

    for (int l = 0; l < NLAYER; l++) {
        const float* rw = rms_w + (size_t)l * DM;
        const float* iw = in_w + (size_t)l * DM * DIP;
        const float* cw = conv_w + (size_t)l * CONVD * 4;
        const float* cb = conv_b + (size_t)l * CONVD;
        const float* db = dt_bias + (size_t)l * NH;
        const float* al = A_log + (size_t)l * NH;
        const float* dp = D_param + (size_t)l * NH;
        const float* gw = gnorm_w + (size_t)l * DI;
        const float* ow = out_w + (size_t)l * DI * DM;

        rmsnorm512_kernel<<<BL, 256, 0, stream>>>(h_buf, rw, xn_buf);
        gemm_kernel<false><<<dim3((DIP + 63) / 64, BL / 128), 256, 0, stream>>>(
            xn_buf, iw, zx_buf, BL, DIP, DM);
        conv_kernel<<<(BL * CONVD) / 256, 256, 0, stream>>>(zx_buf, cw, cb, xc_buf);
        dtscan_kernel<<<BSZ * NCH * NH, 128, 0, stream>>>(zx_buf, db, al, dt_buf, ac_buf,
                                                          ds_buf, dec_buf);
        scores_kernel<<<dim3(2, BSZ * NCH), 256, 0, stream>>>(xc_buf, sc_buf);
        ydiag_kernel<<<dim3(NH, BSZ * NCH), 256, 0, stream>>>(xc_buf, sc_buf, ac_buf,
                                                              dt_buf, y_buf);
        state_kernel<<<dim3(NH, BSZ * NCH), 256, 0, stream>>>(xc_buf, ds_buf, S_buf);
        scan_kernel<<<(BSZ * NH * HD * DSTATE) / 256, 256, 0, stream>>>(S_buf, dec_buf,
                                                                        hs_buf);
        yoff_kernel<<<dim3(NH, BSZ * NCH), 256, 0, stream>>>(xc_buf, hs_buf, ac_buf, dp,
                                                             y_buf);
        gatenorm_kernel<<<BL, 256, 0, stream>>>(y_buf, zx_buf, gw);
        gemm_kernel<true><<<dim3(DM / 64, BL / 128), 256, 0, stream>>>(
            y_buf, ow, h_buf, BL, DM, DI);
    }

    rmsnorm512_kernel<<<BL, 256, 0, stream>>>(h_buf, fnorm_w, xn_buf);
    head_kernel<<<BL, 256, 0, stream>>>(xn_buf, head_w, head_b, out);
}

// Round 2
// 2316.070 us; speedup vs baseline: 2.3822x; 2.3822x over previous
//
#include <hip/hip_runtime.h>
#include <math.h>

#define DM 512
#define DSTATE 64
#define HD 64
#define DI 1024
#define NH 16
#define CONVD 1152
#define DIP 2192
#define CHK 128
#define NCH 16
#define BSZ 2
#define SEQL 2048
#define BL (BSZ*SEQL)
#define NLAYER 12
#define EPSF 1e-5f
#define NPAD_IN 2304

typedef __attribute__((ext_vector_type(4))) float f32x4;
typedef __attribute__((ext_vector_type(8))) short s16x8;

__device__ __forceinline__ float bf2f(ushort u) {
    union { unsigned int i; float f; } v; v.i = ((unsigned int)u) << 16; return v.f;
}
__device__ __forceinline__ ushort f2bf(float f) {
    union { float f; unsigned int u; } v; v.f = f;
    unsigned int u = v.u;
    unsigned int r = (u + 0x7fffu + ((u >> 16) & 1u)) >> 16;
    return (ushort)r;
}

#define GLOAD_LDS16(gptr, lptr) __builtin_amdgcn_global_load_lds( \
    (const __attribute__((address_space(1))) void*)(gptr), \
    (__attribute__((address_space(3))) void*)(lptr), 16, 0, 0)

// ---------------- embed + nerf positional encoding ----------------
__global__ void embed_kernel(const float* __restrict__ x, const float* __restrict__ W,
                             float* __restrict__ h) {
    int tok = blockIdx.x;
    float xe[3];
#pragma unroll
    for (int e = 0; e < 3; e++) {
        float v = x[tok * 3 + e];
        xe[e] = (v == -100.0f) ? 0.0f : v;
    }
    for (int d = threadIdx.x; d < DM; d += blockDim.x) {
        float pe = 0.0f;
        if (d < 510) {
            int e = d / 170, r = d % 170;
            int is_sin = (r < 85);
            int k = is_sin ? r : r - 85;
            float ang = xe[e] * ldexpf(1.0f, k);   // exact in fp32
            double dv = is_sin ? sin((double)ang) : cos((double)ang);
            pe = (float)dv;
        }
        float acc = pe;
#pragma unroll
        for (int e = 0; e < 3; e++) acc += xe[e] * W[e * DM + d];
        h[(size_t)tok * DM + d] = acc;
    }
}

// ---------------- rmsnorm width=512 -> bf16 out (layer input path) --------
__global__ __launch_bounds__(256) void rmsnorm512_bf_kernel(const float* __restrict__ in,
                                                            const float* __restrict__ w,
                                                            ushort* __restrict__ out) {
    int tok = blockIdx.x;
    const float* row = in + (size_t)tok * DM;
    float v0 = row[threadIdx.x];
    float v1 = row[threadIdx.x + 256];
    float ss = v0 * v0 + v1 * v1;
    for (int o = 32; o; o >>= 1) ss += __shfl_down(ss, o);
    __shared__ float sbuf[4];
    if ((threadIdx.x & 63) == 0) sbuf[threadIdx.x >> 6] = ss;
    __syncthreads();
    if (threadIdx.x == 0) {
        float s = sbuf[0] + sbuf[1] + sbuf[2] + sbuf[3];
        sbuf[0] = rsqrtf(s / (float)DM + EPSF);
    }
    __syncthreads();
    float rs = sbuf[0];
    ushort* orow = out + (size_t)tok * DM;
    orow[threadIdx.x] = f2bf(v0 * rs * w[threadIdx.x]);
    orow[threadIdx.x + 256] = f2bf(v1 * rs * w[threadIdx.x + 256]);
}

// ---------------- rmsnorm width=512 -> fp32 out (final) --------
__global__ __launch_bounds__(256) void rmsnorm512_f_kernel(const float* __restrict__ in,
                                                           const float* __restrict__ w,
                                                           float* __restrict__ out) {
    int tok = blockIdx.x;
    const float* row = in + (size_t)tok * DM;
    float v0 = row[threadIdx.x];
    float v1 = row[threadIdx.x + 256];
    float ss = v0 * v0 + v1 * v1;
    for (int o = 32; o; o >>= 1) ss += __shfl_down(ss, o);
    __shared__ float sbuf[4];
    if ((threadIdx.x & 63) == 0) sbuf[threadIdx.x >> 6] = ss;
    __syncthreads();
    if (threadIdx.x == 0) {
        float s = sbuf[0] + sbuf[1] + sbuf[2] + sbuf[3];
        sbuf[0] = rsqrtf(s / (float)DM + EPSF);
    }
    __syncthreads();
    float rs = sbuf[0];
    float* orow = out + (size_t)tok * DM;
    orow[threadIdx.x] = v0 * rs * w[threadIdx.x];
    orow[threadIdx.x + 256] = v1 * rs * w[threadIdx.x + 256];
}

// ---------------- gate silu(z)*y + rmsnorm (width 1024) -> bf16 --------
__global__ __launch_bounds__(256) void gatenorm_kernel(const float* __restrict__ y,
                                                       const ushort* __restrict__ zx,
                                                       const float* __restrict__ gw,
                                                       ushort* __restrict__ yb) {
    int tok = blockIdx.x;
    const ushort* zrow = zx + (size_t)tok * DIP;
    const float* yrow = y + (size_t)tok * DI;
    float v[4];
    float ss = 0.0f;
#pragma unroll
    for (int k = 0; k < 4; k++) {
        int d = threadIdx.x + k * 256;
        float z = bf2f(zrow[d]);
        float s = z / (1.0f + __expf(-z));
        float val = yrow[d] * s;
        v[k] = val;
        ss += val * val;
    }
    for (int o = 32; o; o >>= 1) ss += __shfl_down(ss, o);
    __shared__ float sbuf[4];
    if ((threadIdx.x & 63) == 0) sbuf[threadIdx.x >> 6] = ss;
    __syncthreads();
    if (threadIdx.x == 0) {
        float s = sbuf[0] + sbuf[1] + sbuf[2] + sbuf[3];
        sbuf[0] = rsqrtf(s / (float)DI + EPSF);
    }
    __syncthreads();
    float rs = sbuf[0];
    ushort* ob = yb + (size_t)tok * DI;
#pragma unroll
    for (int k = 0; k < 4; k++) {
        int d = threadIdx.x + k * 256;
        ob[d] = f2bf(v[k] * rs * gw[d]);
    }
}

// ---------------- weight convert+transpose: w[L][K][N] f32 -> wT[L][Npad][K] bf16 ----
__global__ __launch_bounds__(256) void convT_kernel(const float* __restrict__ w,
                                                    ushort* __restrict__ wT,
                                                    int K, int N, int Npad) {
    __shared__ ushort tile[64][65];
    int l = blockIdx.z;
    int n0 = blockIdx.x * 64, k0 = blockIdx.y * 64;
    const float* src = w + (size_t)l * K * N;
    ushort* dst = wT + (size_t)l * Npad * K;
    int tid = threadIdx.x;
#pragma unroll
    for (int t = 0; t < 16; t++) {
        int idx = tid + t * 256;
        int r = idx >> 6, c = idx & 63;          // r: k-local, c: n-local
        float v = (n0 + c < N) ? src[(size_t)(k0 + r) * N + n0 + c] : 0.0f;
        tile[c][r] = f2bf(v);
    }
    __syncthreads();
#pragma unroll
    for (int t = 0; t < 16; t++) {
        int idx = tid + t * 256;
        int r = idx >> 6, c = idx & 63;          // r: n-local, c: k-local
        dst[(size_t)(n0 + r) * K + k0 + c] = tile[r][c];
    }
}

// ---------------- bf16 MFMA GEMM: C[M,N] = A[M,K] * BT[N,K]^T ----------------
// 128x128 tile, BK=64, 256 thr (4 waves 2x2), global_load_lds w/ XOR-swizzled source.
// MODE 0: bf16 store, col guard vs N, dt sidecar (cols 2176..2191 fp32)
// MODE 1: fp32 accumulate into Cf (residual add)
template <int MODE>
__global__ __launch_bounds__(256) void gemm_bf16_kernel(
    const ushort* __restrict__ A, const ushort* __restrict__ BT,
    ushort* __restrict__ Cb, float* __restrict__ Cf, float* __restrict__ dtraw,
    int N, int Nstride, int K)
{
    __shared__ ushort As[128 * 64];
    __shared__ ushort Bs[128 * 64];
    int bm = blockIdx.y * 128, bn = blockIdx.x * 128;
    int tid = threadIdx.x;
    int lane = tid & 63, wid = tid >> 6;
    int wr = wid >> 1, wc = wid & 1;
    int r15 = lane & 15, q = lane >> 4;
    f32x4 acc[4][4] = {};

    for (int k0 = 0; k0 < K; k0 += 64) {
#pragma unroll
        for (int t = 0; t < 4; t++) {
            int cbase = wid * 256 + t * 64;
            int chunk = cbase + lane;
            int row = chunk >> 3, s = chunk & 7;
            int kc = s ^ (row & 7);                 // inverse-swizzled global source
            GLOAD_LDS16(A + (size_t)(bm + row) * K + k0 + kc * 8, As + (size_t)cbase * 8);
            GLOAD_LDS16(BT + (size_t)(bn + row) * K + k0 + kc * 8, Bs + (size_t)cbase * 8);
        }
        __syncthreads();
#pragma unroll
        for (int kh = 0; kh < 2; kh++) {
            s16x8 av[4], bv[4];
#pragma unroll
            for (int m = 0; m < 4; m++) {
                int row = wr * 64 + m * 16 + r15;
                int s = (kh * 4 + q) ^ (row & 7);   // swizzled read
                av[m] = *(const s16x8*)(As + row * 64 + s * 8);
            }
#pragma unroll
            for (int n = 0; n < 4; n++) {
                int row = wc * 64 + n * 16 + r15;
                int s = (kh * 4 + q) ^ (row & 7);
                bv[n] = *(const s16x8*)(Bs + row * 64 + s * 8);
            }
#pragma unroll
            for (int m = 0; m < 4; m++)
#pragma unroll
                for (int n = 0; n < 4; n++)
                    acc[m][n] = __builtin_amdgcn_mfma_f32_16x16x32_bf16(
                        av[m], bv[n], acc[m][n], 0, 0, 0);
        }
        __syncthreads();
    }
#pragma unroll
    for (int m = 0; m < 4; m++) {
        int row0 = bm + wr * 64 + m * 16 + q * 4;
#pragma unroll
        for (int n = 0; n < 4; n++) {
            int col = bn + wc * 64 + n * 16 + r15;
#pragma unroll
            for (int r = 0; r < 4; r++) {
                float v = acc[m][n][r];
                int rr = row0 + r;
                if (MODE == 0) {
                    if (col < N) {
                        Cb[(size_t)rr * Nstride + col] = f2bf(v);
                        if (col >= DI + CONVD) dtraw[(size_t)rr * 16 + (col - DI - CONVD)] = v;
                    }
                } else {
                    Cf[(size_t)rr * Nstride + col] += v;
                }
            }
        }
    }
}

// ---------------- causal depthwise conv (d=4) + bias + silu (bf16 io) ------
__global__ void conv_kernel(const ushort* __restrict__ zx, const float* __restrict__ cw,
                            const float* __restrict__ cb, ushort* __restrict__ xc) {
    int gid = blockIdx.x * 256 + threadIdx.x;
    if (gid >= BL * CONVD) return;
    int c = gid % CONVD;
    int lg = gid / CONVD;       // b*SEQL + l
    int l = lg % SEQL;
    float acc = cb[c];
#pragma unroll
    for (int k = 0; k < 4; k++) {
        int ll = l + k - 3;
        if (ll >= 0) acc += bf2f(zx[(size_t)(lg + k - 3) * DIP + DI + c]) * cw[c * 4 + k];
    }
    xc[(size_t)gid] = f2bf(acc / (1.0f + __expf(-acc)));
}

// ---------------- dt softplus + within-chunk cumsum + dstate/dec ----------------
__global__ void dtscan_kernel(const float* __restrict__ dtraw, const float* __restrict__ dt_bias,
                              const float* __restrict__ A_log, float* __restrict__ dtbuf,
                              float* __restrict__ acum, float* __restrict__ dsbuf,
                              float* __restrict__ decbuf) {
    int bch = blockIdx.x;           // (b*NCH + c) * NH + h
    int bc = bch >> 4, hh = bch & 15;
    int j = threadIdx.x;
    int row = bc * CHK + j;
    float raw = dtraw[(size_t)row * 16 + hh] + dt_bias[hh];
    float dt = raw > 0.0f ? raw + log1pf(__expf(-raw)) : log1pf(__expf(raw));
    float A = -__expf(A_log[hh]);
    float a = dt * A;
    int lane = j & 63;
    float v = a;
#pragma unroll
    for (int o = 1; o < 64; o <<= 1) {
        float u = __shfl_up(v, o);
        if (lane >= o) v += u;
    }
    __shared__ float wsum, stot;
    if (j == 63) wsum = v;
    __syncthreads();
    float ac = (j >= 64) ? v + wsum : v;
    if (j == 127) stot = ac;
    __syncthreads();
    float asum = stot;
    size_t base = (size_t)bch * CHK;
    dtbuf[base + j] = dt;
    acum[base + j] = ac;
    dsbuf[base + j] = __expf(asum - ac) * dt;
    if (j == 0) decbuf[bch] = __expf(asum);
}

// ---------------- scores[i,j] = sum_n Cm[i,n]*Bm[j,n], per (b,c) ----------------
__global__ __launch_bounds__(256) void scores_kernel(const ushort* __restrict__ xc,
                                                     float* __restrict__ scores) {
    __shared__ float Cs[64][65];
    __shared__ float Bs[128][65];
    int bc = blockIdx.y;
    int i0 = blockIdx.x * 64;
    int tid = threadIdx.x;
#pragma unroll
    for (int t = 0; t < 16; t++) {
        int idx = tid + t * 256;
        int i = idx >> 6, n = idx & 63;
        Cs[i][n] = bf2f(xc[(size_t)(bc * CHK + i0 + i) * CONVD + DI + DSTATE + n]);
    }
#pragma unroll
    for (int t = 0; t < 32; t++) {
        int idx = tid + t * 256;
        int jj = idx >> 6, n = idx & 63;
        Bs[jj][n] = bf2f(xc[(size_t)(bc * CHK + jj) * CONVD + DI + n]);
    }
    __syncthreads();
    int tx = tid & 15, ty = tid >> 4;
    float acc[4][8] = {};
    for (int n = 0; n < 64; n++) {
        float a[4], b[8];
#pragma unroll
        for (int ii = 0; ii < 4; ii++) a[ii] = Cs[ty * 4 + ii][n];
#pragma unroll
        for (int jj = 0; jj < 8; jj++) b[jj] = Bs[tx * 8 + jj][n];
#pragma unroll
        for (int ii = 0; ii < 4; ii++)
#pragma unroll
            for (int jj = 0; jj < 8; jj++) acc[ii][jj] += a[ii] * b[jj];
    }
    float* out = scores + (size_t)bc * CHK * CHK;
#pragma unroll
    for (int ii = 0; ii < 4; ii++) {
        int i = i0 + ty * 4 + ii;
#pragma unroll
        for (int jj = 0; jj < 8; jj++) out[(size_t)i * CHK + tx * 8 + jj] = acc[ii][jj];
    }
}

// ---------------- y_diag ----------------
__global__ __launch_bounds__(256) void ydiag_kernel(const ushort* __restrict__ xc,
                                                    const float* __restrict__ scores,
                                                    const float* __restrict__ acum,
                                                    const float* __restrict__ dtbuf,
                                                    float* __restrict__ y) {
    __shared__ float xs[128][68];
    __shared__ float sAc[128];
    __shared__ float sDt[128];
    int hh = blockIdx.x, bc = blockIdx.y, tid = threadIdx.x;
    int bch = bc * NH + hh;
#pragma unroll
    for (int t = 0; t < 32; t++) {
        int idx = tid + t * 256;
        int j = idx >> 6, p = idx & 63;
        xs[j][p] = bf2f(xc[(size_t)(bc * CHK + j) * CONVD + hh * HD + p]);
    }
    if (tid < 128) {
        sAc[tid] = acum[(size_t)bch * CHK + tid];
        sDt[tid] = dtbuf[(size_t)bch * CHK + tid];
    }
    __syncthreads();
    int i = tid >> 1, ph = (tid & 1) * 32;
    const float* srow = scores + (size_t)bc * CHK * CHK + (size_t)i * CHK;
    float4 acc[8] = {};
    float aci = sAc[i];
    for (int j = 0; j <= i; j++) {
        float m = srow[j] * __expf(aci - sAc[j]) * sDt[j];
#pragma unroll
        for (int q2 = 0; q2 < 8; q2++) {
            const float4 xv = *(const float4*)&xs[j][ph + q2 * 4];
            acc[q2].x += m * xv.x; acc[q2].y += m * xv.y;
            acc[q2].z += m * xv.z; acc[q2].w += m * xv.w;
        }
    }
    float* yrow = y + (size_t)(bc * CHK + i) * DI + hh * HD + ph;
#pragma unroll
    for (int q2 = 0; q2 < 8; q2++) *(float4*)&yrow[q2 * 4] = acc[q2];
}

// ---------------- chunk states S[p,n] = sum_j dstate[j]*xh[j,p]*Bm[j,n] --------
__global__ __launch_bounds__(256) void state_kernel(const ushort* __restrict__ xc,
                                                    const float* __restrict__ dsbuf,
                                                    float* __restrict__ S) {
    __shared__ float xs[128][64];
    __shared__ float Bs[128][64];
    int hh = blockIdx.x, bc = blockIdx.y, tid = threadIdx.x;
    int bch = bc * NH + hh;
#pragma unroll
    for (int t = 0; t < 32; t++) {
        int idx = tid + t * 256;
        int j = idx >> 6, p = idx & 63;
        xs[j][p] = bf2f(xc[(size_t)(bc * CHK + j) * CONVD + hh * HD + p]);
        Bs[j][p] = bf2f(xc[(size_t)(bc * CHK + j) * CONVD + DI + p]);
    }
    __syncthreads();
    int p = tid >> 2, nq = (tid & 3) * 16;
    const float* ds = dsbuf + (size_t)bch * CHK;
    float4 acc[4] = {};
    for (int j = 0; j < 128; j++) {
        float t = ds[j] * xs[j][p];
#pragma unroll
        for (int q2 = 0; q2 < 4; q2++) {
            const float4 bv = *(const float4*)&Bs[j][nq + q2 * 4];
            acc[q2].x += t * bv.x; acc[q2].y += t * bv.y;
            acc[q2].z += t * bv.z; acc[q2].w += t * bv.w;
        }
    }
    float* out = S + (size_t)bch * (HD * DSTATE) + p * DSTATE + nq;
#pragma unroll
    for (int q2 = 0; q2 < 4; q2++) *(float4*)&out[q2 * 4] = acc[q2];
}

// ---------------- sequential scan over chunks ----------------
__global__ void scan_kernel(const float* __restrict__ S, const float* __restrict__ decbuf,
                            float* __restrict__ hs) {
    int g = blockIdx.x * 256 + threadIdx.x;
    int n = g & 63, p = (g >> 6) & 63, hh = (g >> 12) & 15, b = g >> 16;
    float state = 0.0f;
#pragma unroll
    for (int c = 0; c < NCH; c++) {
        int bch = (b * NCH + c) * NH + hh;
        size_t idx = (size_t)bch * 4096 + p * 64 + n;
        hs[idx] = state;
        state = state * decbuf[bch] + S[idx];
    }
}

// ---------------- y_off + D*xh ----------------
__global__ __launch_bounds__(256) void yoff_kernel(const ushort* __restrict__ xc,
                                                   const float* __restrict__ hs,
                                                   const float* __restrict__ acum,
                                                   const float* __restrict__ Dp,
                                                   float* __restrict__ y) {
    __shared__ float Cs[128][65];
    __shared__ float Ht[64][68];   // Ht[n][p]
    __shared__ float sAc[128];
    int hh = blockIdx.x, bc = blockIdx.y, tid = threadIdx.x;
    int bch = bc * NH + hh;
#pragma unroll
    for (int t = 0; t < 32; t++) {
        int idx = tid + t * 256;
        int i2 = idx >> 6, n = idx & 63;
        Cs[i2][n] = bf2f(xc[(size_t)(bc * CHK + i2) * CONVD + DI + DSTATE + n]);
    }
#pragma unroll
    for (int t = 0; t < 16; t++) {
        int idx = tid + t * 256;
        int p = idx >> 6, n = idx & 63;
        Ht[n][p] = hs[(size_t)bch * 4096 + p * 64 + n];
    }
    if (tid < 128) sAc[tid] = acum[(size_t)bch * CHK + tid];
    __syncthreads();
    int i = tid >> 1, ph = (tid & 1) * 32;
    float4 acc[8] = {};
    for (int n = 0; n < 64; n++) {
        float cv = Cs[i][n];
#pragma unroll
        for (int q2 = 0; q2 < 8; q2++) {
            const float4 hv = *(const float4*)&Ht[n][ph + q2 * 4];
            acc[q2].x += cv * hv.x; acc[q2].y += cv * hv.y;
            acc[q2].z += cv * hv.z; acc[q2].w += cv * hv.w;
        }
    }
    float e = __expf(sAc[i]);
    float Dh = Dp[hh];
    size_t xoff = (size_t)(bc * CHK + i) * CONVD + hh * HD + ph;
    float* yrow = y + (size_t)(bc * CHK + i) * DI + hh * HD + ph;
#pragma unroll
    for (int q2 = 0; q2 < 8; q2++) {
        float4 yv = *(float4*)&yrow[q2 * 4];
        yv.x += e * acc[q2].x + Dh * bf2f(xc[xoff + q2 * 4 + 0]);
        yv.y += e * acc[q2].y + Dh * bf2f(xc[xoff + q2 * 4 + 1]);
        yv.z += e * acc[q2].z + Dh * bf2f(xc[xoff + q2 * 4 + 2]);
        yv.w += e * acc[q2].w + Dh * bf2f(xc[xoff + q2 * 4 + 3]);
        *(float4*)&yrow[q2 * 4] = yv;
    }
}

// ---------------- head ----------------
__global__ void head_kernel(const float* __restrict__ xn, const float* __restrict__ hw,
                            const float* __restrict__ hb, float* __restrict__ out) {
    int tok = blockIdx.x, tid = threadIdx.x;
    int jj = tid >> 3, part = tid & 7;
    float s = 0.0f;
    if (jj < 30) {
        const float* row = xn + (size_t)tok * DM;
        for (int k = part * 64; k < part * 64 + 64; k++) s += row[k] * hw[(size_t)k * 30 + jj];
    }
    s += __shfl_xor(s, 1);
    s += __shfl_xor(s, 2);
    s += __shfl_xor(s, 4);
    if (part == 0 && jj < 30) out[(size_t)tok * 30 + jj] = s + hb[jj];
}

extern "C" void kernel_launch(void* const* d_in, const int* in_sizes, int n_in,
                              void* d_out, int out_size, void* d_ws, size_t ws_size,
                              hipStream_t stream) {
    const float* x        = (const float*)d_in[0];
    const float* W_embed  = (const float*)d_in[1];
    const float* rms_w    = (const float*)d_in[2];
    const float* in_w     = (const float*)d_in[3];
    const float* conv_w   = (const float*)d_in[4];
    const float* conv_b   = (const float*)d_in[5];
    const float* dt_bias  = (const float*)d_in[6];
    const float* A_log    = (const float*)d_in[7];
    const float* D_param  = (const float*)d_in[8];
    const float* gnorm_w  = (const float*)d_in[9];
    const float* out_w    = (const float*)d_in[10];
    const float* fnorm_w  = (const float*)d_in[11];
    const float* head_w   = (const float*)d_in[12];
    const float* head_b   = (const float*)d_in[13];
    float* out = (float*)d_out;

    char* p = (char*)d_ws;
    auto alloc = [&](size_t bytes) { char* r = p; p += (bytes + 255) & ~(size_t)255; return r; };

    float*  h_buf   = (float*)alloc((size_t)BL * DM * 4);
    float*  y_buf   = (float*)alloc((size_t)BL * DI * 4);
    float*  fxn_buf = (float*)alloc((size_t)BL * DM * 4);
    float*  sc_buf  = (float*)alloc((size_t)BSZ * NCH * CHK * CHK * 4);
    float*  S_buf   = (float*)alloc((size_t)BSZ * NCH * NH * HD * DSTATE * 4);
    float*  hs_buf  = (float*)alloc((size_t)BSZ * NCH * NH * HD * DSTATE * 4);
    float*  dt_buf  = (float*)alloc((size_t)BSZ * NCH * NH * CHK * 4);
    float*  ac_buf  = (float*)alloc((size_t)BSZ * NCH * NH * CHK * 4);
    float*  ds_buf  = (float*)alloc((size_t)BSZ * NCH * NH * CHK * 4);
    float*  dec_buf = (float*)alloc((size_t)BSZ * NCH * NH * 4);
    float*  dtraw   = (float*)alloc((size_t)BL * 16 * 4);
    ushort* xn_bf   = (ushort*)alloc((size_t)BL * DM * 2);
    ushort* zx_bf   = (ushort*)alloc((size_t)BL * DIP * 2);
    ushort* xc_bf   = (ushort*)alloc((size_t)BL * CONVD * 2);
    ushort* y_bf    = (ushort*)alloc((size_t)BL * DI * 2);

    size_t in_full  = (size_t)NLAYER * NPAD_IN * DM * 2;
    size_t out_full = (size_t)NLAYER * DM * DI * 2;
    size_t used = (size_t)(p - (char*)d_ws);
    bool full = (used + in_full + out_full + 4096) <= ws_size;
    ushort* inT  = (ushort*)alloc(full ? in_full  : (size_t)NPAD_IN * DM * 2);
    ushort* outT = (ushort*)alloc(full ? out_full : (size_t)DM * DI * 2);

    embed_kernel<<<BL, 256, 0, stream>>>(x, W_embed, h_buf);

    if (full) {
        convT_kernel<<<dim3(NPAD_IN / 64, DM / 64, NLAYER), 256, 0, stream>>>(
            in_w, inT, DM, DIP, NPAD_IN);
        convT_kernel<<<dim3(DM / 64, DI / 64, NLAYER), 256, 0, stream>>>(
            out_w, outT, DI, DM, DM);
    }

    for (int l = 0; l < NLAYER; l++) {
        const float* rw = rms_w + (size_t)l * DM;
        const float* cw = conv_w + (size_t)l * CONVD * 4;
        const float* cb = conv_b + (size_t)l * CONVD;
        const float* db = dt_bias + (size_t)l * NH;
        const float* al = A_log + (size_t)l * NH;
        const float* dp = D_param + (size_t)l * NH;
        const float* gw = gnorm_w + (size_t)l * DI;

        ushort* inT_l  = full ? inT  + (size_t)l * NPAD_IN * DM : inT;
        ushort* outT_l = full ? outT + (size_t)l * DM * DI      : outT;
        if (!full) {
            convT_kernel<<<dim3(NPAD_IN / 64, DM / 64, 1), 256, 0, stream>>>(
                in_w + (size_t)l * DM * DIP, inT_l, DM, DIP, NPAD_IN);
            convT_kernel<<<dim3(DM / 64, DI / 64, 1), 256, 0, stream>>>(
                out_w + (size_t)l * DI * DM, outT_l, DI, DM, DM);
        }

        rmsnorm512_bf_kernel<<<BL, 256, 0, stream>>>(h_buf, rw, xn_bf);
        gemm_bf16_kernel<0><<<dim3(NPAD_IN / 128, BL / 128), 256, 0, stream>>>(
            xn_bf, inT_l, zx_bf, nullptr, dtraw, DIP, DIP, DM);
        conv_kernel<<<(BL * CONVD) / 256, 256, 0, stream>>>(zx_bf, cw, cb, xc_bf);
        dtscan_kernel<<<BSZ * NCH * NH, 128, 0, stream>>>(dtraw, db, al, dt_buf, ac_buf,
                                                          ds_buf, dec_buf);
        scores_kernel<<<dim3(2, BSZ * NCH), 256, 0, stream>>>(xc_bf, sc_buf);
        ydiag_kernel<<<dim3(NH, BSZ * NCH), 256, 0, stream>>>(xc_bf, sc_buf, ac_buf,
                                                              dt_buf, y_buf);
        state_kernel<<<dim3(NH, BSZ * NCH), 256, 0, stream>>>(xc_bf, ds_buf, S_buf);
        scan_kernel<<<(BSZ * NH * HD * DSTATE) / 256, 256, 0, stream>>>(S_buf, dec_buf,
                                                                        hs_buf);
        yoff_kernel<<<dim3(NH, BSZ * NCH), 256, 0, stream>>>(xc_bf, hs_buf, ac_buf, dp,
                                                             y_buf);
        gatenorm_kernel<<<BL, 256, 0, stream>>>(y_buf, zx_bf, gw, y_bf);
        gemm_bf16_kernel<1><<<dim3(DM / 128, BL / 128), 256, 0, stream>>>(
            y_bf, outT_l, nullptr, h_buf, nullptr, DM, DM, DI);
    }

    rmsnorm512_f_kernel<<<BL, 256, 0, stream>>>(h_buf, fnorm_w, fxn_buf);
    head_kernel<<<BL, 256, 0, stream>>>(fxn_buf, head_w, head_b, out);
}

// Round 3
// 2141.642 us; speedup vs baseline: 2.5762x; 1.0814x over previous
//
#include <hip/hip_runtime.h>
#include <math.h>

#define DM 512
#define DSTATE 64
#define HD 64
#define DI 1024
#define NH 16
#define CONVD 1152
#define DIP 2192
#define CHK 128
#define NCH 16
#define BSZ 2
#define SEQL 2048
#define BL (BSZ*SEQL)
#define NLAYER 12
#define EPSF 1e-5f
#define NPAD_IN 2304

typedef __attribute__((ext_vector_type(4))) float f32x4;
typedef __attribute__((ext_vector_type(8))) short s16x8;

__device__ __forceinline__ float bf2f(ushort u) {
    union { unsigned int i; float f; } v; v.i = ((unsigned int)u) << 16; return v.f;
}
__device__ __forceinline__ ushort f2bf(float f) {
    union { float f; unsigned int u; } v; v.f = f;
    unsigned int u = v.u;
    unsigned int r = (u + 0x7fffu + ((u >> 16) & 1u)) >> 16;
    return (ushort)r;
}

#define GLOAD_LDS16(gptr, lptr) __builtin_amdgcn_global_load_lds( \
    (const __attribute__((address_space(1))) void*)(gptr), \
    (__attribute__((address_space(3))) void*)(lptr), 16, 0, 0)

#define MFMA_BF16(a, b, c) __builtin_amdgcn_mfma_f32_16x16x32_bf16(a, b, c, 0, 0, 0)

// ---------------- embed + nerf positional encoding ----------------
__global__ void embed_kernel(const float* __restrict__ x, const float* __restrict__ W,
                             float* __restrict__ h) {
    int tok = blockIdx.x;
    float xe[3];
#pragma unroll
    for (int e = 0; e < 3; e++) {
        float v = x[tok * 3 + e];
        xe[e] = (v == -100.0f) ? 0.0f : v;
    }
    for (int d = threadIdx.x; d < DM; d += blockDim.x) {
        float pe = 0.0f;
        if (d < 510) {
            int e = d / 170, r = d % 170;
            int is_sin = (r < 85);
            int k = is_sin ? r : r - 85;
            float ang = xe[e] * ldexpf(1.0f, k);   // exact in fp32
            double dv = is_sin ? sin((double)ang) : cos((double)ang);
            pe = (float)dv;
        }
        float acc = pe;
#pragma unroll
        for (int e = 0; e < 3; e++) acc += xe[e] * W[e * DM + d];
        h[(size_t)tok * DM + d] = acc;
    }
}

// ---------------- rmsnorm width=512 -> bf16 out ----------------
__global__ __launch_bounds__(256) void rmsnorm512_bf_kernel(const float* __restrict__ in,
                                                            const float* __restrict__ w,
                                                            ushort* __restrict__ out) {
    int tok = blockIdx.x;
    const float* row = in + (size_t)tok * DM;
    float v0 = row[threadIdx.x];
    float v1 = row[threadIdx.x + 256];
    float ss = v0 * v0 + v1 * v1;
    for (int o = 32; o; o >>= 1) ss += __shfl_down(ss, o);
    __shared__ float sbuf[4];
    if ((threadIdx.x & 63) == 0) sbuf[threadIdx.x >> 6] = ss;
    __syncthreads();
    if (threadIdx.x == 0) {
        float s = sbuf[0] + sbuf[1] + sbuf[2] + sbuf[3];
        sbuf[0] = rsqrtf(s / (float)DM + EPSF);
    }
    __syncthreads();
    float rs = sbuf[0];
    ushort* orow = out + (size_t)tok * DM;
    orow[threadIdx.x] = f2bf(v0 * rs * w[threadIdx.x]);
    orow[threadIdx.x + 256] = f2bf(v1 * rs * w[threadIdx.x + 256]);
}

// ---------------- gate silu(z)*y + rmsnorm (width 1024) -> bf16 --------
__global__ __launch_bounds__(256) void gatenorm_kernel(const float* __restrict__ y,
                                                       const ushort* __restrict__ zx,
                                                       const float* __restrict__ gw,
                                                       ushort* __restrict__ yb) {
    int tok = blockIdx.x;
    const ushort* zrow = zx + (size_t)tok * DIP;
    const float* yrow = y + (size_t)tok * DI;
    float v[4];
    float ss = 0.0f;
#pragma unroll
    for (int k = 0; k < 4; k++) {
        int d = threadIdx.x + k * 256;
        float z = bf2f(zrow[d]);
        float s = z / (1.0f + __expf(-z));
        float val = yrow[d] * s;
        v[k] = val;
        ss += val * val;
    }
    for (int o = 32; o; o >>= 1) ss += __shfl_down(ss, o);
    __shared__ float sbuf[4];
    if ((threadIdx.x & 63) == 0) sbuf[threadIdx.x >> 6] = ss;
    __syncthreads();
    if (threadIdx.x == 0) {
        float s = sbuf[0] + sbuf[1] + sbuf[2] + sbuf[3];
        sbuf[0] = rsqrtf(s / (float)DI + EPSF);
    }
    __syncthreads();
    float rs = sbuf[0];
    ushort* ob = yb + (size_t)tok * DI;
#pragma unroll
    for (int k = 0; k < 4; k++) {
        int d = threadIdx.x + k * 256;
        ob[d] = f2bf(v[k] * rs * gw[d]);
    }
}

// ---------------- weight convert+transpose: w[L][K][N] f32 -> wT[L][Npad][K] bf16 ----
__global__ __launch_bounds__(256) void convT_kernel(const float* __restrict__ w,
                                                    ushort* __restrict__ wT,
                                                    int K, int N, int Npad) {
    __shared__ ushort tile[64][65];
    int l = blockIdx.z;
    int n0 = blockIdx.x * 64, k0 = blockIdx.y * 64;
    const float* src = w + (size_t)l * K * N;
    ushort* dst = wT + (size_t)l * Npad * K;
    int tid = threadIdx.x;
#pragma unroll
    for (int t = 0; t < 16; t++) {
        int idx = tid + t * 256;
        int r = idx >> 6, c = idx & 63;
        float v = (n0 + c < N) ? src[(size_t)(k0 + r) * N + n0 + c] : 0.0f;
        tile[c][r] = f2bf(v);
    }
    __syncthreads();
#pragma unroll
    for (int t = 0; t < 16; t++) {
        int idx = tid + t * 256;
        int r = idx >> 6, c = idx & 63;
        dst[(size_t)(n0 + r) * K + k0 + c] = tile[r][c];
    }
}

// ---------------- bf16 MFMA GEMM: C[M,N] = A[M,K] * BT[N,K]^T ----------------
// BM = MT*32 (MT=4 -> 128, MT=2 -> 64) x BN=128 tile, BK=64, 4 waves (2x2).
// MODE 0: bf16 store + dt sidecar; MODE 1: fp32 accumulate; MODE 2: fp32 + bias (head)
template <int MODE, int MT>
__global__ __launch_bounds__(256) void gemm_bf16_kernel(
    const ushort* __restrict__ A, const ushort* __restrict__ BT,
    ushort* __restrict__ Cb, float* __restrict__ Cf, float* __restrict__ aux,
    int N, int Nstride, int K)
{
    __shared__ ushort As[MT * 32 * 64];
    __shared__ ushort Bs[128 * 64];
    int bm = blockIdx.y * (MT * 32), bn = blockIdx.x * 128;
    int tid = threadIdx.x;
    int lane = tid & 63, wid = tid >> 6;
    int wr = wid >> 1, wc = wid & 1;
    int r15 = lane & 15, q = lane >> 4;
    f32x4 acc[MT][4] = {};

    for (int k0 = 0; k0 < K; k0 += 64) {
#pragma unroll
        for (int t = 0; t < MT; t++) {
            int cbase = wid * (MT * 64) + t * 64;
            int chunk = cbase + lane;
            int row = chunk >> 3, s = chunk & 7;
            int kc = s ^ (row & 7);
            GLOAD_LDS16(A + (size_t)(bm + row) * K + k0 + kc * 8, As + (size_t)cbase * 8);
        }
#pragma unroll
        for (int t = 0; t < 4; t++) {
            int cbase = wid * 256 + t * 64;
            int chunk = cbase + lane;
            int row = chunk >> 3, s = chunk & 7;
            int kc = s ^ (row & 7);
            GLOAD_LDS16(BT + (size_t)(bn + row) * K + k0 + kc * 8, Bs + (size_t)cbase * 8);
        }
        __syncthreads();
#pragma unroll
        for (int kh = 0; kh < 2; kh++) {
            s16x8 av[MT], bv[4];
#pragma unroll
            for (int m = 0; m < MT; m++) {
                int row = wr * (MT * 16) + m * 16 + r15;
                int s = (kh * 4 + q) ^ (row & 7);
                av[m] = *(const s16x8*)(As + row * 64 + s * 8);
            }
#pragma unroll
            for (int n = 0; n < 4; n++) {
                int row = wc * 64 + n * 16 + r15;
                int s = (kh * 4 + q) ^ (row & 7);
                bv[n] = *(const s16x8*)(Bs + row * 64 + s * 8);
            }
#pragma unroll
            for (int m = 0; m < MT; m++)
#pragma unroll
                for (int n = 0; n < 4; n++)
                    acc[m][n] = MFMA_BF16(av[m], bv[n], acc[m][n]);
        }
        __syncthreads();
    }
#pragma unroll
    for (int m = 0; m < MT; m++) {
        int row0 = bm + wr * (MT * 16) + m * 16 + q * 4;
#pragma unroll
        for (int n = 0; n < 4; n++) {
            int col = bn + wc * 64 + n * 16 + r15;
#pragma unroll
            for (int r = 0; r < 4; r++) {
                float v = acc[m][n][r];
                int rr = row0 + r;
                if (MODE == 0) {
                    if (col < N) {
                        Cb[(size_t)rr * Nstride + col] = f2bf(v);
                        if (col >= DI + CONVD) aux[(size_t)rr * 16 + (col - DI - CONVD)] = v;
                    }
                } else if (MODE == 1) {
                    Cf[(size_t)rr * Nstride + col] += v;
                } else {
                    if (col < N) Cf[(size_t)rr * Nstride + col] = v + aux[col];
                }
            }
        }
    }
}

// ---------------- causal depthwise conv (d=4) + bias + silu, 8 ch/thread ------
__global__ void conv_kernel(const ushort* __restrict__ zx, const float* __restrict__ cw,
                            const float* __restrict__ cb, ushort* __restrict__ xc) {
    int gid = blockIdx.x * 256 + threadIdx.x;      // BL*CONVD/8 units
    int cu = gid % (CONVD / 8);
    int lg = gid / (CONVD / 8);
    int c8 = cu * 8;
    int l = lg % SEQL;
    float acc[8];
#pragma unroll
    for (int e = 0; e < 8; e++) acc[e] = cb[c8 + e];
#pragma unroll
    for (int k = 0; k < 4; k++) {
        if (l + k - 3 >= 0) {
            s16x8 v = *(const s16x8*)(zx + (size_t)(lg + k - 3) * DIP + DI + c8);
#pragma unroll
            for (int e = 0; e < 8; e++) acc[e] += bf2f((ushort)v[e]) * cw[(c8 + e) * 4 + k];
        }
    }
    s16x8 o;
#pragma unroll
    for (int e = 0; e < 8; e++) {
        float s = acc[e] / (1.0f + __expf(-acc[e]));
        o[e] = (short)f2bf(s);
    }
    *(s16x8*)(xc + (size_t)lg * CONVD + c8) = o;
}

// ---------------- dt softplus + within-chunk cumsum + dstate/dec ----------------
__global__ void dtscan_kernel(const float* __restrict__ dtraw, const float* __restrict__ dt_bias,
                              const float* __restrict__ A_log, float* __restrict__ dtbuf,
                              float* __restrict__ acum, float* __restrict__ dsbuf,
                              float* __restrict__ decbuf) {
    int bch = blockIdx.x;
    int bc = bch >> 4, hh = bch & 15;
    int j = threadIdx.x;
    int row = bc * CHK + j;
    float raw = dtraw[(size_t)row * 16 + hh] + dt_bias[hh];
    float dt = raw > 0.0f ? raw + log1pf(__expf(-raw)) : log1pf(__expf(raw));
    float A = -__expf(A_log[hh]);
    float a = dt * A;
    int lane = j & 63;
    float v = a;
#pragma unroll
    for (int o = 1; o < 64; o <<= 1) {
        float u = __shfl_up(v, o);
        if (lane >= o) v += u;
    }
    __shared__ float wsum, stot;
    if (j == 63) wsum = v;
    __syncthreads();
    float ac = (j >= 64) ? v + wsum : v;
    if (j == 127) stot = ac;
    __syncthreads();
    float asum = stot;
    size_t base = (size_t)bch * CHK;
    dtbuf[base + j] = dt;
    acum[base + j] = ac;
    dsbuf[base + j] = __expf(asum - ac) * dt;
    if (j == 0) decbuf[bch] = __expf(asum);
}

// ---------------- F1: fused scores + M + y_diag(+D*xh) + chunk-state ----------------
// grid (8 head-pairs, 32 bc); 256 threads (4 waves, 2x2 quadrants)
__global__ __launch_bounds__(256, 2) void ssd1_kernel(
    const ushort* __restrict__ xc, const float* __restrict__ acg,
    const float* __restrict__ dtg, const float* __restrict__ dsg,
    const float* __restrict__ Dp, float* __restrict__ y, float* __restrict__ S)
{
    __shared__ ushort Mb[128 * 128];        // union: Cs=[0,8192) Bs=[8192,16384) ; later M (swizzled)
    __shared__ ushort xhT[64 * 136];        // xhT[p][j], swizzled rows
    __shared__ ushort BmT[64 * 136];        // BmT[n][j], swizzled rows
    __shared__ float sAc[128], sDt[128], sDs[128];

    int hp = blockIdx.x, bc = blockIdx.y;
    int tid = threadIdx.x, lane = tid & 63, wid = tid >> 6;
    int wr = wid >> 1, wc = wid & 1;
    int l15 = lane & 15, lq = lane >> 4;
    ushort* Cs = Mb;
    ushort* Bs = Mb + 8192;
    const size_t xbase = (size_t)(bc * CHK) * CONVD;

    // stage Cs [128 i][64 n] and Bs [128 j][64 n], gemm-style swizzle
#pragma unroll
    for (int t = 0; t < 4; t++) {
        int cbase = t * 256 + wid * 64;
        int chunk = cbase + lane;
        int row = chunk >> 3, s = chunk & 7;
        int kc = s ^ (row & 7);
        GLOAD_LDS16(xc + xbase + (size_t)row * CONVD + DI + DSTATE + kc * 8, Cs + (size_t)cbase * 8);
        GLOAD_LDS16(xc + xbase + (size_t)row * CONVD + DI + kc * 8, Bs + (size_t)cbase * 8);
    }
    // stage BmT[n][j] transposed+swizzled (reg path)
    {
        int j = (wid & 1) * 64 + lane;
        int pch = wid >> 1;
#pragma unroll
        for (int it = 0; it < 4; it++) {
            int pc = pch * 4 + it;
            s16x8 v = *(const s16x8*)(xc + xbase + (size_t)j * CONVD + DI + pc * 8);
#pragma unroll
            for (int e = 0; e < 8; e++) {
                int R = pc * 8 + e;
                BmT[R * 136 + (((j >> 3) ^ (R & 7)) << 3) + (j & 7)] = (ushort)v[e];
            }
        }
    }
    __syncthreads();

    // scores quadrant (wr,wc): rows i = wr*64+, cols j = wc*64+
    f32x4 acc_s[4][4] = {};
#pragma unroll
    for (int kh = 0; kh < 2; kh++) {
        s16x8 av[4], bv[4];
#pragma unroll
        for (int m = 0; m < 4; m++) {
            int row = wr * 64 + m * 16 + l15;
            int sl = (kh * 4 + lq) ^ (row & 7);
            av[m] = *(const s16x8*)(Cs + row * 64 + sl * 8);
        }
#pragma unroll
        for (int n = 0; n < 4; n++) {
            int row = wc * 64 + n * 16 + l15;
            int sl = (kh * 4 + lq) ^ (row & 7);
            bv[n] = *(const s16x8*)(Bs + row * 64 + sl * 8);
        }
#pragma unroll
        for (int m = 0; m < 4; m++)
#pragma unroll
            for (int n = 0; n < 4; n++)
                acc_s[m][n] = MFMA_BF16(av[m], bv[n], acc_s[m][n]);
    }

    for (int hp2 = 0; hp2 < 2; hp2++) {
        int hh = hp * 2 + hp2;
        int bch = bc * NH + hh;
        __syncthreads();   // all prior reads of Cs/Bs (or M/xhT from prev head) done
        // stage xhT[p][j] transposed+swizzled
        {
            int j = (wid & 1) * 64 + lane;
            int pch = wid >> 1;
#pragma unroll
            for (int it = 0; it < 4; it++) {
                int pc = pch * 4 + it;
                s16x8 v = *(const s16x8*)(xc + xbase + (size_t)j * CONVD + hh * HD + pc * 8);
#pragma unroll
                for (int e = 0; e < 8; e++) {
                    int R = pc * 8 + e;
                    xhT[R * 136 + (((j >> 3) ^ (R & 7)) << 3) + (j & 7)] = (ushort)v[e];
                }
            }
        }
        if (tid < 128) {
            sAc[tid] = acg[(size_t)bch * CHK + tid];
            sDt[tid] = dtg[(size_t)bch * CHK + tid];
            sDs[tid] = dsg[(size_t)bch * CHK + tid];
        }
        __syncthreads();
        // build M (bf16, swizzled) from register scores
#pragma unroll
        for (int m = 0; m < 4; m++) {
#pragma unroll
            for (int n = 0; n < 4; n++) {
                int j = wc * 64 + n * 16 + l15;
                float acj = sAc[j], dtj = sDt[j];
#pragma unroll
                for (int r = 0; r < 4; r++) {
                    int i = wr * 64 + m * 16 + lq * 4 + r;
                    float v = (j <= i) ? acc_s[m][n][r] * __expf(sAc[i] - acj) * dtj : 0.0f;
                    Mb[i * 128 + ((((i & 7) ^ (j >> 3)) << 3) | (j & 7))] = f2bf(v);
                }
            }
        }
        __syncthreads();

        // PV: yT[p][i] = sum_j xhT[p][j] * M[i][j]    (p: wr*32+m*16 m<2; i: wc*64+n*16 n<4)
        // state: S[p][n] = sum_j (ds_j*xhT[p][j]) * BmT[n][j]   (n: wc*32+nf*16 nf<2)
        f32x4 acc_y[2][4] = {};
        f32x4 acc_st[2][2] = {};
#pragma unroll
        for (int ks = 0; ks < 4; ks++) {
            int cj = ks * 4 + lq;
            int j0 = ks * 32 + lq * 8;
            s16x8 axh[2], axs[2];
#pragma unroll
            for (int m = 0; m < 2; m++) {
                int p = wr * 32 + m * 16 + l15;
                axh[m] = *(const s16x8*)(xhT + p * 136 + ((cj ^ (p & 7)) << 3));
                s16x8 r;
#pragma unroll
                for (int e = 0; e < 8; e++)
                    r[e] = (short)f2bf(bf2f((ushort)axh[m][e]) * sDs[j0 + e]);
                axs[m] = r;
            }
            s16x8 bm_[4];
#pragma unroll
            for (int n = 0; n < 4; n++) {
                int i = wc * 64 + n * 16 + l15;
                bm_[n] = *(const s16x8*)(Mb + i * 128 + ((cj ^ (i & 7)) << 3));
            }
            s16x8 bb[2];
#pragma unroll
            for (int n = 0; n < 2; n++) {
                int nn = wc * 32 + n * 16 + l15;
                bb[n] = *(const s16x8*)(BmT + nn * 136 + ((cj ^ (nn & 7)) << 3));
            }
#pragma unroll
            for (int m = 0; m < 2; m++) {
#pragma unroll
                for (int n = 0; n < 4; n++)
                    acc_y[m][n] = MFMA_BF16(axh[m], bm_[n], acc_y[m][n]);
#pragma unroll
                for (int n = 0; n < 2; n++)
                    acc_st[m][n] = MFMA_BF16(axs[m], bb[n], acc_st[m][n]);
            }
        }
        // epilogue
        float Dh = Dp[hh];
#pragma unroll
        for (int m = 0; m < 2; m++) {
            int p0 = wr * 32 + m * 16 + lq * 4;
#pragma unroll
            for (int n = 0; n < 4; n++) {
                int i = wc * 64 + n * 16 + l15;
                f32x4 v = acc_y[m][n];
#pragma unroll
                for (int r = 0; r < 4; r++) {
                    int p = p0 + r;
                    v[r] += Dh * bf2f(xhT[p * 136 + ((((p & 7) ^ (i >> 3)) << 3) | (i & 7))]);
                }
                *(f32x4*)&y[(size_t)(bc * CHK + i) * DI + hh * HD + p0] = v;
            }
#pragma unroll
            for (int n = 0; n < 2; n++) {
                int nn = wc * 32 + n * 16 + l15;
#pragma unroll
                for (int r = 0; r < 4; r++)
                    S[(size_t)bch * 4096 + (size_t)(p0 + r) * 64 + nn] = acc_st[m][n][r];
            }
        }
    }
}

// ---------------- sequential scan over chunks ----------------
__global__ void scan_kernel(const float* __restrict__ S, const float* __restrict__ decbuf,
                            float* __restrict__ hs) {
    int g = blockIdx.x * 256 + threadIdx.x;
    int n = g & 63, p = (g >> 6) & 63, hh = (g >> 12) & 15, b = g >> 16;
    float state = 0.0f;
#pragma unroll
    for (int c = 0; c < NCH; c++) {
        int bch = (b * NCH + c) * NH + hh;
        size_t idx = (size_t)bch * 4096 + p * 64 + n;
        hs[idx] = state;
        state = state * decbuf[bch] + S[idx];
    }
}

// ---------------- F2: y += exp(ac_i) * (C @ hs^T)  via MFMA, transposed output ------
// grid (NH, 32 bc)
__global__ __launch_bounds__(256) void ssd2_kernel(
    const ushort* __restrict__ xc, const float* __restrict__ hsg,
    const float* __restrict__ acg, float* __restrict__ y)
{
    __shared__ ushort Cs[128 * 64];
    __shared__ ushort Hs[64 * 64];
    __shared__ float sAc[128];
    int hh = blockIdx.x, bc = blockIdx.y;
    int tid = threadIdx.x, lane = tid & 63, wid = tid >> 6;
    int wr = wid >> 1, wc = wid & 1, l15 = lane & 15, lq = lane >> 4;
    int bch = bc * NH + hh;
    const size_t xbase = (size_t)(bc * CHK) * CONVD;
#pragma unroll
    for (int t = 0; t < 4; t++) {
        int cbase = t * 256 + wid * 64;
        int chunk = cbase + lane;
        int row = chunk >> 3, s = chunk & 7;
        int kc = s ^ (row & 7);
        GLOAD_LDS16(xc + xbase + (size_t)row * CONVD + DI + DSTATE + kc * 8, Cs + (size_t)cbase * 8);
    }
#pragma unroll
    for (int t = 0; t < 2; t++) {
        int chunk = t * 256 + tid;
        int p = chunk >> 3, s = chunk & 7;
        int kc = s ^ (p & 7);
        const float* src = hsg + (size_t)bch * 4096 + p * 64 + kc * 8;
        ushort* dst = Hs + p * 64 + s * 8;
#pragma unroll
        for (int e = 0; e < 8; e++) dst[e] = f2bf(src[e]);
    }
    if (tid < 128) sAc[tid] = acg[(size_t)bch * CHK + tid];
    __syncthreads();
    f32x4 acc[2][4] = {};
#pragma unroll
    for (int kh = 0; kh < 2; kh++) {
        s16x8 av[2], bv[4];
#pragma unroll
        for (int m = 0; m < 2; m++) {
            int p = wr * 32 + m * 16 + l15;
            int sl = (kh * 4 + lq) ^ (p & 7);
            av[m] = *(const s16x8*)(Hs + p * 64 + sl * 8);
        }
#pragma unroll
        for (int n = 0; n < 4; n++) {
            int i = wc * 64 + n * 16 + l15;
            int sl = (kh * 4 + lq) ^ (i & 7);
            bv[n] = *(const s16x8*)(Cs + i * 64 + sl * 8);
        }
#pragma unroll
        for (int m = 0; m < 2; m++)
#pragma unroll
            for (int n = 0; n < 4; n++)
                acc[m][n] = MFMA_BF16(av[m], bv[n], acc[m][n]);
    }
#pragma unroll
    for (int m = 0; m < 2; m++) {
        int p0 = wr * 32 + m * 16 + lq * 4;
#pragma unroll
        for (int n = 0; n < 4; n++) {
            int i = wc * 64 + n * 16 + l15;
            float e = __expf(sAc[i]);
            float* dst = &y[(size_t)(bc * CHK + i) * DI + hh * HD + p0];
            f32x4 v = *(f32x4*)dst;
#pragma unroll
            for (int r = 0; r < 4; r++) v[r] += e * acc[m][n][r];
            *(f32x4*)dst = v;
        }
    }
}

extern "C" void kernel_launch(void* const* d_in, const int* in_sizes, int n_in,
                              void* d_out, int out_size, void* d_ws, size_t ws_size,
                              hipStream_t stream) {
    const float* x        = (const float*)d_in[0];
    const float* W_embed  = (const float*)d_in[1];
    const float* rms_w    = (const float*)d_in[2];
    const float* in_w     = (const float*)d_in[3];
    const float* conv_w   = (const float*)d_in[4];
    const float* conv_b   = (const float*)d_in[5];
    const float* dt_bias  = (const float*)d_in[6];
    const float* A_log    = (const float*)d_in[7];
    const float* D_param  = (const float*)d_in[8];
    const float* gnorm_w  = (const float*)d_in[9];
    const float* out_w    = (const float*)d_in[10];
    const float* fnorm_w  = (const float*)d_in[11];
    const float* head_w   = (const float*)d_in[12];
    const float* head_b   = (const float*)d_in[13];
    float* out = (float*)d_out;

    char* p = (char*)d_ws;
    auto alloc = [&](size_t bytes) { char* r = p; p += (bytes + 255) & ~(size_t)255; return r; };

    float*  h_buf   = (float*)alloc((size_t)BL * DM * 4);
    float*  y_buf   = (float*)alloc((size_t)BL * DI * 4);
    float*  S_buf   = (float*)alloc((size_t)BSZ * NCH * NH * HD * DSTATE * 4);
    float*  hs_buf  = (float*)alloc((size_t)BSZ * NCH * NH * HD * DSTATE * 4);
    float*  dt_buf  = (float*)alloc((size_t)BSZ * NCH * NH * CHK * 4);
    float*  ac_buf  = (float*)alloc((size_t)BSZ * NCH * NH * CHK * 4);
    float*  ds_buf  = (float*)alloc((size_t)BSZ * NCH * NH * CHK * 4);
    float*  dec_buf = (float*)alloc((size_t)BSZ * NCH * NH * 4);
    float*  dtraw   = (float*)alloc((size_t)BL * 16 * 4);
    ushort* xn_bf   = (ushort*)alloc((size_t)BL * DM * 2);
    ushort* zx_bf   = (ushort*)alloc((size_t)BL * DIP * 2);
    ushort* xc_bf   = (ushort*)alloc((size_t)BL * CONVD * 2);
    ushort* y_bf    = (ushort*)alloc((size_t)BL * DI * 2);
    ushort* headT   = (ushort*)alloc((size_t)128 * DM * 2);

    size_t in_full  = (size_t)NLAYER * NPAD_IN * DM * 2;
    size_t out_full = (size_t)NLAYER * DM * DI * 2;
    size_t used = (size_t)(p - (char*)d_ws);
    bool full = (used + in_full + out_full + 4096) <= ws_size;
    ushort* inT  = (ushort*)alloc(full ? in_full  : (size_t)NPAD_IN * DM * 2);
    ushort* outT = (ushort*)alloc(full ? out_full : (size_t)DM * DI * 2);

    embed_kernel<<<BL, 256, 0, stream>>>(x, W_embed, h_buf);
    convT_kernel<<<dim3(2, DM / 64, 1), 256, 0, stream>>>(head_w, headT, DM, 30, 128);
    if (full) {
        convT_kernel<<<dim3(NPAD_IN / 64, DM / 64, NLAYER), 256, 0, stream>>>(
            in_w, inT, DM, DIP, NPAD_IN);
        convT_kernel<<<dim3(DM / 64, DI / 64, NLAYER), 256, 0, stream>>>(
            out_w, outT, DI, DM, DM);
    }

    for (int l = 0; l < NLAYER; l++) {
        const float* rw = rms_w + (size_t)l * DM;
        const float* cw = conv_w + (size_t)l * CONVD * 4;
        const float* cb = conv_b + (size_t)l * CONVD;
        const float* db = dt_bias + (size_t)l * NH;
        const float* al = A_log + (size_t)l * NH;
        const float* dp = D_param + (size_t)l * NH;
        const float* gw = gnorm_w + (size_t)l * DI;

        ushort* inT_l  = full ? inT  + (size_t)l * NPAD_IN * DM : inT;
        ushort* outT_l = full ? outT + (size_t)l * DM * DI      : outT;
        if (!full) {
            convT_kernel<<<dim3(NPAD_IN / 64, DM / 64, 1), 256, 0, stream>>>(
                in_w + (size_t)l * DM * DIP, inT_l, DM, DIP, NPAD_IN);
            convT_kernel<<<dim3(DM / 64, DI / 64, 1), 256, 0, stream>>>(
                out_w + (size_t)l * DI * DM, outT_l, DI, DM, DM);
        }

        rmsnorm512_bf_kernel<<<BL, 256, 0, stream>>>(h_buf, rw, xn_bf);
        gemm_bf16_kernel<0, 4><<<dim3(NPAD_IN / 128, BL / 128), 256, 0, stream>>>(
            xn_bf, inT_l, zx_bf, nullptr, dtraw, DIP, DIP, DM);
        conv_kernel<<<(BL * CONVD / 8) / 256, 256, 0, stream>>>(zx_bf, cw, cb, xc_bf);
        dtscan_kernel<<<BSZ * NCH * NH, 128, 0, stream>>>(dtraw, db, al, dt_buf, ac_buf,
                                                          ds_buf, dec_buf);
        ssd1_kernel<<<dim3(8, BSZ * NCH), 256, 0, stream>>>(xc_bf, ac_buf, dt_buf, ds_buf,
                                                            dp, y_buf, S_buf);
        scan_kernel<<<(BSZ * NH * HD * DSTATE) / 256, 256, 0, stream>>>(S_buf, dec_buf,
                                                                        hs_buf);
        ssd2_kernel<<<dim3(NH, BSZ * NCH), 256, 0, stream>>>(xc_bf, hs_buf, ac_buf, y_buf);
        gatenorm_kernel<<<BL, 256, 0, stream>>>(y_buf, zx_bf, gw, y_bf);
        gemm_bf16_kernel<1, 2><<<dim3(DM / 128, BL / 64), 256, 0, stream>>>(
            y_bf, outT_l, nullptr, h_buf, nullptr, DM, DM, DI);
    }

    rmsnorm512_bf_kernel<<<BL, 256, 0, stream>>>(h_buf, fnorm_w, xn_bf);
    gemm_bf16_kernel<2, 4><<<dim3(1, BL / 128), 256, 0, stream>>>(
        xn_bf, headT, nullptr, out, (float*)head_b, 30, 30, DM);
}

// Round 4
// 1787.330 us; speedup vs baseline: 3.0869x; 1.1982x over previous
//
#include <hip/hip_runtime.h>
#include <math.h>

#define DM 512
#define DSTATE 64
#define HD 64
#define DI 1024
#define NH 16
#define CONVD 1152
#define DIP 2192
#define CHK 128
#define NCH 16
#define BSZ 2
#define SEQL 2048
#define BL (BSZ*SEQL)
#define NLAYER 12
#define EPSF 1e-5f
#define NPAD_IN 2304

typedef __attribute__((ext_vector_type(4))) float f32x4;
typedef __attribute__((ext_vector_type(8))) short s16x8;

__device__ __forceinline__ float bf2f(ushort u) {
    union { unsigned int i; float f; } v; v.i = ((unsigned int)u) << 16; return v.f;
}
__device__ __forceinline__ ushort f2bf(float f) {
    union { float f; unsigned int u; } v; v.f = f;
    unsigned int u = v.u;
    unsigned int r = (u + 0x7fffu + ((u >> 16) & 1u)) >> 16;
    return (ushort)r;
}

#define GLOAD_LDS16(gptr, lptr) __builtin_amdgcn_global_load_lds( \
    (const __attribute__((address_space(1))) void*)(gptr), \
    (__attribute__((address_space(3))) void*)(lptr), 16, 0, 0)

#define MFMA_BF16(a, b, c) __builtin_amdgcn_mfma_f32_16x16x32_bf16(a, b, c, 0, 0, 0)

// ---------------- embed + nerf positional encoding ----------------
__global__ void embed_kernel(const float* __restrict__ x, const float* __restrict__ W,
                             float* __restrict__ h) {
    int tok = blockIdx.x;
    float xe[3];
#pragma unroll
    for (int e = 0; e < 3; e++) {
        float v = x[tok * 3 + e];
        xe[e] = (v == -100.0f) ? 0.0f : v;
    }
    for (int d = threadIdx.x; d < DM; d += blockDim.x) {
        float pe = 0.0f;
        if (d < 510) {
            int e = d / 170, r = d % 170;
            int is_sin = (r < 85);
            int k = is_sin ? r : r - 85;
            float ang = xe[e] * ldexpf(1.0f, k);   // exact in fp32
            double dv = is_sin ? sin((double)ang) : cos((double)ang);
            pe = (float)dv;
        }
        float acc = pe;
#pragma unroll
        for (int e = 0; e < 3; e++) acc += xe[e] * W[e * DM + d];
        h[(size_t)tok * DM + d] = acc;
    }
}

// ---------------- rmsnorm width=512 -> bf16 out ----------------
__global__ __launch_bounds__(256) void rmsnorm512_bf_kernel(const float* __restrict__ in,
                                                            const float* __restrict__ w,
                                                            ushort* __restrict__ out) {
    int tok = blockIdx.x;
    const float* row = in + (size_t)tok * DM;
    float v0 = row[threadIdx.x];
    float v1 = row[threadIdx.x + 256];
    float ss = v0 * v0 + v1 * v1;
    for (int o = 32; o; o >>= 1) ss += __shfl_down(ss, o);
    __shared__ float sbuf[4];
    if ((threadIdx.x & 63) == 0) sbuf[threadIdx.x >> 6] = ss;
    __syncthreads();
    if (threadIdx.x == 0) {
        float s = sbuf[0] + sbuf[1] + sbuf[2] + sbuf[3];
        sbuf[0] = rsqrtf(s / (float)DM + EPSF);
    }
    __syncthreads();
    float rs = sbuf[0];
    ushort* orow = out + (size_t)tok * DM;
    orow[threadIdx.x] = f2bf(v0 * rs * w[threadIdx.x]);
    orow[threadIdx.x + 256] = f2bf(v1 * rs * w[threadIdx.x + 256]);
}

// ---------------- gate silu(z)*y + rmsnorm (width 1024) -> bf16 --------
__global__ __launch_bounds__(256) void gatenorm_kernel(const float* __restrict__ y,
                                                       const ushort* __restrict__ zx,
                                                       const float* __restrict__ gw,
                                                       ushort* __restrict__ yb) {
    int tok = blockIdx.x;
    const ushort* zrow = zx + (size_t)tok * DIP;
    const float* yrow = y + (size_t)tok * DI;
    float v[4];
    float ss = 0.0f;
#pragma unroll
    for (int k = 0; k < 4; k++) {
        int d = threadIdx.x + k * 256;
        float z = bf2f(zrow[d]);
        float s = z / (1.0f + __expf(-z));
        float val = yrow[d] * s;
        v[k] = val;
        ss += val * val;
    }
    for (int o = 32; o; o >>= 1) ss += __shfl_down(ss, o);
    __shared__ float sbuf[4];
    if ((threadIdx.x & 63) == 0) sbuf[threadIdx.x >> 6] = ss;
    __syncthreads();
    if (threadIdx.x == 0) {
        float s = sbuf[0] + sbuf[1] + sbuf[2] + sbuf[3];
        sbuf[0] = rsqrtf(s / (float)DI + EPSF);
    }
    __syncthreads();
    float rs = sbuf[0];
    ushort* ob = yb + (size_t)tok * DI;
#pragma unroll
    for (int k = 0; k < 4; k++) {
        int d = threadIdx.x + k * 256;
        ob[d] = f2bf(v[k] * rs * gw[d]);
    }
}

// ---------------- weight convert+transpose: w[L][K][N] f32 -> wT[L][Npad][K] bf16 ----
__global__ __launch_bounds__(256) void convT_kernel(const float* __restrict__ w,
                                                    ushort* __restrict__ wT,
                                                    int K, int N, int Npad) {
    __shared__ ushort tile[64][65];
    int l = blockIdx.z;
    int n0 = blockIdx.x * 64, k0 = blockIdx.y * 64;
    const float* src = w + (size_t)l * K * N;
    ushort* dst = wT + (size_t)l * Npad * K;
    int tid = threadIdx.x;
#pragma unroll
    for (int t = 0; t < 16; t++) {
        int idx = tid + t * 256;
        int r = idx >> 6, c = idx & 63;
        float v = (n0 + c < N) ? src[(size_t)(k0 + r) * N + n0 + c] : 0.0f;
        tile[c][r] = f2bf(v);
    }
    __syncthreads();
#pragma unroll
    for (int t = 0; t < 16; t++) {
        int idx = tid + t * 256;
        int r = idx >> 6, c = idx & 63;
        dst[(size_t)(n0 + r) * K + k0 + c] = tile[r][c];
    }
}

// ---------------- bf16 MFMA GEMM: C[M,N] = A[M,K] * BT[N,K]^T ----------------
// BM = MT*32 x BN=128 tile, BK=64, 4 waves (2x2).
// MODE 0: bf16 store + dt sidecar; MODE 1: fp32 accumulate; MODE 2: fp32 + bias (head)
template <int MODE, int MT>
__global__ __launch_bounds__(256) void gemm_bf16_kernel(
    const ushort* __restrict__ A, const ushort* __restrict__ BT,
    ushort* __restrict__ Cb, float* __restrict__ Cf, float* __restrict__ aux,
    int N, int Nstride, int K)
{
    __shared__ ushort As[MT * 32 * 64];
    __shared__ ushort Bs[128 * 64];
    int bm = blockIdx.y * (MT * 32), bn = blockIdx.x * 128;
    int tid = threadIdx.x;
    int lane = tid & 63, wid = tid >> 6;
    int wr = wid >> 1, wc = wid & 1;
    int r15 = lane & 15, q = lane >> 4;
    f32x4 acc[MT][4] = {};

    for (int k0 = 0; k0 < K; k0 += 64) {
#pragma unroll
        for (int t = 0; t < MT; t++) {
            int cbase = wid * (MT * 64) + t * 64;
            int chunk = cbase + lane;
            int row = chunk >> 3, s = chunk & 7;
            int kc = s ^ (row & 7);
            GLOAD_LDS16(A + (size_t)(bm + row) * K + k0 + kc * 8, As + (size_t)cbase * 8);
        }
#pragma unroll
        for (int t = 0; t < 4; t++) {
            int cbase = wid * 256 + t * 64;
            int chunk = cbase + lane;
            int row = chunk >> 3, s = chunk & 7;
            int kc = s ^ (row & 7);
            GLOAD_LDS16(BT + (size_t)(bn + row) * K + k0 + kc * 8, Bs + (size_t)cbase * 8);
        }
        __syncthreads();
#pragma unroll
        for (int kh = 0; kh < 2; kh++) {
            s16x8 av[MT], bv[4];
#pragma unroll
            for (int m = 0; m < MT; m++) {
                int row = wr * (MT * 16) + m * 16 + r15;
                int s = (kh * 4 + q) ^ (row & 7);
                av[m] = *(const s16x8*)(As + row * 64 + s * 8);
            }
#pragma unroll
            for (int n = 0; n < 4; n++) {
                int row = wc * 64 + n * 16 + r15;
                int s = (kh * 4 + q) ^ (row & 7);
                bv[n] = *(const s16x8*)(Bs + row * 64 + s * 8);
            }
#pragma unroll
            for (int m = 0; m < MT; m++)
#pragma unroll
                for (int n = 0; n < 4; n++)
                    acc[m][n] = MFMA_BF16(av[m], bv[n], acc[m][n]);
        }
        __syncthreads();
    }
#pragma unroll
    for (int m = 0; m < MT; m++) {
        int row0 = bm + wr * (MT * 16) + m * 16 + q * 4;
#pragma unroll
        for (int n = 0; n < 4; n++) {
            int col = bn + wc * 64 + n * 16 + r15;
#pragma unroll
            for (int r = 0; r < 4; r++) {
                float v = acc[m][n][r];
                int rr = row0 + r;
                if (MODE == 0) {
                    if (col < N) {
                        Cb[(size_t)rr * Nstride + col] = f2bf(v);
                        if (col >= DI + CONVD) aux[(size_t)rr * 16 + (col - DI - CONVD)] = v;
                    }
                } else if (MODE == 1) {
                    Cf[(size_t)rr * Nstride + col] += v;
                } else {
                    if (col < N) Cf[(size_t)rr * Nstride + col] = v + aux[col];
                }
            }
        }
    }
}

// ---------------- causal depthwise conv (d=4) + bias + silu, 8 ch/thread ------
__global__ void conv_kernel(const ushort* __restrict__ zx, const float* __restrict__ cw,
                            const float* __restrict__ cb, ushort* __restrict__ xc) {
    int gid = blockIdx.x * 256 + threadIdx.x;
    int cu = gid % (CONVD / 8);
    int lg = gid / (CONVD / 8);
    int c8 = cu * 8;
    int l = lg % SEQL;
    float acc[8];
#pragma unroll
    for (int e = 0; e < 8; e++) acc[e] = cb[c8 + e];
#pragma unroll
    for (int k = 0; k < 4; k++) {
        if (l + k - 3 >= 0) {
            s16x8 v = *(const s16x8*)(zx + (size_t)(lg + k - 3) * DIP + DI + c8);
#pragma unroll
            for (int e = 0; e < 8; e++) acc[e] += bf2f((ushort)v[e]) * cw[(c8 + e) * 4 + k];
        }
    }
    s16x8 o;
#pragma unroll
    for (int e = 0; e < 8; e++) {
        float s = acc[e] / (1.0f + __expf(-acc[e]));
        o[e] = (short)f2bf(s);
    }
    *(s16x8*)(xc + (size_t)lg * CONVD + c8) = o;
}

// ---------------- dt softplus + within-chunk cumsum + dstate/dec ----------------
__global__ void dtscan_kernel(const float* __restrict__ dtraw, const float* __restrict__ dt_bias,
                              const float* __restrict__ A_log, float* __restrict__ dtbuf,
                              float* __restrict__ acum, float* __restrict__ dsbuf,
                              float* __restrict__ decbuf) {
    int bch = blockIdx.x;
    int bc = bch >> 4, hh = bch & 15;
    int j = threadIdx.x;
    int row = bc * CHK + j;
    float raw = dtraw[(size_t)row * 16 + hh] + dt_bias[hh];
    float dt = raw > 0.0f ? raw + log1pf(__expf(-raw)) : log1pf(__expf(raw));
    float A = -__expf(A_log[hh]);
    float a = dt * A;
    int lane = j & 63;
    float v = a;
#pragma unroll
    for (int o = 1; o < 64; o <<= 1) {
        float u = __shfl_up(v, o);
        if (lane >= o) v += u;
    }
    __shared__ float wsum, stot;
    if (j == 63) wsum = v;
    __syncthreads();
    float ac = (j >= 64) ? v + wsum : v;
    if (j == 127) stot = ac;
    __syncthreads();
    float asum = stot;
    size_t base = (size_t)bch * CHK;
    dtbuf[base + j] = dt;
    acum[base + j] = ac;
    dsbuf[base + j] = __expf(asum - ac) * dt;
    if (j == 0) decbuf[bch] = __expf(asum);
}

// ---------------- F1: fused scores + M + y_diag(+D*xh) + chunk-state ----------------
// grid (NH, 32 bc); 512 threads (8 waves). Wave w: scores tile-row w;
// PV: p-half (w>>2), i-quarter (w&3); state: n-tile (w&3).
__global__ __launch_bounds__(512, 4) void ssd1_kernel(
    const ushort* __restrict__ xc, const float* __restrict__ acg,
    const float* __restrict__ dtg, const float* __restrict__ dsg,
    const float* __restrict__ Dp, float* __restrict__ y, float* __restrict__ S)
{
    __shared__ ushort Mb[128 * 128];   // union: Cs=[0,8192) Bs=[8192,16384); later M (XOR-swz, stride 128)
    __shared__ ushort xhT[64 * 136];   // xhT[p][j], XOR-swz rows
    __shared__ ushort BmT[64 * 136];   // BmT[n][j], XOR-swz rows
    __shared__ float sAc[128], sDt[128], sDs[128];

    int hh = blockIdx.x, bc = blockIdx.y;
    int tid = threadIdx.x, lane = tid & 63, w = tid >> 6;
    int l15 = lane & 15, lq = lane >> 4;
    int bch = bc * NH + hh;
    const size_t xbase = (size_t)(bc * CHK) * CONVD;
    ushort* Cs = Mb;
    ushort* Bs = Mb + 8192;

    // stage Cs[128 i][64 n], Bs[128 j][64 n] via gload_lds (swizzled source)
#pragma unroll
    for (int t = 0; t < 2; t++) {
        int cbase = t * 512 + w * 64;
        int chunk = cbase + lane;
        int row = chunk >> 3, s = chunk & 7;
        int kc = s ^ (row & 7);
        GLOAD_LDS16(xc + xbase + (size_t)row * CONVD + DI + DSTATE + kc * 8, Cs + (size_t)cbase * 8);
        GLOAD_LDS16(xc + xbase + (size_t)row * CONVD + DI + kc * 8, Bs + (size_t)cbase * 8);
    }
    // stage xhT[p][j], BmT[n][j] transposed+swizzled (reg scatter)
    {
        int j = tid & 127, pc = tid >> 7;    // pc: 0..3
#pragma unroll
        for (int it = 0; it < 2; it++) {
            int pc8 = pc * 2 + it;
            s16x8 vx = *(const s16x8*)(xc + xbase + (size_t)j * CONVD + hh * HD + pc8 * 8);
            s16x8 vb = *(const s16x8*)(xc + xbase + (size_t)j * CONVD + DI + pc8 * 8);
#pragma unroll
            for (int e = 0; e < 8; e++) {
                int R = pc8 * 8 + e;
                int off = R * 136 + (((j >> 3) ^ (R & 7)) << 3) + (j & 7);
                xhT[off] = (ushort)vx[e];
                BmT[off] = (ushort)vb[e];
            }
        }
    }
    if (tid < 128) {
        sAc[tid] = acg[(size_t)bch * CHK + tid];
        sDt[tid] = dtg[(size_t)bch * CHK + tid];
        sDs[tid] = dsg[(size_t)bch * CHK + tid];
    }
    __syncthreads();

    // scores tile-row w: rows i in [w*16, w*16+16), all 8 j-tiles
    f32x4 acc_s[8] = {};
    {
        int row = w * 16 + l15;
#pragma unroll
        for (int kh = 0; kh < 2; kh++) {
            int sl = (kh * 4 + lq) ^ (row & 7);
            s16x8 av = *(const s16x8*)(Cs + row * 64 + sl * 8);
#pragma unroll
            for (int nj = 0; nj < 8; nj++) {
                int jr = nj * 16 + l15;
                int sl2 = (kh * 4 + lq) ^ (jr & 7);
                s16x8 bv = *(const s16x8*)(Bs + jr * 64 + sl2 * 8);
                acc_s[nj] = MFMA_BF16(av, bv, acc_s[nj]);
            }
        }
    }
    __syncthreads();   // all reads of Cs/Bs done before M overlay

    // M-build: wave w owns rows i in [w*16,+16). dense nj<w, tri nj==w, one zero tile nj==w+1
#pragma unroll
    for (int nj = 0; nj < 8; nj++) {
        int j = nj * 16 + l15;
        int slot = ((((w * 16 + lq * 4) & 7) ^ (j >> 3)) << 3) | (j & 7);  // i&7 == (lq*4+r)&7; recompute per r below
        (void)slot;
        if (nj < w) {
            float acj = sAc[j], dtj = sDt[j];
#pragma unroll
            for (int r = 0; r < 4; r++) {
                int i = w * 16 + lq * 4 + r;
                float v = acc_s[nj][r] * __expf(sAc[i] - acj) * dtj;
                Mb[i * 128 + ((((i & 7) ^ (j >> 3)) << 3) | (j & 7))] = f2bf(v);
            }
        } else if (nj == w) {
            float acj = sAc[j], dtj = sDt[j];
#pragma unroll
            for (int r = 0; r < 4; r++) {
                int i = w * 16 + lq * 4 + r;
                float v = (j <= i) ? acc_s[nj][r] * __expf(sAc[i] - acj) * dtj : 0.0f;
                Mb[i * 128 + ((((i & 7) ^ (j >> 3)) << 3) | (j & 7))] = f2bf(v);
            }
        } else if (nj == w + 1) {
#pragma unroll
            for (int r = 0; r < 4; r++) {
                int i = w * 16 + lq * 4 + r;
                Mb[i * 128 + ((((i & 7) ^ (j >> 3)) << 3) | (j & 7))] = 0;
            }
        }
    }
    __syncthreads();

    // PV + state. Wave w: p in [ph*32,+32) (2 tiles), PV i in [iq*32,+32) (2 tiles, ks<=iq),
    // state n-tile = iq (full 4 ks).
    int ph = w >> 2, iq = w & 3;
    f32x4 acc_y[2][2] = {};
    f32x4 acc_st[2] = {};
    int nn = iq * 16 + l15;
#pragma unroll
    for (int ks = 0; ks < 4; ks++) {
        int cj = ks * 4 + lq;
        int j0 = ks * 32 + lq * 8;
        s16x8 axh[2], axs[2];
#pragma unroll
        for (int m = 0; m < 2; m++) {
            int p = ph * 32 + m * 16 + l15;
            axh[m] = *(const s16x8*)(xhT + p * 136 + ((cj ^ (p & 7)) << 3));
            s16x8 r;
#pragma unroll
            for (int e = 0; e < 8; e++)
                r[e] = (short)f2bf(bf2f((ushort)axh[m][e]) * sDs[j0 + e]);
            axs[m] = r;
        }
        s16x8 bb = *(const s16x8*)(BmT + nn * 136 + ((cj ^ (nn & 7)) << 3));
#pragma unroll
        for (int m = 0; m < 2; m++)
            acc_st[m] = MFMA_BF16(axs[m], bb, acc_st[m]);
        if (ks <= iq) {
            s16x8 bm_[2];
#pragma unroll
            for (int n = 0; n < 2; n++) {
                int i = iq * 32 + n * 16 + l15;
                bm_[n] = *(const s16x8*)(Mb + i * 128 + ((cj ^ (i & 7)) << 3));
            }
#pragma unroll
            for (int m = 0; m < 2; m++)
#pragma unroll
                for (int n = 0; n < 2; n++)
                    acc_y[m][n] = MFMA_BF16(axh[m], bm_[n], acc_y[m][n]);
        }
    }

    // epilogue
    float Dh = Dp[hh];
#pragma unroll
    for (int m = 0; m < 2; m++) {
        int p0 = ph * 32 + m * 16 + lq * 4;
#pragma unroll
        for (int n = 0; n < 2; n++) {
            int i = iq * 32 + n * 16 + l15;
            f32x4 v = acc_y[m][n];
#pragma unroll
            for (int r = 0; r < 4; r++) {
                int p = p0 + r;
                v[r] += Dh * bf2f(xhT[p * 136 + ((((p & 7) ^ (i >> 3)) << 3) | (i & 7))]);
            }
            *(f32x4*)&y[(size_t)(bc * CHK + i) * DI + hh * HD + p0] = v;
        }
#pragma unroll
        for (int r = 0; r < 4; r++)
            S[(size_t)bch * 4096 + (size_t)(p0 + r) * 64 + nn] = acc_st[m][r];
    }
}

// ---------------- sequential scan over chunks ----------------
__global__ void scan_kernel(const float* __restrict__ S, const float* __restrict__ decbuf,
                            float* __restrict__ hs) {
    int g = blockIdx.x * 256 + threadIdx.x;
    int n = g & 63, p = (g >> 6) & 63, hh = (g >> 12) & 15, b = g >> 16;
    float state = 0.0f;
#pragma unroll
    for (int c = 0; c < NCH; c++) {
        int bch = (b * NCH + c) * NH + hh;
        size_t idx = (size_t)bch * 4096 + p * 64 + n;
        hs[idx] = state;
        state = state * decbuf[bch] + S[idx];
    }
}

// ---------------- F2: y += exp(ac_i) * (C @ hs^T)  via MFMA, transposed output ------
__global__ __launch_bounds__(256) void ssd2_kernel(
    const ushort* __restrict__ xc, const float* __restrict__ hsg,
    const float* __restrict__ acg, float* __restrict__ y)
{
    __shared__ ushort Cs[128 * 64];
    __shared__ ushort Hs[64 * 64];
    __shared__ float sAc[128];
    int hh = blockIdx.x, bc = blockIdx.y;
    int tid = threadIdx.x, lane = tid & 63, wid = tid >> 6;
    int wr = wid >> 1, wc = wid & 1, l15 = lane & 15, lq = lane >> 4;
    int bch = bc * NH + hh;
    const size_t xbase = (size_t)(bc * CHK) * CONVD;
#pragma unroll
    for (int t = 0; t < 4; t++) {
        int cbase = t * 256 + wid * 64;
        int chunk = cbase + lane;
        int row = chunk >> 3, s = chunk & 7;
        int kc = s ^ (row & 7);
        GLOAD_LDS16(xc + xbase + (size_t)row * CONVD + DI + DSTATE + kc * 8, Cs + (size_t)cbase * 8);
    }
#pragma unroll
    for (int t = 0; t < 2; t++) {
        int chunk = t * 256 + tid;
        int p = chunk >> 3, s = chunk & 7;
        int kc = s ^ (p & 7);
        const float* src = hsg + (size_t)bch * 4096 + p * 64 + kc * 8;
        ushort* dst = Hs + p * 64 + s * 8;
#pragma unroll
        for (int e = 0; e < 8; e++) dst[e] = f2bf(src[e]);
    }
    if (tid < 128) sAc[tid] = acg[(size_t)bch * CHK + tid];
    __syncthreads();
    f32x4 acc[2][4] = {};
#pragma unroll
    for (int kh = 0; kh < 2; kh++) {
        s16x8 av[2], bv[4];
#pragma unroll
        for (int m = 0; m < 2; m++) {
            int p = wr * 32 + m * 16 + l15;
            int sl = (kh * 4 + lq) ^ (p & 7);
            av[m] = *(const s16x8*)(Hs + p * 64 + sl * 8);
        }
#pragma unroll
        for (int n = 0; n < 4; n++) {
            int i = wc * 64 + n * 16 + l15;
            int sl = (kh * 4 + lq) ^ (i & 7);
            bv[n] = *(const s16x8*)(Cs + i * 64 + sl * 8);
        }
#pragma unroll
        for (int m = 0; m < 2; m++)
#pragma unroll
            for (int n = 0; n < 4; n++)
                acc[m][n] = MFMA_BF16(av[m], bv[n], acc[m][n]);
    }
#pragma unroll
    for (int m = 0; m < 2; m++) {
        int p0 = wr * 32 + m * 16 + lq * 4;
#pragma unroll
        for (int n = 0; n < 4; n++) {
            int i = wc * 64 + n * 16 + l15;
            float e = __expf(sAc[i]);
            float* dst = &y[(size_t)(bc * CHK + i) * DI + hh * HD + p0];
            f32x4 v = *(f32x4*)dst;
#pragma unroll
            for (int r = 0; r < 4; r++) v[r] += e * acc[m][n][r];
            *(f32x4*)dst = v;
        }
    }
}

extern "C" void kernel_launch(void* const* d_in, const int* in_sizes, int n_in,
                              void* d_out, int out_size, void* d_ws, size_t ws_size,
                              hipStream_t stream) {
    const float* x        = (const float*)d_in[0];
    const float* W_embed  = (const float*)d_in[1];
    const float* rms_w    = (const float*)d_in[2];
    const float* in_w     = (const float*)d_in[3];
    const float* conv_w   = (const float*)d_in[4];
    const float* conv_b   = (const float*)d_in[5];
    const float* dt_bias  = (const float*)d_in[6];
    const float* A_log    = (const float*)d_in[7];
    const float* D_param  = (const float*)d_in[8];
    const float* gnorm_w  = (const float*)d_in[9];
    const float* out_w    = (const float*)d_in[10];
    const float* fnorm_w  = (const float*)d_in[11];
    const float* head_w   = (const float*)d_in[12];
    const float* head_b   = (const float*)d_in[13];
    float* out = (float*)d_out;

    char* p = (char*)d_ws;
    auto alloc = [&](size_t bytes) { char* r = p; p += (bytes + 255) & ~(size_t)255; return r; };

    float*  h_buf   = (float*)alloc((size_t)BL * DM * 4);
    float*  y_buf   = (float*)alloc((size_t)BL * DI * 4);
    float*  S_buf   = (float*)alloc((size_t)BSZ * NCH * NH * HD * DSTATE * 4);
    float*  hs_buf  = (float*)alloc((size_t)BSZ * NCH * NH * HD * DSTATE * 4);
    float*  dt_buf  = (float*)alloc((size_t)BSZ * NCH * NH * CHK * 4);
    float*  ac_buf  = (float*)alloc((size_t)BSZ * NCH * NH * CHK * 4);
    float*  ds_buf  = (float*)alloc((size_t)BSZ * NCH * NH * CHK * 4);
    float*  dec_buf = (float*)alloc((size_t)BSZ * NCH * NH * 4);
    float*  dtraw   = (float*)alloc((size_t)BL * 16 * 4);
    ushort* xn_bf   = (ushort*)alloc((size_t)BL * DM * 2);
    ushort* zx_bf   = (ushort*)alloc((size_t)BL * DIP * 2);
    ushort* xc_bf   = (ushort*)alloc((size_t)BL * CONVD * 2);
    ushort* y_bf    = (ushort*)alloc((size_t)BL * DI * 2);
    ushort* headT   = (ushort*)alloc((size_t)128 * DM * 2);

    size_t in_full  = (size_t)NLAYER * NPAD_IN * DM * 2;
    size_t out_full = (size_t)NLAYER * DM * DI * 2;
    size_t used = (size_t)(p - (char*)d_ws);
    bool full = (used + in_full + out_full + 4096) <= ws_size;
    ushort* inT  = (ushort*)alloc(full ? in_full  : (size_t)NPAD_IN * DM * 2);
    ushort* outT = (ushort*)alloc(full ? out_full : (size_t)DM * DI * 2);

    embed_kernel<<<BL, 256, 0, stream>>>(x, W_embed, h_buf);
    convT_kernel<<<dim3(2, DM / 64, 1), 256, 0, stream>>>(head_w, headT, DM, 30, 128);
    if (full) {
        convT_kernel<<<dim3(NPAD_IN / 64, DM / 64, NLAYER), 256, 0, stream>>>(
            in_w, inT, DM, DIP, NPAD_IN);
        convT_kernel<<<dim3(DM / 64, DI / 64, NLAYER), 256, 0, stream>>>(
            out_w, outT, DI, DM, DM);
    }

    for (int l = 0; l < NLAYER; l++) {
        const float* rw = rms_w + (size_t)l * DM;
        const float* cw = conv_w + (size_t)l * CONVD * 4;
        const float* cb = conv_b + (size_t)l * CONVD;
        const float* db = dt_bias + (size_t)l * NH;
        const float* al = A_log + (size_t)l * NH;
        const float* dp = D_param + (size_t)l * NH;
        const float* gw = gnorm_w + (size_t)l * DI;

        ushort* inT_l  = full ? inT  + (size_t)l * NPAD_IN * DM : inT;
        ushort* outT_l = full ? outT + (size_t)l * DM * DI      : outT;
        if (!full) {
            convT_kernel<<<dim3(NPAD_IN / 64, DM / 64, 1), 256, 0, stream>>>(
                in_w + (size_t)l * DM * DIP, inT_l, DM, DIP, NPAD_IN);
            convT_kernel<<<dim3(DM / 64, DI / 64, 1), 256, 0, stream>>>(
                out_w + (size_t)l * DI * DM, outT_l, DI, DM, DM);
        }

        rmsnorm512_bf_kernel<<<BL, 256, 0, stream>>>(h_buf, rw, xn_bf);
        gemm_bf16_kernel<0, 4><<<dim3(NPAD_IN / 128, BL / 128), 256, 0, stream>>>(
            xn_bf, inT_l, zx_bf, nullptr, dtraw, DIP, DIP, DM);
        conv_kernel<<<(BL * CONVD / 8) / 256, 256, 0, stream>>>(zx_bf, cw, cb, xc_bf);
        dtscan_kernel<<<BSZ * NCH * NH, 128, 0, stream>>>(dtraw, db, al, dt_buf, ac_buf,
                                                          ds_buf, dec_buf);
        ssd1_kernel<<<dim3(NH, BSZ * NCH), 512, 0, stream>>>(xc_bf, ac_buf, dt_buf, ds_buf,
                                                             dp, y_buf, S_buf);
        scan_kernel<<<(BSZ * NH * HD * DSTATE) / 256, 256, 0, stream>>>(S_buf, dec_buf,
                                                                        hs_buf);
        ssd2_kernel<<<dim3(NH, BSZ * NCH), 256, 0, stream>>>(xc_bf, hs_buf, ac_buf, y_buf);
        gatenorm_kernel<<<BL, 256, 0, stream>>>(y_buf, zx_bf, gw, y_bf);
        gemm_bf16_kernel<1, 2><<<dim3(DM / 128, BL / 64), 256, 0, stream>>>(
            y_bf, outT_l, nullptr, h_buf, nullptr, DM, DM, DI);
    }

    rmsnorm512_bf_kernel<<<BL, 256, 0, stream>>>(h_buf, fnorm_w, xn_bf);
    gemm_bf16_kernel<2, 4><<<dim3(1, BL / 128), 256, 0, stream>>>(
        xn_bf, headT, nullptr, out, (float*)head_b, 30, 30, DM);
}

// Round 5
// 1732.250 us; speedup vs baseline: 3.1851x; 1.0318x over previous
//
#include <hip/hip_runtime.h>
#include <math.h>

#define DM 512
#define DSTATE 64
#define HD 64
#define DI 1024
#define NH 16
#define CONVD 1152
#define DIP 2192
#define CHK 128
#define NCH 16
#define BSZ 2
#define SEQL 2048
#define BL (BSZ*SEQL)
#define NLAYER 12
#define EPSF 1e-5f
#define NPAD_IN 2304

typedef __attribute__((ext_vector_type(4))) float f32x4;
typedef __attribute__((ext_vector_type(8))) short s16x8;

__device__ __forceinline__ float bf2f(ushort u) {
    union { unsigned int i; float f; } v; v.i = ((unsigned int)u) << 16; return v.f;
}
__device__ __forceinline__ ushort f2bf(float f) {
    union { float f; unsigned int u; } v; v.f = f;
    unsigned int u = v.u;
    unsigned int r = (u + 0x7fffu + ((u >> 16) & 1u)) >> 16;
    return (ushort)r;
}

#define GLOAD_LDS16(gptr, lptr) __builtin_amdgcn_global_load_lds( \
    (const __attribute__((address_space(1))) void*)(gptr), \
    (__attribute__((address_space(3))) void*)(lptr), 16, 0, 0)

#define MFMA_BF16(a, b, c) __builtin_amdgcn_mfma_f32_16x16x32_bf16(a, b, c, 0, 0, 0)

// ---------------- embed + nerf positional encoding ----------------
__global__ void embed_kernel(const float* __restrict__ x, const float* __restrict__ W,
                             float* __restrict__ h) {
    int tok = blockIdx.x;
    float xe[3];
#pragma unroll
    for (int e = 0; e < 3; e++) {
        float v = x[tok * 3 + e];
        xe[e] = (v == -100.0f) ? 0.0f : v;
    }
    for (int d = threadIdx.x; d < DM; d += blockDim.x) {
        float pe = 0.0f;
        if (d < 510) {
            int e = d / 170, r = d % 170;
            int is_sin = (r < 85);
            int k = is_sin ? r : r - 85;
            float ang = xe[e] * ldexpf(1.0f, k);   // exact in fp32
            double dv = is_sin ? sin((double)ang) : cos((double)ang);
            pe = (float)dv;
        }
        float acc = pe;
#pragma unroll
        for (int e = 0; e < 3; e++) acc += xe[e] * W[e * DM + d];
        h[(size_t)tok * DM + d] = acc;
    }
}

// ---------------- rmsnorm width=512 -> bf16 out ----------------
__global__ __launch_bounds__(256) void rmsnorm512_bf_kernel(const float* __restrict__ in,
                                                            const float* __restrict__ w,
                                                            ushort* __restrict__ out) {
    int tok = blockIdx.x;
    const float* row = in + (size_t)tok * DM;
    float v0 = row[threadIdx.x];
    float v1 = row[threadIdx.x + 256];
    float ss = v0 * v0 + v1 * v1;
    for (int o = 32; o; o >>= 1) ss += __shfl_down(ss, o);
    __shared__ float sbuf[4];
    if ((threadIdx.x & 63) == 0) sbuf[threadIdx.x >> 6] = ss;
    __syncthreads();
    if (threadIdx.x == 0) {
        float s = sbuf[0] + sbuf[1] + sbuf[2] + sbuf[3];
        sbuf[0] = rsqrtf(s / (float)DM + EPSF);
    }
    __syncthreads();
    float rs = sbuf[0];
    ushort* orow = out + (size_t)tok * DM;
    orow[threadIdx.x] = f2bf(v0 * rs * w[threadIdx.x]);
    orow[threadIdx.x + 256] = f2bf(v1 * rs * w[threadIdx.x + 256]);
}

// ---------------- gate silu(z)*y + rmsnorm (width 1024) -> bf16 --------
__global__ __launch_bounds__(256) void gatenorm_kernel(const float* __restrict__ y,
                                                       const ushort* __restrict__ zx,
                                                       const float* __restrict__ gw,
                                                       ushort* __restrict__ yb) {
    int tok = blockIdx.x;
    const ushort* zrow = zx + (size_t)tok * DIP;
    const float* yrow = y + (size_t)tok * DI;
    float v[4];
    float ss = 0.0f;
#pragma unroll
    for (int k = 0; k < 4; k++) {
        int d = threadIdx.x + k * 256;
        float z = bf2f(zrow[d]);
        float s = z / (1.0f + __expf(-z));
        float val = yrow[d] * s;
        v[k] = val;
        ss += val * val;
    }
    for (int o = 32; o; o >>= 1) ss += __shfl_down(ss, o);
    __shared__ float sbuf[4];
    if ((threadIdx.x & 63) == 0) sbuf[threadIdx.x >> 6] = ss;
    __syncthreads();
    if (threadIdx.x == 0) {
        float s = sbuf[0] + sbuf[1] + sbuf[2] + sbuf[3];
        sbuf[0] = rsqrtf(s / (float)DI + EPSF);
    }
    __syncthreads();
    float rs = sbuf[0];
    ushort* ob = yb + (size_t)tok * DI;
#pragma unroll
    for (int k = 0; k < 4; k++) {
        int d = threadIdx.x + k * 256;
        ob[d] = f2bf(v[k] * rs * gw[d]);
    }
}

// ---------------- weight convert+transpose: w[L][K][N] f32 -> wT[L][Npad][K] bf16 ----
__global__ __launch_bounds__(256) void convT_kernel(const float* __restrict__ w,
                                                    ushort* __restrict__ wT,
                                                    int K, int N, int Npad) {
    __shared__ ushort tile[64][65];
    int l = blockIdx.z;
    int n0 = blockIdx.x * 64, k0 = blockIdx.y * 64;
    const float* src = w + (size_t)l * K * N;
    ushort* dst = wT + (size_t)l * Npad * K;
    int tid = threadIdx.x;
#pragma unroll
    for (int t = 0; t < 16; t++) {
        int idx = tid + t * 256;
        int r = idx >> 6, c = idx & 63;
        float v = (n0 + c < N) ? src[(size_t)(k0 + r) * N + n0 + c] : 0.0f;
        tile[c][r] = f2bf(v);
    }
    __syncthreads();
#pragma unroll
    for (int t = 0; t < 16; t++) {
        int idx = tid + t * 256;
        int r = idx >> 6, c = idx & 63;
        dst[(size_t)(n0 + r) * K + k0 + c] = tile[r][c];
    }
}

// ---------------- bf16 MFMA GEMM: C[M,N] = A[M,K] * BT[N,K]^T ----------------
// BM = MT*32 x BN=128 tile, BK=64, 4 waves (2x2), double-buffered prefetch:
//   stage(b0); bar; loop { stage(b^1, kt+1); compute(b, kt); bar }
// (the __syncthreads drain lands the prefetch; loads fly during MFMA)
// MODE 0: bf16 store + dt sidecar; MODE 1: fp32 accumulate; MODE 2: fp32 + bias (head)
template <int MODE, int MT>
__global__ __launch_bounds__(256) void gemm_bf16_kernel(
    const ushort* __restrict__ A, const ushort* __restrict__ BT,
    ushort* __restrict__ Cb, float* __restrict__ Cf, float* __restrict__ aux,
    int N, int Nstride, int K)
{
    __shared__ ushort As[2][MT * 32 * 64];
    __shared__ ushort Bs[2][128 * 64];
    int bm = blockIdx.y * (MT * 32), bn = blockIdx.x * 128;
    int tid = threadIdx.x;
    int lane = tid & 63, wid = tid >> 6;
    int wr = wid >> 1, wc = wid & 1;
    int r15 = lane & 15, q = lane >> 4;
    f32x4 acc[MT][4] = {};
    const int nkt = K >> 6;

    // stage tile kt into buffer b
#define STAGE_GEMM(b, kt) do {                                              \
        int k0s = (kt) << 6;                                                \
        _Pragma("unroll")                                                   \
        for (int t = 0; t < MT; t++) {                                      \
            int cbase = wid * (MT * 64) + t * 64;                           \
            int chunk = cbase + lane;                                       \
            int row = chunk >> 3, s = chunk & 7;                            \
            int kc = s ^ (row & 7);                                         \
            GLOAD_LDS16(A + (size_t)(bm + row) * K + k0s + kc * 8,          \
                        &As[b][cbase * 8]);                                 \
        }                                                                   \
        _Pragma("unroll")                                                   \
        for (int t = 0; t < 4; t++) {                                       \
            int cbase = wid * 256 + t * 64;                                 \
            int chunk = cbase + lane;                                       \
            int row = chunk >> 3, s = chunk & 7;                            \
            int kc = s ^ (row & 7);                                         \
            GLOAD_LDS16(BT + (size_t)(bn + row) * K + k0s + kc * 8,         \
                        &Bs[b][cbase * 8]);                                 \
        }                                                                   \
    } while (0)

    STAGE_GEMM(0, 0);
    __syncthreads();
    for (int kt = 0; kt < nkt; kt++) {
        int cur = kt & 1;
        if (kt + 1 < nkt) STAGE_GEMM(cur ^ 1, kt + 1);
        const ushort* Ac = As[cur];
        const ushort* Bc = Bs[cur];
#pragma unroll
        for (int kh = 0; kh < 2; kh++) {
            s16x8 av[MT], bv[4];
#pragma unroll
            for (int m = 0; m < MT; m++) {
                int row = wr * (MT * 16) + m * 16 + r15;
                int s = (kh * 4 + q) ^ (row & 7);
                av[m] = *(const s16x8*)(Ac + row * 64 + s * 8);
            }
#pragma unroll
            for (int n = 0; n < 4; n++) {
                int row = wc * 64 + n * 16 + r15;
                int s = (kh * 4 + q) ^ (row & 7);
                bv[n] = *(const s16x8*)(Bc + row * 64 + s * 8);
            }
#pragma unroll
            for (int m = 0; m < MT; m++)
#pragma unroll
                for (int n = 0; n < 4; n++)
                    acc[m][n] = MFMA_BF16(av[m], bv[n], acc[m][n]);
        }
        __syncthreads();   // drains prefetch (vmcnt0) + guards buffer reuse
    }
#undef STAGE_GEMM

#pragma unroll
    for (int m = 0; m < MT; m++) {
        int row0 = bm + wr * (MT * 16) + m * 16 + q * 4;
#pragma unroll
        for (int n = 0; n < 4; n++) {
            int col = bn + wc * 64 + n * 16 + r15;
#pragma unroll
            for (int r = 0; r < 4; r++) {
                float v = acc[m][n][r];
                int rr = row0 + r;
                if (MODE == 0) {
                    if (col < N) {
                        Cb[(size_t)rr * Nstride + col] = f2bf(v);
                        if (col >= DI + CONVD) aux[(size_t)rr * 16 + (col - DI - CONVD)] = v;
                    }
                } else if (MODE == 1) {
                    Cf[(size_t)rr * Nstride + col] += v;
                } else {
                    if (col < N) Cf[(size_t)rr * Nstride + col] = v + aux[col];
                }
            }
        }
    }
}

// ---------------- causal depthwise conv (d=4) + bias + silu, 8 ch/thread ------
__global__ void conv_kernel(const ushort* __restrict__ zx, const float* __restrict__ cw,
                            const float* __restrict__ cb, ushort* __restrict__ xc) {
    int gid = blockIdx.x * 256 + threadIdx.x;
    int cu = gid % (CONVD / 8);
    int lg = gid / (CONVD / 8);
    int c8 = cu * 8;
    int l = lg % SEQL;
    float acc[8];
#pragma unroll
    for (int e = 0; e < 8; e++) acc[e] = cb[c8 + e];
#pragma unroll
    for (int k = 0; k < 4; k++) {
        if (l + k - 3 >= 0) {
            s16x8 v = *(const s16x8*)(zx + (size_t)(lg + k - 3) * DIP + DI + c8);
#pragma unroll
            for (int e = 0; e < 8; e++) acc[e] += bf2f((ushort)v[e]) * cw[(c8 + e) * 4 + k];
        }
    }
    s16x8 o;
#pragma unroll
    for (int e = 0; e < 8; e++) {
        float s = acc[e] / (1.0f + __expf(-acc[e]));
        o[e] = (short)f2bf(s);
    }
    *(s16x8*)(xc + (size_t)lg * CONVD + c8) = o;
}

// ---------------- F1: fused dt-scan + scores + M + y_diag(+D*xh) + chunk-state ------
// grid (NH, 32 bc); 512 threads (8 waves). Threads 0-127 additionally compute
// softplus(dt)+cumsum inline (was dtscan_kernel) -> sDt/sAc/sDs in LDS.
__global__ __launch_bounds__(512, 4) void ssd1_kernel(
    const ushort* __restrict__ xc, const float* __restrict__ dtraw,
    const float* __restrict__ dt_bias, const float* __restrict__ A_log,
    const float* __restrict__ Dp, float* __restrict__ acg,
    float* __restrict__ decbuf, float* __restrict__ y, float* __restrict__ S)
{
    __shared__ ushort Mb[128 * 128];   // union: Cs=[0,8192) Bs=[8192,16384); later M (XOR-swz)
    __shared__ ushort xhT[64 * 136];   // xhT[p][j], XOR-swz rows
    __shared__ ushort BmT[64 * 136];   // BmT[n][j], XOR-swz rows
    __shared__ float sAc[128], sDt[128], sDs[128];
    __shared__ float s_wsum, s_stot;

    int hh = blockIdx.x, bc = blockIdx.y;
    int tid = threadIdx.x, lane = tid & 63, w = tid >> 6;
    int l15 = lane & 15, lq = lane >> 4;
    int bch = bc * NH + hh;
    const size_t xbase = (size_t)(bc * CHK) * CONVD;
    ushort* Cs = Mb;
    ushort* Bs = Mb + 8192;

    // stage Cs[128 i][64 n], Bs[128 j][64 n] via gload_lds (swizzled source)
#pragma unroll
    for (int t = 0; t < 2; t++) {
        int cbase = t * 512 + w * 64;
        int chunk = cbase + lane;
        int row = chunk >> 3, s = chunk & 7;
        int kc = s ^ (row & 7);
        GLOAD_LDS16(xc + xbase + (size_t)row * CONVD + DI + DSTATE + kc * 8, Cs + (size_t)cbase * 8);
        GLOAD_LDS16(xc + xbase + (size_t)row * CONVD + DI + kc * 8, Bs + (size_t)cbase * 8);
    }
    // stage xhT[p][j], BmT[n][j] transposed+swizzled (reg scatter)
    {
        int j = tid & 127, pc = tid >> 7;    // pc: 0..3
#pragma unroll
        for (int it = 0; it < 2; it++) {
            int pc8 = pc * 2 + it;
            s16x8 vx = *(const s16x8*)(xc + xbase + (size_t)j * CONVD + hh * HD + pc8 * 8);
            s16x8 vb = *(const s16x8*)(xc + xbase + (size_t)j * CONVD + DI + pc8 * 8);
#pragma unroll
            for (int e = 0; e < 8; e++) {
                int R = pc8 * 8 + e;
                int off = R * 136 + (((j >> 3) ^ (R & 7)) << 3) + (j & 7);
                xhT[off] = (ushort)vx[e];
                BmT[off] = (ushort)vb[e];
            }
        }
    }
    // dt-scan part 1: softplus + wave-local inclusive scan (threads 0-127)
    float v_scan = 0.0f, dt_v = 0.0f;
    if (tid < 128) {
        float raw = dtraw[(size_t)(bc * CHK + tid) * 16 + hh] + dt_bias[hh];
        dt_v = raw > 0.0f ? raw + log1pf(__expf(-raw)) : log1pf(__expf(raw));
        v_scan = dt_v * (-__expf(A_log[hh]));
#pragma unroll
        for (int o = 1; o < 64; o <<= 1) {
            float u = __shfl_up(v_scan, o);
            if (lane >= o) v_scan += u;
        }
        if (tid == 63) s_wsum = v_scan;
    }
    __syncthreads();   // B1: staging landed (vmcnt+lgkm drain), s_wsum ready

    // scores (all waves) + dt-scan part 2 (threads 0-127)
    float ac_v = 0.0f;
    if (tid < 128) {
        ac_v = (tid >= 64) ? v_scan + s_wsum : v_scan;
        if (tid == 127) s_stot = ac_v;
    }
    f32x4 acc_s[8] = {};
    {
        int row = w * 16 + l15;
#pragma unroll
        for (int kh = 0; kh < 2; kh++) {
            int sl = (kh * 4 + lq) ^ (row & 7);
            s16x8 av = *(const s16x8*)(Cs + row * 64 + sl * 8);
#pragma unroll
            for (int nj = 0; nj < 8; nj++) {
                int jr = nj * 16 + l15;
                int sl2 = (kh * 4 + lq) ^ (jr & 7);
                s16x8 bv = *(const s16x8*)(Bs + jr * 64 + sl2 * 8);
                acc_s[nj] = MFMA_BF16(av, bv, acc_s[nj]);
            }
        }
    }
    __syncthreads();   // B2: s_stot ready, scores reads of Cs/Bs done

    if (tid < 128) {
        float asum = s_stot;
        sAc[tid] = ac_v;
        sDt[tid] = dt_v;
        sDs[tid] = __expf(asum - ac_v) * dt_v;
        acg[(size_t)bch * CHK + tid] = ac_v;
        if (tid == 0) decbuf[bch] = __expf(asum);
    }
    __syncthreads();   // B3: sAc/sDt/sDs ready; Mb region free for overlay

    // M-build: wave w owns rows i in [w*16,+16). dense nj<w, tri nj==w, zero tile nj==w+1
#pragma unroll
    for (int nj = 0; nj < 8; nj++) {
        int j = nj * 16 + l15;
        if (nj < w) {
            float acj = sAc[j], dtj = sDt[j];
#pragma unroll
            for (int r = 0; r < 4; r++) {
                int i = w * 16 + lq * 4 + r;
                float v = acc_s[nj][r] * __expf(sAc[i] - acj) * dtj;
                Mb[i * 128 + ((((i & 7) ^ (j >> 3)) << 3) | (j & 7))] = f2bf(v);
            }
        } else if (nj == w) {
            float acj = sAc[j], dtj = sDt[j];
#pragma unroll
            for (int r = 0; r < 4; r++) {
                int i = w * 16 + lq * 4 + r;
                float v = (j <= i) ? acc_s[nj][r] * __expf(sAc[i] - acj) * dtj : 0.0f;
                Mb[i * 128 + ((((i & 7) ^ (j >> 3)) << 3) | (j & 7))] = f2bf(v);
            }
        } else if (nj == w + 1) {
#pragma unroll
            for (int r = 0; r < 4; r++) {
                int i = w * 16 + lq * 4 + r;
                Mb[i * 128 + ((((i & 7) ^ (j >> 3)) << 3) | (j & 7))] = 0;
            }
        }
    }
    __syncthreads();   // B4

    // PV + state. Wave w: p in [ph*32,+32), PV i in [iq*32,+32) (ks<=iq), state n-tile = iq.
    int ph = w >> 2, iq = w & 3;
    f32x4 acc_y[2][2] = {};
    f32x4 acc_st[2] = {};
    int nn = iq * 16 + l15;
#pragma unroll
    for (int ks = 0; ks < 4; ks++) {
        int cj = ks * 4 + lq;
        int j0 = ks * 32 + lq * 8;
        s16x8 axh[2], axs[2];
#pragma unroll
        for (int m = 0; m < 2; m++) {
            int p = ph * 32 + m * 16 + l15;
            axh[m] = *(const s16x8*)(xhT + p * 136 + ((cj ^ (p & 7)) << 3));
            s16x8 r;
#pragma unroll
            for (int e = 0; e < 8; e++)
                r[e] = (short)f2bf(bf2f((ushort)axh[m][e]) * sDs[j0 + e]);
            axs[m] = r;
        }
        s16x8 bb = *(const s16x8*)(BmT + nn * 136 + ((cj ^ (nn & 7)) << 3));
#pragma unroll
        for (int m = 0; m < 2; m++)
            acc_st[m] = MFMA_BF16(axs[m], bb, acc_st[m]);
        if (ks <= iq) {
            s16x8 bm_[2];
#pragma unroll
            for (int n = 0; n < 2; n++) {
                int i = iq * 32 + n * 16 + l15;
                bm_[n] = *(const s16x8*)(Mb + i * 128 + ((cj ^ (i & 7)) << 3));
            }
#pragma unroll
            for (int m = 0; m < 2; m++)
#pragma unroll
                for (int n = 0; n < 2; n++)
                    acc_y[m][n] = MFMA_BF16(axh[m], bm_[n], acc_y[m][n]);
        }
    }

    // epilogue
    float Dh = Dp[hh];
#pragma unroll
    for (int m = 0; m < 2; m++) {
        int p0 = ph * 32 + m * 16 + lq * 4;
#pragma unroll
        for (int n = 0; n < 2; n++) {
            int i = iq * 32 + n * 16 + l15;
            f32x4 v = acc_y[m][n];
#pragma unroll
            for (int r = 0; r < 4; r++) {
                int p = p0 + r;
                v[r] += Dh * bf2f(xhT[p * 136 + ((((p & 7) ^ (i >> 3)) << 3) | (i & 7))]);
            }
            *(f32x4*)&y[(size_t)(bc * CHK + i) * DI + hh * HD + p0] = v;
        }
#pragma unroll
        for (int r = 0; r < 4; r++)
            S[(size_t)bch * 4096 + (size_t)(p0 + r) * 64 + nn] = acc_st[m][r];
    }
}

// ---------------- sequential scan over chunks ----------------
__global__ void scan_kernel(const float* __restrict__ S, const float* __restrict__ decbuf,
                            float* __restrict__ hs) {
    int g = blockIdx.x * 256 + threadIdx.x;
    int n = g & 63, p = (g >> 6) & 63, hh = (g >> 12) & 15, b = g >> 16;
    float state = 0.0f;
#pragma unroll
    for (int c = 0; c < NCH; c++) {
        int bch = (b * NCH + c) * NH + hh;
        size_t idx = (size_t)bch * 4096 + p * 64 + n;
        hs[idx] = state;
        state = state * decbuf[bch] + S[idx];
    }
}

// ---------------- F2: y += exp(ac_i) * (C @ hs^T)  via MFMA, transposed output ------
__global__ __launch_bounds__(256) void ssd2_kernel(
    const ushort* __restrict__ xc, const float* __restrict__ hsg,
    const float* __restrict__ acg, float* __restrict__ y)
{
    __shared__ ushort Cs[128 * 64];
    __shared__ ushort Hs[64 * 64];
    __shared__ float sAc[128];
    int hh = blockIdx.x, bc = blockIdx.y;
    int tid = threadIdx.x, lane = tid & 63, wid = tid >> 6;
    int wr = wid >> 1, wc = wid & 1, l15 = lane & 15, lq = lane >> 4;
    int bch = bc * NH + hh;
    const size_t xbase = (size_t)(bc * CHK) * CONVD;
#pragma unroll
    for (int t = 0; t < 4; t++) {
        int cbase = t * 256 + wid * 64;
        int chunk = cbase + lane;
        int row = chunk >> 3, s = chunk & 7;
        int kc = s ^ (row & 7);
        GLOAD_LDS16(xc + xbase + (size_t)row * CONVD + DI + DSTATE + kc * 8, Cs + (size_t)cbase * 8);
    }
#pragma unroll
    for (int t = 0; t < 2; t++) {
        int chunk = t * 256 + tid;
        int p = chunk >> 3, s = chunk & 7;
        int kc = s ^ (p & 7);
        const float* src = hsg + (size_t)bch * 4096 + p * 64 + kc * 8;
        ushort* dst = Hs + p * 64 + s * 8;
#pragma unroll
        for (int e = 0; e < 8; e++) dst[e] = f2bf(src[e]);
    }
    if (tid < 128) sAc[tid] = acg[(size_t)bch * CHK + tid];
    __syncthreads();
    f32x4 acc[2][4] = {};
#pragma unroll
    for (int kh = 0; kh < 2; kh++) {
        s16x8 av[2], bv[4];
#pragma unroll
        for (int m = 0; m < 2; m++) {
            int p = wr * 32 + m * 16 + l15;
            int sl = (kh * 4 + lq) ^ (p & 7);
            av[m] = *(const s16x8*)(Hs + p * 64 + sl * 8);
        }
#pragma unroll
        for (int n = 0; n < 4; n++) {
            int i = wc * 64 + n * 16 + l15;
            int sl = (kh * 4 + lq) ^ (i & 7);
            bv[n] = *(const s16x8*)(Cs + i * 64 + sl * 8);
        }
#pragma unroll
        for (int m = 0; m < 2; m++)
#pragma unroll
            for (int n = 0; n < 4; n++)
                acc[m][n] = MFMA_BF16(av[m], bv[n], acc[m][n]);
    }
#pragma unroll
    for (int m = 0; m < 2; m++) {
        int p0 = wr * 32 + m * 16 + lq * 4;
#pragma unroll
        for (int n = 0; n < 4; n++) {
            int i = wc * 64 + n * 16 + l15;
            float e = __expf(sAc[i]);
            float* dst = &y[(size_t)(bc * CHK + i) * DI + hh * HD + p0];
            f32x4 v = *(f32x4*)dst;
#pragma unroll
            for (int r = 0; r < 4; r++) v[r] += e * acc[m][n][r];
            *(f32x4*)dst = v;
        }
    }
}

extern "C" void kernel_launch(void* const* d_in, const int* in_sizes, int n_in,
                              void* d_out, int out_size, void* d_ws, size_t ws_size,
                              hipStream_t stream) {
    const float* x        = (const float*)d_in[0];
    const float* W_embed  = (const float*)d_in[1];
    const float* rms_w    = (const float*)d_in[2];
    const float* in_w     = (const float*)d_in[3];
    const float* conv_w   = (const float*)d_in[4];
    const float* conv_b   = (const float*)d_in[5];
    const float* dt_bias  = (const float*)d_in[6];
    const float* A_log    = (const float*)d_in[7];
    const float* D_param  = (const float*)d_in[8];
    const float* gnorm_w  = (const float*)d_in[9];
    const float* out_w    = (const float*)d_in[10];
    const float* fnorm_w  = (const float*)d_in[11];
    const float* head_w   = (const float*)d_in[12];
    const float* head_b   = (const float*)d_in[13];
    float* out = (float*)d_out;

    char* p = (char*)d_ws;
    auto alloc = [&](size_t bytes) { char* r = p; p += (bytes + 255) & ~(size_t)255; return r; };

    float*  h_buf   = (float*)alloc((size_t)BL * DM * 4);
    float*  y_buf   = (float*)alloc((size_t)BL * DI * 4);
    float*  S_buf   = (float*)alloc((size_t)BSZ * NCH * NH * HD * DSTATE * 4);
    float*  hs_buf  = (float*)alloc((size_t)BSZ * NCH * NH * HD * DSTATE * 4);
    float*  ac_buf  = (float*)alloc((size_t)BSZ * NCH * NH * CHK * 4);
    float*  dec_buf = (float*)alloc((size_t)BSZ * NCH * NH * 4);
    float*  dtraw   = (float*)alloc((size_t)BL * 16 * 4);
    ushort* xn_bf   = (ushort*)alloc((size_t)BL * DM * 2);
    ushort* zx_bf   = (ushort*)alloc((size_t)BL * DIP * 2);
    ushort* xc_bf   = (ushort*)alloc((size_t)BL * CONVD * 2);
    ushort* y_bf    = (ushort*)alloc((size_t)BL * DI * 2);
    ushort* headT   = (ushort*)alloc((size_t)128 * DM * 2);

    size_t in_full  = (size_t)NLAYER * NPAD_IN * DM * 2;
    size_t out_full = (size_t)NLAYER * DM * DI * 2;
    size_t used = (size_t)(p - (char*)d_ws);
    bool full = (used + in_full + out_full + 4096) <= ws_size;
    ushort* inT  = (ushort*)alloc(full ? in_full  : (size_t)NPAD_IN * DM * 2);
    ushort* outT = (ushort*)alloc(full ? out_full : (size_t)DM * DI * 2);

    embed_kernel<<<BL, 256, 0, stream>>>(x, W_embed, h_buf);
    convT_kernel<<<dim3(2, DM / 64, 1), 256, 0, stream>>>(head_w, headT, DM, 30, 128);
    if (full) {
        convT_kernel<<<dim3(NPAD_IN / 64, DM / 64, NLAYER), 256, 0, stream>>>(
            in_w, inT, DM, DIP, NPAD_IN);
        convT_kernel<<<dim3(DM / 64, DI / 64, NLAYER), 256, 0, stream>>>(
            out_w, outT, DI, DM, DM);
    }

    for (int l = 0; l < NLAYER; l++) {
        const float* rw = rms_w + (size_t)l * DM;
        const float* cw = conv_w + (size_t)l * CONVD * 4;
        const float* cb = conv_b + (size_t)l * CONVD;
        const float* db = dt_bias + (size_t)l * NH;
        const float* al = A_log + (size_t)l * NH;
        const float* dp = D_param + (size_t)l * NH;
        const float* gw = gnorm_w + (size_t)l * DI;

        ushort* inT_l  = full ? inT  + (size_t)l * NPAD_IN * DM : inT;
        ushort* outT_l = full ? outT + (size_t)l * DM * DI      : outT;
        if (!full) {
            convT_kernel<<<dim3(NPAD_IN / 64, DM / 64, 1), 256, 0, stream>>>(
                in_w + (size_t)l * DM * DIP, inT_l, DM, DIP, NPAD_IN);
            convT_kernel<<<dim3(DM / 64, DI / 64, 1), 256, 0, stream>>>(
                out_w + (size_t)l * DI * DM, outT_l, DI, DM, DM);
        }

        rmsnorm512_bf_kernel<<<BL, 256, 0, stream>>>(h_buf, rw, xn_bf);
        gemm_bf16_kernel<0, 4><<<dim3(NPAD_IN / 128, BL / 128), 256, 0, stream>>>(
            xn_bf, inT_l, zx_bf, nullptr, dtraw, DIP, DIP, DM);
        conv_kernel<<<(BL * CONVD / 8) / 256, 256, 0, stream>>>(zx_bf, cw, cb, xc_bf);
        ssd1_kernel<<<dim3(NH, BSZ * NCH), 512, 0, stream>>>(xc_bf, dtraw, db, al, dp,
                                                             ac_buf, dec_buf, y_buf, S_buf);
        scan_kernel<<<(BSZ * NH * HD * DSTATE) / 256, 256, 0, stream>>>(S_buf, dec_buf,
                                                                        hs_buf);
        ssd2_kernel<<<dim3(NH, BSZ * NCH), 256, 0, stream>>>(xc_bf, hs_buf, ac_buf, y_buf);
        gatenorm_kernel<<<BL, 256, 0, stream>>>(y_buf, zx_bf, gw, y_bf);
        gemm_bf16_kernel<1, 2><<<dim3(DM / 128, BL / 64), 256, 0, stream>>>(
            y_bf, outT_l, nullptr, h_buf, nullptr, DM, DM, DI);
    }

    rmsnorm512_bf_kernel<<<BL, 256, 0, stream>>>(h_buf, fnorm_w, xn_bf);
    gemm_bf16_kernel<2, 4><<<dim3(1, BL / 128), 256, 0, stream>>>(
        xn_bf, headT, nullptr, out, (float*)head_b, 30, 30, DM);
}

// Round 6
// 1373.846 us; speedup vs baseline: 4.0160x; 1.2609x over previous
//
#include <hip/hip_runtime.h>
#include <math.h>

#define DM 512
#define DSTATE 64
#define HD 64
#define DI 1024
#define NH 16
#define CONVD 1152
#define DIP 2192
#define CHK 128
#define NCH 16
#define BSZ 2
#define SEQL 2048
#define BL (BSZ*SEQL)
#define NLAYER 12
#define EPSF 1e-5f
#define NPAD_IN 2304

typedef __attribute__((ext_vector_type(4))) float f32x4;
typedef __attribute__((ext_vector_type(8))) short s16x8;

__device__ __forceinline__ float bf2f(ushort u) {
    union { unsigned int i; float f; } v; v.i = ((unsigned int)u) << 16; return v.f;
}
__device__ __forceinline__ ushort f2bf(float f) {
    union { float f; unsigned int u; } v; v.f = f;
    unsigned int u = v.u;
    unsigned int r = (u + 0x7fffu + ((u >> 16) & 1u)) >> 16;
    return (ushort)r;
}

#define GLOAD_LDS16(gptr, lptr) __builtin_amdgcn_global_load_lds( \
    (const __attribute__((address_space(1))) void*)(gptr), \
    (__attribute__((address_space(3))) void*)(lptr), 16, 0, 0)

#define MFMA_BF16(a, b, c) __builtin_amdgcn_mfma_f32_16x16x32_bf16(a, b, c, 0, 0, 0)

// ---------------- embed + nerf positional encoding ----------------
__global__ void embed_kernel(const float* __restrict__ x, const float* __restrict__ W,
                             float* __restrict__ h) {
    int tok = blockIdx.x;
    float xe[3];
#pragma unroll
    for (int e = 0; e < 3; e++) {
        float v = x[tok * 3 + e];
        xe[e] = (v == -100.0f) ? 0.0f : v;
    }
    for (int d = threadIdx.x; d < DM; d += blockDim.x) {
        float pe = 0.0f;
        if (d < 510) {
            int e = d / 170, r = d % 170;
            int is_sin = (r < 85);
            int k = is_sin ? r : r - 85;
            float ang = xe[e] * ldexpf(1.0f, k);   // exact in fp32
            double dv = is_sin ? sin((double)ang) : cos((double)ang);
            pe = (float)dv;
        }
        float acc = pe;
#pragma unroll
        for (int e = 0; e < 3; e++) acc += xe[e] * W[e * DM + d];
        h[(size_t)tok * DM + d] = acc;
    }
}

// ---------------- rmsnorm width=512 -> bf16 out ----------------
__global__ __launch_bounds__(256) void rmsnorm512_bf_kernel(const float* __restrict__ in,
                                                            const float* __restrict__ w,
                                                            ushort* __restrict__ out) {
    int tok = blockIdx.x;
    const float* row = in + (size_t)tok * DM;
    float v0 = row[threadIdx.x];
    float v1 = row[threadIdx.x + 256];
    float ss = v0 * v0 + v1 * v1;
    for (int o = 32; o; o >>= 1) ss += __shfl_down(ss, o);
    __shared__ float sbuf[4];
    if ((threadIdx.x & 63) == 0) sbuf[threadIdx.x >> 6] = ss;
    __syncthreads();
    if (threadIdx.x == 0) {
        float s = sbuf[0] + sbuf[1] + sbuf[2] + sbuf[3];
        sbuf[0] = rsqrtf(s / (float)DM + EPSF);
    }
    __syncthreads();
    float rs = sbuf[0];
    ushort* orow = out + (size_t)tok * DM;
    orow[threadIdx.x] = f2bf(v0 * rs * w[threadIdx.x]);
    orow[threadIdx.x + 256] = f2bf(v1 * rs * w[threadIdx.x + 256]);
}

// ---------------- gate silu(z)*y + rmsnorm (width 1024) -> bf16 --------
__global__ __launch_bounds__(256) void gatenorm_kernel(const float* __restrict__ y,
                                                       const ushort* __restrict__ zx,
                                                       const float* __restrict__ gw,
                                                       ushort* __restrict__ yb) {
    int tok = blockIdx.x;
    const ushort* zrow = zx + (size_t)tok * DIP;
    const float* yrow = y + (size_t)tok * DI;
    float v[4];
    float ss = 0.0f;
#pragma unroll
    for (int k = 0; k < 4; k++) {
        int d = threadIdx.x + k * 256;
        float z = bf2f(zrow[d]);
        float s = z / (1.0f + __expf(-z));
        float val = yrow[d] * s;
        v[k] = val;
        ss += val * val;
    }
    for (int o = 32; o; o >>= 1) ss += __shfl_down(ss, o);
    __shared__ float sbuf[4];
    if ((threadIdx.x & 63) == 0) sbuf[threadIdx.x >> 6] = ss;
    __syncthreads();
    if (threadIdx.x == 0) {
        float s = sbuf[0] + sbuf[1] + sbuf[2] + sbuf[3];
        sbuf[0] = rsqrtf(s / (float)DI + EPSF);
    }
    __syncthreads();
    float rs = sbuf[0];
    ushort* ob = yb + (size_t)tok * DI;
#pragma unroll
    for (int k = 0; k < 4; k++) {
        int d = threadIdx.x + k * 256;
        ob[d] = f2bf(v[k] * rs * gw[d]);
    }
}

// ---------------- weight convert+transpose: w[L][K][N] f32 -> wT[L][Npad][K] bf16 ----
__global__ __launch_bounds__(256) void convT_kernel(const float* __restrict__ w,
                                                    ushort* __restrict__ wT,
                                                    int K, int N, int Npad) {
    __shared__ ushort tile[64][65];
    int l = blockIdx.z;
    int n0 = blockIdx.x * 64, k0 = blockIdx.y * 64;
    const float* src = w + (size_t)l * K * N;
    ushort* dst = wT + (size_t)l * Npad * K;
    int tid = threadIdx.x;
#pragma unroll
    for (int t = 0; t < 16; t++) {
        int idx = tid + t * 256;
        int r = idx >> 6, c = idx & 63;
        float v = (n0 + c < N) ? src[(size_t)(k0 + r) * N + n0 + c] : 0.0f;
        tile[c][r] = f2bf(v);
    }
    __syncthreads();
#pragma unroll
    for (int t = 0; t < 16; t++) {
        int idx = tid + t * 256;
        int r = idx >> 6, c = idx & 63;
        dst[(size_t)(n0 + r) * K + k0 + c] = tile[r][c];
    }
}

// ---------------- bf16 MFMA GEMM: C[M,N] = A[M,K] * BT[N,K]^T ----------------
// BM = MT*32 x BN=128 tile, BK=64, 4 waves (2x2), double-buffered prefetch.
// MODE 0: bf16 store + dt sidecar; MODE 1: fp32 accumulate; MODE 2: fp32 + bias (head)
template <int MODE, int MT>
__global__ __launch_bounds__(256) void gemm_bf16_kernel(
    const ushort* __restrict__ A, const ushort* __restrict__ BT,
    ushort* __restrict__ Cb, float* __restrict__ Cf, float* __restrict__ aux,
    int N, int Nstride, int K)
{
    __shared__ ushort As[2][MT * 32 * 64];
    __shared__ ushort Bs[2][128 * 64];
    int bm = blockIdx.y * (MT * 32), bn = blockIdx.x * 128;
    int tid = threadIdx.x;
    int lane = tid & 63, wid = tid >> 6;
    int wr = wid >> 1, wc = wid & 1;
    int r15 = lane & 15, q = lane >> 4;
    f32x4 acc[MT][4] = {};
    const int nkt = K >> 6;

#define STAGE_GEMM(b, kt) do {                                              \
        int k0s = (kt) << 6;                                                \
        _Pragma("unroll")                                                   \
        for (int t = 0; t < MT; t++) {                                      \
            int cbase = wid * (MT * 64) + t * 64;                           \
            int chunk = cbase + lane;                                       \
            int row = chunk >> 3, s = chunk & 7;                            \
            int kc = s ^ (row & 7);                                         \
            GLOAD_LDS16(A + (size_t)(bm + row) * K + k0s + kc * 8,          \
                        &As[b][cbase * 8]);                                 \
        }                                                                   \
        _Pragma("unroll")                                                   \
        for (int t = 0; t < 4; t++) {                                       \
            int cbase = wid * 256 + t * 64;                                 \
            int chunk = cbase + lane;                                       \
            int row = chunk >> 3, s = chunk & 7;                            \
            int kc = s ^ (row & 7);                                         \
            GLOAD_LDS16(BT + (size_t)(bn + row) * K + k0s + kc * 8,         \
                        &Bs[b][cbase * 8]);                                 \
        }                                                                   \
    } while (0)

    STAGE_GEMM(0, 0);
    __syncthreads();
    for (int kt = 0; kt < nkt; kt++) {
        int cur = kt & 1;
        if (kt + 1 < nkt) STAGE_GEMM(cur ^ 1, kt + 1);
        const ushort* Ac = As[cur];
        const ushort* Bc = Bs[cur];
#pragma unroll
        for (int kh = 0; kh < 2; kh++) {
            s16x8 av[MT], bv[4];
#pragma unroll
            for (int m = 0; m < MT; m++) {
                int row = wr * (MT * 16) + m * 16 + r15;
                int s = (kh * 4 + q) ^ (row & 7);
                av[m] = *(const s16x8*)(Ac + row * 64 + s * 8);
            }
#pragma unroll
            for (int n = 0; n < 4; n++) {
                int row = wc * 64 + n * 16 + r15;
                int s = (kh * 4 + q) ^ (row & 7);
                bv[n] = *(const s16x8*)(Bc + row * 64 + s * 8);
            }
#pragma unroll
            for (int m = 0; m < MT; m++)
#pragma unroll
                for (int n = 0; n < 4; n++)
                    acc[m][n] = MFMA_BF16(av[m], bv[n], acc[m][n]);
        }
        __syncthreads();   // drains prefetch (vmcnt0) + guards buffer reuse
    }
#undef STAGE_GEMM

#pragma unroll
    for (int m = 0; m < MT; m++) {
        int row0 = bm + wr * (MT * 16) + m * 16 + q * 4;
#pragma unroll
        for (int n = 0; n < 4; n++) {
            int col = bn + wc * 64 + n * 16 + r15;
#pragma unroll
            for (int r = 0; r < 4; r++) {
                float v = acc[m][n][r];
                int rr = row0 + r;
                if (MODE == 0) {
                    if (col < N) {
                        Cb[(size_t)rr * Nstride + col] = f2bf(v);
                        if (col >= DI + CONVD) aux[(size_t)rr * 16 + (col - DI - CONVD)] = v;
                    }
                } else if (MODE == 1) {
                    Cf[(size_t)rr * Nstride + col] += v;
                } else {
                    if (col < N) Cf[(size_t)rr * Nstride + col] = v + aux[col];
                }
            }
        }
    }
}

// ---------------- causal depthwise conv (d=4) + bias + silu ------
// thread: 8 contiguous channels x 4 rows; weights loaded once (contiguous 128B),
// 7-row sliding register window. grid: (BL/4)*(CONVD/8)/256 = 576 blocks.
__global__ __launch_bounds__(256) void conv_kernel(const ushort* __restrict__ zx,
                                                   const float* __restrict__ cw,
                                                   const float* __restrict__ cb,
                                                   ushort* __restrict__ xc) {
    int gid = blockIdx.x * 256 + threadIdx.x;
    int cu = gid % (CONVD / 8);
    int rb = gid / (CONVD / 8);
    int c8 = cu * 8;
    int l0 = rb * 4;
    int lmod = l0 & (SEQL - 1);

    float wk[4][8];
    const float4* wp = (const float4*)(cw + c8 * 4);   // [c][k], 8 c -> 32 floats contig
#pragma unroll
    for (int e = 0; e < 8; e++) {
        float4 v = wp[e];
        wk[0][e] = v.x; wk[1][e] = v.y; wk[2][e] = v.z; wk[3][e] = v.w;
    }
    float4 b0 = *(const float4*)(cb + c8);
    float4 b1 = *(const float4*)(cb + c8 + 4);
    float bias[8] = {b0.x, b0.y, b0.z, b0.w, b1.x, b1.y, b1.z, b1.w};

    const ushort* base = zx + (size_t)l0 * DIP + DI + c8;
    s16x8 zero = {};
    s16x8 rows[7];
    rows[0] = (lmod >= 3) ? *(const s16x8*)(base - 3 * DIP) : zero;
    rows[1] = (lmod >= 2) ? *(const s16x8*)(base - 2 * DIP) : zero;
    rows[2] = (lmod >= 1) ? *(const s16x8*)(base - 1 * DIP) : zero;
#pragma unroll
    for (int r = 0; r < 4; r++) rows[3 + r] = *(const s16x8*)(base + (size_t)r * DIP);

    ushort* ob = xc + (size_t)l0 * CONVD + c8;
#pragma unroll
    for (int r = 0; r < 4; r++) {
        s16x8 o;
#pragma unroll
        for (int e = 0; e < 8; e++) {
            float a = bias[e];
#pragma unroll
            for (int k = 0; k < 4; k++)
                a += bf2f((ushort)rows[r + k][e]) * wk[k][e];
            float s = a / (1.0f + __expf(-a));
            o[e] = (short)f2bf(s);
        }
        *(s16x8*)(ob + (size_t)r * CONVD) = o;
    }
}

// ---------------- F1: fused dt-scan + scores + M + y_diag(+D*xh) + chunk-state ------
// grid (NH, 32 bc); 512 threads (8 waves).
__global__ __launch_bounds__(512, 4) void ssd1_kernel(
    const ushort* __restrict__ xc, const float* __restrict__ dtraw,
    const float* __restrict__ dt_bias, const float* __restrict__ A_log,
    const float* __restrict__ Dp, float* __restrict__ acg,
    float* __restrict__ decbuf, float* __restrict__ y, float* __restrict__ S)
{
    __shared__ ushort Mb[128 * 128];   // union: Cs=[0,8192) Bs=[8192,16384); later M (XOR-swz)
    __shared__ ushort xhT[64 * 136];   // xhT[p][j], XOR-swz rows
    __shared__ ushort BmT[64 * 136];   // BmT[n][j], XOR-swz rows
    __shared__ float sAc[128], sDt[128], sDs[128];
    __shared__ float s_wsum, s_stot;

    int hh = blockIdx.x, bc = blockIdx.y;
    int tid = threadIdx.x, lane = tid & 63, w = tid >> 6;
    int l15 = lane & 15, lq = lane >> 4;
    int bch = bc * NH + hh;
    const size_t xbase = (size_t)(bc * CHK) * CONVD;
    ushort* Cs = Mb;
    ushort* Bs = Mb + 8192;

#pragma unroll
    for (int t = 0; t < 2; t++) {
        int cbase = t * 512 + w * 64;
        int chunk = cbase + lane;
        int row = chunk >> 3, s = chunk & 7;
        int kc = s ^ (row & 7);
        GLOAD_LDS16(xc + xbase + (size_t)row * CONVD + DI + DSTATE + kc * 8, Cs + (size_t)cbase * 8);
        GLOAD_LDS16(xc + xbase + (size_t)row * CONVD + DI + kc * 8, Bs + (size_t)cbase * 8);
    }
    {
        int j = tid & 127, pc = tid >> 7;
#pragma unroll
        for (int it = 0; it < 2; it++) {
            int pc8 = pc * 2 + it;
            s16x8 vx = *(const s16x8*)(xc + xbase + (size_t)j * CONVD + hh * HD + pc8 * 8);
            s16x8 vb = *(const s16x8*)(xc + xbase + (size_t)j * CONVD + DI + pc8 * 8);
#pragma unroll
            for (int e = 0; e < 8; e++) {
                int R = pc8 * 8 + e;
                int off = R * 136 + (((j >> 3) ^ (R & 7)) << 3) + (j & 7);
                xhT[off] = (ushort)vx[e];
                BmT[off] = (ushort)vb[e];
            }
        }
    }
    // dt-scan part 1: softplus + wave-local inclusive scan (threads 0-127)
    float v_scan = 0.0f, dt_v = 0.0f;
    if (tid < 128) {
        float raw = dtraw[(size_t)(bc * CHK + tid) * 16 + hh] + dt_bias[hh];
        dt_v = raw > 0.0f ? raw + log1pf(__expf(-raw)) : log1pf(__expf(raw));
        v_scan = dt_v * (-__expf(A_log[hh]));
#pragma unroll
        for (int o = 1; o < 64; o <<= 1) {
            float u = __shfl_up(v_scan, o);
            if (lane >= o) v_scan += u;
        }
        if (tid == 63) s_wsum = v_scan;
    }
    __syncthreads();   // B1

    float ac_v = 0.0f;
    if (tid < 128) {
        ac_v = (tid >= 64) ? v_scan + s_wsum : v_scan;
        if (tid == 127) s_stot = ac_v;
    }
    f32x4 acc_s[8] = {};
    {
        int row = w * 16 + l15;
#pragma unroll
        for (int kh = 0; kh < 2; kh++) {
            int sl = (kh * 4 + lq) ^ (row & 7);
            s16x8 av = *(const s16x8*)(Cs + row * 64 + sl * 8);
#pragma unroll
            for (int nj = 0; nj < 8; nj++) {
                int jr = nj * 16 + l15;
                int sl2 = (kh * 4 + lq) ^ (jr & 7);
                s16x8 bv = *(const s16x8*)(Bs + jr * 64 + sl2 * 8);
                acc_s[nj] = MFMA_BF16(av, bv, acc_s[nj]);
            }
        }
    }
    __syncthreads();   // B2

    if (tid < 128) {
        float asum = s_stot;
        sAc[tid] = ac_v;
        sDt[tid] = dt_v;
        sDs[tid] = __expf(asum - ac_v) * dt_v;
        acg[(size_t)bch * CHK + tid] = ac_v;
        if (tid == 0) decbuf[bch] = __expf(asum);
    }
    __syncthreads();   // B3

#pragma unroll
    for (int nj = 0; nj < 8; nj++) {
        int j = nj * 16 + l15;
        if (nj < w) {
            float acj = sAc[j], dtj = sDt[j];
#pragma unroll
            for (int r = 0; r < 4; r++) {
                int i = w * 16 + lq * 4 + r;
                float v = acc_s[nj][r] * __expf(sAc[i] - acj) * dtj;
                Mb[i * 128 + ((((i & 7) ^ (j >> 3)) << 3) | (j & 7))] = f2bf(v);
            }
        } else if (nj == w) {
            float acj = sAc[j], dtj = sDt[j];
#pragma unroll
            for (int r = 0; r < 4; r++) {
                int i = w * 16 + lq * 4 + r;
                float v = (j <= i) ? acc_s[nj][r] * __expf(sAc[i] - acj) * dtj : 0.0f;
                Mb[i * 128 + ((((i & 7) ^ (j >> 3)) << 3) | (j & 7))] = f2bf(v);
            }
        } else if (nj == w + 1) {
#pragma unroll
            for (int r = 0; r < 4; r++) {
                int i = w * 16 + lq * 4 + r;
                Mb[i * 128 + ((((i & 7) ^ (j >> 3)) << 3) | (j & 7))] = 0;
            }
        }
    }
    __syncthreads();   // B4

    int ph = w >> 2, iq = w & 3;
    f32x4 acc_y[2][2] = {};
    f32x4 acc_st[2] = {};
    int nn = iq * 16 + l15;
#pragma unroll
    for (int ks = 0; ks < 4; ks++) {
        int cj = ks * 4 + lq;
        int j0 = ks * 32 + lq * 8;
        s16x8 axh[2], axs[2];
#pragma unroll
        for (int m = 0; m < 2; m++) {
            int p = ph * 32 + m * 16 + l15;
            axh[m] = *(const s16x8*)(xhT + p * 136 + ((cj ^ (p & 7)) << 3));
            s16x8 r;
#pragma unroll
            for (int e = 0; e < 8; e++)
                r[e] = (short)f2bf(bf2f((ushort)axh[m][e]) * sDs[j0 + e]);
            axs[m] = r;
        }
        s16x8 bb = *(const s16x8*)(BmT + nn * 136 + ((cj ^ (nn & 7)) << 3));
#pragma unroll
        for (int m = 0; m < 2; m++)
            acc_st[m] = MFMA_BF16(axs[m], bb, acc_st[m]);
        if (ks <= iq) {
            s16x8 bm_[2];
#pragma unroll
            for (int n = 0; n < 2; n++) {
                int i = iq * 32 + n * 16 + l15;
                bm_[n] = *(const s16x8*)(Mb + i * 128 + ((cj ^ (i & 7)) << 3));
            }
#pragma unroll
            for (int m = 0; m < 2; m++)
#pragma unroll
                for (int n = 0; n < 2; n++)
                    acc_y[m][n] = MFMA_BF16(axh[m], bm_[n], acc_y[m][n]);
        }
    }

    float Dh = Dp[hh];
#pragma unroll
    for (int m = 0; m < 2; m++) {
        int p0 = ph * 32 + m * 16 + lq * 4;
#pragma unroll
        for (int n = 0; n < 2; n++) {
            int i = iq * 32 + n * 16 + l15;
            f32x4 v = acc_y[m][n];
#pragma unroll
            for (int r = 0; r < 4; r++) {
                int p = p0 + r;
                v[r] += Dh * bf2f(xhT[p * 136 + ((((p & 7) ^ (i >> 3)) << 3) | (i & 7))]);
            }
            *(f32x4*)&y[(size_t)(bc * CHK + i) * DI + hh * HD + p0] = v;
        }
#pragma unroll
        for (int r = 0; r < 4; r++)
            S[(size_t)bch * 4096 + (size_t)(p0 + r) * 64 + nn] = acc_st[m][r];
    }
}

// ---------------- sequential scan over chunks ----------------
__global__ void scan_kernel(const float* __restrict__ S, const float* __restrict__ decbuf,
                            float* __restrict__ hs) {
    int g = blockIdx.x * 256 + threadIdx.x;
    int n = g & 63, p = (g >> 6) & 63, hh = (g >> 12) & 15, b = g >> 16;
    float state = 0.0f;
#pragma unroll
    for (int c = 0; c < NCH; c++) {
        int bch = (b * NCH + c) * NH + hh;
        size_t idx = (size_t)bch * 4096 + p * 64 + n;
        hs[idx] = state;
        state = state * decbuf[bch] + S[idx];
    }
}

// ---------------- F2: y += exp(ac_i) * (C @ hs^T)  via MFMA, transposed output ------
__global__ __launch_bounds__(256) void ssd2_kernel(
    const ushort* __restrict__ xc, const float* __restrict__ hsg,
    const float* __restrict__ acg, float* __restrict__ y)
{
    __shared__ ushort Cs[128 * 64];
    __shared__ ushort Hs[64 * 64];
    __shared__ float sAc[128];
    int hh = blockIdx.x, bc = blockIdx.y;
    int tid = threadIdx.x, lane = tid & 63, wid = tid >> 6;
    int wr = wid >> 1, wc = wid & 1, l15 = lane & 15, lq = lane >> 4;
    int bch = bc * NH + hh;
    const size_t xbase = (size_t)(bc * CHK) * CONVD;
#pragma unroll
    for (int t = 0; t < 4; t++) {
        int cbase = t * 256 + wid * 64;
        int chunk = cbase + lane;
        int row = chunk >> 3, s = chunk & 7;
        int kc = s ^ (row & 7);
        GLOAD_LDS16(xc + xbase + (size_t)row * CONVD + DI + DSTATE + kc * 8, Cs + (size_t)cbase * 8);
    }
#pragma unroll
    for (int t = 0; t < 2; t++) {
        int chunk = t * 256 + tid;
        int p = chunk >> 3, s = chunk & 7;
        int kc = s ^ (p & 7);
        const float* src = hsg + (size_t)bch * 4096 + p * 64 + kc * 8;
        ushort* dst = Hs + p * 64 + s * 8;
#pragma unroll
        for (int e = 0; e < 8; e++) dst[e] = f2bf(src[e]);
    }
    if (tid < 128) sAc[tid] = acg[(size_t)bch * CHK + tid];
    __syncthreads();
    f32x4 acc[2][4] = {};
#pragma unroll
    for (int kh = 0; kh < 2; kh++) {
        s16x8 av[2], bv[4];
#pragma unroll
        for (int m = 0; m < 2; m++) {
            int p = wr * 32 + m * 16 + l15;
            int sl = (kh * 4 + lq) ^ (p & 7);
            av[m] = *(const s16x8*)(Hs + p * 64 + sl * 8);
        }
#pragma unroll
        for (int n = 0; n < 4; n++) {
            int i = wc * 64 + n * 16 + l15;
            int sl = (kh * 4 + lq) ^ (i & 7);
            bv[n] = *(const s16x8*)(Cs + i * 64 + sl * 8);
        }
#pragma unroll
        for (int m = 0; m < 2; m++)
#pragma unroll
            for (int n = 0; n < 4; n++)
                acc[m][n] = MFMA_BF16(av[m], bv[n], acc[m][n]);
    }
#pragma unroll
    for (int m = 0; m < 2; m++) {
        int p0 = wr * 32 + m * 16 + lq * 4;
#pragma unroll
        for (int n = 0; n < 4; n++) {
            int i = wc * 64 + n * 16 + l15;
            float e = __expf(sAc[i]);
            float* dst = &y[(size_t)(bc * CHK + i) * DI + hh * HD + p0];
            f32x4 v = *(f32x4*)dst;
#pragma unroll
            for (int r = 0; r < 4; r++) v[r] += e * acc[m][n][r];
            *(f32x4*)dst = v;
        }
    }
}

extern "C" void kernel_launch(void* const* d_in, const int* in_sizes, int n_in,
                              void* d_out, int out_size, void* d_ws, size_t ws_size,
                              hipStream_t stream) {
    const float* x        = (const float*)d_in[0];
    const float* W_embed  = (const float*)d_in[1];
    const float* rms_w    = (const float*)d_in[2];
    const float* in_w     = (const float*)d_in[3];
    const float* conv_w   = (const float*)d_in[4];
    const float* conv_b   = (const float*)d_in[5];
    const float* dt_bias  = (const float*)d_in[6];
    const float* A_log    = (const float*)d_in[7];
    const float* D_param  = (const float*)d_in[8];
    const float* gnorm_w  = (const float*)d_in[9];
    const float* out_w    = (const float*)d_in[10];
    const float* fnorm_w  = (const float*)d_in[11];
    const float* head_w   = (const float*)d_in[12];
    const float* head_b   = (const float*)d_in[13];
    float* out = (float*)d_out;

    char* p = (char*)d_ws;
    auto alloc = [&](size_t bytes) { char* r = p; p += (bytes + 255) & ~(size_t)255; return r; };

    float*  h_buf   = (float*)alloc((size_t)BL * DM * 4);
    float*  y_buf   = (float*)alloc((size_t)BL * DI * 4);
    float*  S_buf   = (float*)alloc((size_t)BSZ * NCH * NH * HD * DSTATE * 4);
    float*  hs_buf  = (float*)alloc((size_t)BSZ * NCH * NH * HD * DSTATE * 4);
    float*  ac_buf  = (float*)alloc((size_t)BSZ * NCH * NH * CHK * 4);
    float*  dec_buf = (float*)alloc((size_t)BSZ * NCH * NH * 4);
    float*  dtraw   = (float*)alloc((size_t)BL * 16 * 4);
    ushort* xn_bf   = (ushort*)alloc((size_t)BL * DM * 2);
    ushort* zx_bf   = (ushort*)alloc((size_t)BL * DIP * 2);
    ushort* xc_bf   = (ushort*)alloc((size_t)BL * CONVD * 2);
    ushort* y_bf    = (ushort*)alloc((size_t)BL * DI * 2);
    ushort* headT   = (ushort*)alloc((size_t)128 * DM * 2);

    size_t in_full  = (size_t)NLAYER * NPAD_IN * DM * 2;
    size_t out_full = (size_t)NLAYER * DM * DI * 2;
    size_t used = (size_t)(p - (char*)d_ws);
    bool full = (used + in_full + out_full + 4096) <= ws_size;
    ushort* inT  = (ushort*)alloc(full ? in_full  : (size_t)NPAD_IN * DM * 2);
    ushort* outT = (ushort*)alloc(full ? out_full : (size_t)DM * DI * 2);

    embed_kernel<<<BL, 256, 0, stream>>>(x, W_embed, h_buf);
    convT_kernel<<<dim3(2, DM / 64, 1), 256, 0, stream>>>(head_w, headT, DM, 30, 128);
    if (full) {
        convT_kernel<<<dim3(NPAD_IN / 64, DM / 64, NLAYER), 256, 0, stream>>>(
            in_w, inT, DM, DIP, NPAD_IN);
        convT_kernel<<<dim3(DM / 64, DI / 64, NLAYER), 256, 0, stream>>>(
            out_w, outT, DI, DM, DM);
    }

    for (int l = 0; l < NLAYER; l++) {
        const float* rw = rms_w + (size_t)l * DM;
        const float* cw = conv_w + (size_t)l * CONVD * 4;
        const float* cb = conv_b + (size_t)l * CONVD;
        const float* db = dt_bias + (size_t)l * NH;
        const float* al = A_log + (size_t)l * NH;
        const float* dp = D_param + (size_t)l * NH;
        const float* gw = gnorm_w + (size_t)l * DI;

        ushort* inT_l  = full ? inT  + (size_t)l * NPAD_IN * DM : inT;
        ushort* outT_l = full ? outT + (size_t)l * DM * DI      : outT;
        if (!full) {
            convT_kernel<<<dim3(NPAD_IN / 64, DM / 64, 1), 256, 0, stream>>>(
                in_w + (size_t)l * DM * DIP, inT_l, DM, DIP, NPAD_IN);
            convT_kernel<<<dim3(DM / 64, DI / 64, 1), 256, 0, stream>>>(
                out_w + (size_t)l * DI * DM, outT_l, DI, DM, DM);
        }

        rmsnorm512_bf_kernel<<<BL, 256, 0, stream>>>(h_buf, rw, xn_bf);
        gemm_bf16_kernel<0, 4><<<dim3(NPAD_IN / 128, BL / 128), 256, 0, stream>>>(
            xn_bf, inT_l, zx_bf, nullptr, dtraw, DIP, DIP, DM);
        conv_kernel<<<((BL / 4) * (CONVD / 8)) / 256, 256, 0, stream>>>(zx_bf, cw, cb, xc_bf);
        ssd1_kernel<<<dim3(NH, BSZ * NCH), 512, 0, stream>>>(xc_bf, dtraw, db, al, dp,
                                                             ac_buf, dec_buf, y_buf, S_buf);
        scan_kernel<<<(BSZ * NH * HD * DSTATE) / 256, 256, 0, stream>>>(S_buf, dec_buf,
                                                                        hs_buf);
        ssd2_kernel<<<dim3(NH, BSZ * NCH), 256, 0, stream>>>(xc_bf, hs_buf, ac_buf, y_buf);
        gatenorm_kernel<<<BL, 256, 0, stream>>>(y_buf, zx_bf, gw, y_bf);
        gemm_bf16_kernel<1, 2><<<dim3(DM / 128, BL / 64), 256, 0, stream>>>(
            y_bf, outT_l, nullptr, h_buf, nullptr, DM, DM, DI);
    }

    rmsnorm512_bf_kernel<<<BL, 256, 0, stream>>>(h_buf, fnorm_w, xn_bf);
    gemm_bf16_kernel<2, 4><<<dim3(1, BL / 128), 256, 0, stream>>>(
        xn_bf, headT, nullptr, out, (float*)head_b, 30, 30, DM);
}

// Round 8
// 1244.372 us; speedup vs baseline: 4.4339x; 1.1040x over previous
//
#include <hip/hip_runtime.h>
#include <math.h>

#define DM 512
#define DSTATE 64
#define HD 64
#define DI 1024
#define NH 16
#define CONVD 1152
#define DIP 2192
#define CHK 128
#define NCH 16
#define BSZ 2
#define SEQL 2048
#define BL (BSZ*SEQL)
#define NLAYER 12
#define EPSF 1e-5f
#define NPAD_IN 2304

typedef __attribute__((ext_vector_type(4))) float f32x4;
typedef __attribute__((ext_vector_type(8))) short s16x8;

__device__ __forceinline__ float bf2f(ushort u) {
    union { unsigned int i; float f; } v; v.i = ((unsigned int)u) << 16; return v.f;
}
__device__ __forceinline__ ushort f2bf(float f) {
    union { float f; unsigned int u; } v; v.f = f;
    unsigned int u = v.u;
    unsigned int r = (u + 0x7fffu + ((u >> 16) & 1u)) >> 16;
    return (ushort)r;
}

#define GLOAD_LDS16(gptr, lptr) __builtin_amdgcn_global_load_lds( \
    (const __attribute__((address_space(1))) void*)(gptr), \
    (__attribute__((address_space(3))) void*)(lptr), 16, 0, 0)

#define MFMA_BF16(a, b, c) __builtin_amdgcn_mfma_f32_16x16x32_bf16(a, b, c, 0, 0, 0)

// ---------------- embed + nerf positional encoding ----------------
__global__ void embed_kernel(const float* __restrict__ x, const float* __restrict__ W,
                             float* __restrict__ h) {
    int tok = blockIdx.x;
    float xe[3];
#pragma unroll
    for (int e = 0; e < 3; e++) {
        float v = x[tok * 3 + e];
        xe[e] = (v == -100.0f) ? 0.0f : v;
    }
    for (int d = threadIdx.x; d < DM; d += blockDim.x) {
        float pe = 0.0f;
        if (d < 510) {
            int e = d / 170, r = d % 170;
            int is_sin = (r < 85);
            int k = is_sin ? r : r - 85;
            float ang = xe[e] * ldexpf(1.0f, k);   // exact in fp32
            double dv = is_sin ? sin((double)ang) : cos((double)ang);
            pe = (float)dv;
        }
        float acc = pe;
#pragma unroll
        for (int e = 0; e < 3; e++) acc += xe[e] * W[e * DM + d];
        h[(size_t)tok * DM + d] = acc;
    }
}

// ---------------- rmsnorm width=512 -> bf16 out ----------------
__global__ __launch_bounds__(256) void rmsnorm512_bf_kernel(const float* __restrict__ in,
                                                            const float* __restrict__ w,
                                                            ushort* __restrict__ out) {
    int tok = blockIdx.x;
    const float* row = in + (size_t)tok * DM;
    float v0 = row[threadIdx.x];
    float v1 = row[threadIdx.x + 256];
    float ss = v0 * v0 + v1 * v1;
    for (int o = 32; o; o >>= 1) ss += __shfl_down(ss, o);
    __shared__ float sbuf[4];
    if ((threadIdx.x & 63) == 0) sbuf[threadIdx.x >> 6] = ss;
    __syncthreads();
    if (threadIdx.x == 0) {
        float s = sbuf[0] + sbuf[1] + sbuf[2] + sbuf[3];
        sbuf[0] = rsqrtf(s / (float)DM + EPSF);
    }
    __syncthreads();
    float rs = sbuf[0];
    ushort* orow = out + (size_t)tok * DM;
    orow[threadIdx.x] = f2bf(v0 * rs * w[threadIdx.x]);
    orow[threadIdx.x + 256] = f2bf(v1 * rs * w[threadIdx.x + 256]);
}

// ---------------- gate silu(z)*y + rmsnorm (width 1024) -> bf16 --------
__global__ __launch_bounds__(256) void gatenorm_kernel(const float* __restrict__ y,
                                                       const ushort* __restrict__ zx,
                                                       const float* __restrict__ gw,
                                                       ushort* __restrict__ yb) {
    int tok = blockIdx.x;
    const ushort* zrow = zx + (size_t)tok * DIP;
    const float* yrow = y + (size_t)tok * DI;
    float v[4];
    float ss = 0.0f;
#pragma unroll
    for (int k = 0; k < 4; k++) {
        int d = threadIdx.x + k * 256;
        float z = bf2f(zrow[d]);
        float s = z / (1.0f + __expf(-z));
        float val = yrow[d] * s;
        v[k] = val;
        ss += val * val;
    }
    for (int o = 32; o; o >>= 1) ss += __shfl_down(ss, o);
    __shared__ float sbuf[4];
    if ((threadIdx.x & 63) == 0) sbuf[threadIdx.x >> 6] = ss;
    __syncthreads();
    if (threadIdx.x == 0) {
        float s = sbuf[0] + sbuf[1] + sbuf[2] + sbuf[3];
        sbuf[0] = rsqrtf(s / (float)DI + EPSF);
    }
    __syncthreads();
    float rs = sbuf[0];
    ushort* ob = yb + (size_t)tok * DI;
#pragma unroll
    for (int k = 0; k < 4; k++) {
        int d = threadIdx.x + k * 256;
        ob[d] = f2bf(v[k] * rs * gw[d]);
    }
}

// ---------------- weight convert+transpose: w[L][K][N] f32 -> wT[L][Npad][K] bf16 ----
__global__ __launch_bounds__(256) void convT_kernel(const float* __restrict__ w,
                                                    ushort* __restrict__ wT,
                                                    int K, int N, int Npad) {
    __shared__ ushort tile[64][65];
    int l = blockIdx.z;
    int n0 = blockIdx.x * 64, k0 = blockIdx.y * 64;
    const float* src = w + (size_t)l * K * N;
    ushort* dst = wT + (size_t)l * Npad * K;
    int tid = threadIdx.x;
#pragma unroll
    for (int t = 0; t < 16; t++) {
        int idx = tid + t * 256;
        int r = idx >> 6, c = idx & 63;
        float v = (n0 + c < N) ? src[(size_t)(k0 + r) * N + n0 + c] : 0.0f;
        tile[c][r] = f2bf(v);
    }
    __syncthreads();
#pragma unroll
    for (int t = 0; t < 16; t++) {
        int idx = tid + t * 256;
        int r = idx >> 6, c = idx & 63;
        dst[(size_t)(n0 + r) * K + k0 + c] = tile[r][c];
    }
}

// ---------------- bf16 MFMA GEMM: C[M,N] = A[M,K] * BT[N,K]^T ----------------
// BM = MT*32 x BN=128 tile, BK=64, 4 waves (2x2), double-buffered prefetch,
// bijective XCD-aware block swizzle (grid must be %8==0).
// MODE 0: bf16 store + dt sidecar; MODE 1: fp32 accumulate; MODE 2: fp32 + bias (head)
template <int MODE, int MT>
__global__ __launch_bounds__(256) void gemm_bf16_kernel(
    const ushort* __restrict__ A, const ushort* __restrict__ BT,
    ushort* __restrict__ Cb, float* __restrict__ Cf, float* __restrict__ aux,
    int N, int Nstride, int K)
{
    __shared__ ushort As[2][MT * 32 * 64];
    __shared__ ushort Bs[2][128 * 64];
    // XCD swizzle: contiguous run of nwg/8 blocks per XCD -> A/B panel L2 reuse
    int nwg = gridDim.x * gridDim.y;
    int w0 = blockIdx.y * gridDim.x + blockIdx.x;
    int wg = (w0 & 7) * (nwg >> 3) + (w0 >> 3);
    int by = wg / gridDim.x, bx = wg - by * gridDim.x;
    int bm = by * (MT * 32), bn = bx * 128;
    int tid = threadIdx.x;
    int lane = tid & 63, wid = tid >> 6;
    int wr = wid >> 1, wc = wid & 1;
    int r15 = lane & 15, q = lane >> 4;
    f32x4 acc[MT][4] = {};
    const int nkt = K >> 6;

#define STAGE_GEMM(b, kt) do {                                              \
        int k0s = (kt) << 6;                                                \
        _Pragma("unroll")                                                   \
        for (int t = 0; t < MT; t++) {                                      \
            int cbase = wid * (MT * 64) + t * 64;                           \
            int chunk = cbase + lane;                                       \
            int row = chunk >> 3, s = chunk & 7;                            \
            int kc = s ^ (row & 7);                                         \
            GLOAD_LDS16(A + (size_t)(bm + row) * K + k0s + kc * 8,          \
                        &As[b][cbase * 8]);                                 \
        }                                                                   \
        _Pragma("unroll")                                                   \
        for (int t = 0; t < 4; t++) {                                       \
            int cbase = wid * 256 + t * 64;                                 \
            int chunk = cbase + lane;                                       \
            int row = chunk >> 3, s = chunk & 7;                            \
            int kc = s ^ (row & 7);                                         \
            GLOAD_LDS16(BT + (size_t)(bn + row) * K + k0s + kc * 8,         \
                        &Bs[b][cbase * 8]);                                 \
        }                                                                   \
    } while (0)

    STAGE_GEMM(0, 0);
    __syncthreads();
    for (int kt = 0; kt < nkt; kt++) {
        int cur = kt & 1;
        if (kt + 1 < nkt) STAGE_GEMM(cur ^ 1, kt + 1);
        const ushort* Ac = As[cur];
        const ushort* Bc = Bs[cur];
#pragma unroll
        for (int kh = 0; kh < 2; kh++) {
            s16x8 av[MT], bv[4];
#pragma unroll
            for (int m = 0; m < MT; m++) {
                int row = wr * (MT * 16) + m * 16 + r15;
                int s = (kh * 4 + q) ^ (row & 7);
                av[m] = *(const s16x8*)(Ac + row * 64 + s * 8);
            }
#pragma unroll
            for (int n = 0; n < 4; n++) {
                int row = wc * 64 + n * 16 + r15;
                int s = (kh * 4 + q) ^ (row & 7);
                bv[n] = *(const s16x8*)(Bc + row * 64 + s * 8);
            }
#pragma unroll
            for (int m = 0; m < MT; m++)
#pragma unroll
                for (int n = 0; n < 4; n++)
                    acc[m][n] = MFMA_BF16(av[m], bv[n], acc[m][n]);
        }
        __syncthreads();   // drains prefetch (vmcnt0) + guards buffer reuse
    }
#undef STAGE_GEMM

#pragma unroll
    for (int m = 0; m < MT; m++) {
        int row0 = bm + wr * (MT * 16) + m * 16 + q * 4;
#pragma unroll
        for (int n = 0; n < 4; n++) {
            int col = bn + wc * 64 + n * 16 + r15;
#pragma unroll
            for (int r = 0; r < 4; r++) {
                float v = acc[m][n][r];
                int rr = row0 + r;
                if (MODE == 0) {
                    if (col < N) {
                        Cb[(size_t)rr * Nstride + col] = f2bf(v);
                        if (col >= DI + CONVD) aux[(size_t)rr * 16 + (col - DI - CONVD)] = v;
                    }
                } else if (MODE == 1) {
                    Cf[(size_t)rr * Nstride + col] += v;
                } else {
                    if (col < N) Cf[(size_t)rr * Nstride + col] = v + aux[col];
                }
            }
        }
    }
}

// ---------------- causal depthwise conv (d=4) + bias + silu ------
__global__ __launch_bounds__(256) void conv_kernel(const ushort* __restrict__ zx,
                                                   const float* __restrict__ cw,
                                                   const float* __restrict__ cb,
                                                   ushort* __restrict__ xc) {
    int gid = blockIdx.x * 256 + threadIdx.x;
    int cu = gid % (CONVD / 8);
    int rb = gid / (CONVD / 8);
    int c8 = cu * 8;
    int l0 = rb * 4;
    int lmod = l0 & (SEQL - 1);

    float wk[4][8];
    const float4* wp = (const float4*)(cw + c8 * 4);
#pragma unroll
    for (int e = 0; e < 8; e++) {
        float4 v = wp[e];
        wk[0][e] = v.x; wk[1][e] = v.y; wk[2][e] = v.z; wk[3][e] = v.w;
    }
    float4 b0 = *(const float4*)(cb + c8);
    float4 b1 = *(const float4*)(cb + c8 + 4);
    float bias[8] = {b0.x, b0.y, b0.z, b0.w, b1.x, b1.y, b1.z, b1.w};

    const ushort* base = zx + (size_t)l0 * DIP + DI + c8;
    s16x8 zero = {};
    s16x8 rows[7];
    rows[0] = (lmod >= 3) ? *(const s16x8*)(base - 3 * DIP) : zero;
    rows[1] = (lmod >= 2) ? *(const s16x8*)(base - 2 * DIP) : zero;
    rows[2] = (lmod >= 1) ? *(const s16x8*)(base - 1 * DIP) : zero;
#pragma unroll
    for (int r = 0; r < 4; r++) rows[3 + r] = *(const s16x8*)(base + (size_t)r * DIP);

    ushort* ob = xc + (size_t)l0 * CONVD + c8;
#pragma unroll
    for (int r = 0; r < 4; r++) {
        s16x8 o;
#pragma unroll
        for (int e = 0; e < 8; e++) {
            float a = bias[e];
#pragma unroll
            for (int k = 0; k < 4; k++)
                a += bf2f((ushort)rows[r + k][e]) * wk[k][e];
            float s = a / (1.0f + __expf(-a));
            o[e] = (short)f2bf(s);
        }
        *(s16x8*)(ob + (size_t)r * CONVD) = o;
    }
}

// ---------------- F1: fused dt-scan + scores + M + y_diag(+D*xh) + chunk-state ------
__global__ __launch_bounds__(512, 4) void ssd1_kernel(
    const ushort* __restrict__ xc, const float* __restrict__ dtraw,
    const float* __restrict__ dt_bias, const float* __restrict__ A_log,
    const float* __restrict__ Dp, float* __restrict__ acg,
    float* __restrict__ decbuf, float* __restrict__ y, float* __restrict__ S)
{
    __shared__ ushort Mb[128 * 128];
    __shared__ ushort xhT[64 * 136];
    __shared__ ushort BmT[64 * 136];
    __shared__ float sAc[128], sDt[128], sDs[128];
    __shared__ float s_wsum, s_stot;

    int hh = blockIdx.x, bc = blockIdx.y;
    int tid = threadIdx.x, lane = tid & 63, w = tid >> 6;
    int l15 = lane & 15, lq = lane >> 4;
    int bch = bc * NH + hh;
    const size_t xbase = (size_t)(bc * CHK) * CONVD;
    ushort* Cs = Mb;
    ushort* Bs = Mb + 8192;

#pragma unroll
    for (int t = 0; t < 2; t++) {
        int cbase = t * 512 + w * 64;
        int chunk = cbase + lane;
        int row = chunk >> 3, s = chunk & 7;
        int kc = s ^ (row & 7);
        GLOAD_LDS16(xc + xbase + (size_t)row * CONVD + DI + DSTATE + kc * 8, Cs + (size_t)cbase * 8);
        GLOAD_LDS16(xc + xbase + (size_t)row * CONVD + DI + kc * 8, Bs + (size_t)cbase * 8);
    }
    {
        int j = tid & 127, pc = tid >> 7;
#pragma unroll
        for (int it = 0; it < 2; it++) {
            int pc8 = pc * 2 + it;
            s16x8 vx = *(const s16x8*)(xc + xbase + (size_t)j * CONVD + hh * HD + pc8 * 8);
            s16x8 vb = *(const s16x8*)(xc + xbase + (size_t)j * CONVD + DI + pc8 * 8);
#pragma unroll
            for (int e = 0; e < 8; e++) {
                int R = pc8 * 8 + e;
                int off = R * 136 + (((j >> 3) ^ (R & 7)) << 3) + (j & 7);
                xhT[off] = (ushort)vx[e];
                BmT[off] = (ushort)vb[e];
            }
        }
    }
    float v_scan = 0.0f, dt_v = 0.0f;
    if (tid < 128) {
        float raw = dtraw[(size_t)(bc * CHK + tid) * 16 + hh] + dt_bias[hh];
        dt_v = raw > 0.0f ? raw + log1pf(__expf(-raw)) : log1pf(__expf(raw));
        v_scan = dt_v * (-__expf(A_log[hh]));
#pragma unroll
        for (int o = 1; o < 64; o <<= 1) {
            float u = __shfl_up(v_scan, o);
            if (lane >= o) v_scan += u;
        }
        if (tid == 63) s_wsum = v_scan;
    }
    __syncthreads();   // B1

    float ac_v = 0.0f;
    if (tid < 128) {
        ac_v = (tid >= 64) ? v_scan + s_wsum : v_scan;
        if (tid == 127) s_stot = ac_v;
    }
    f32x4 acc_s[8] = {};
    {
        int row = w * 16 + l15;
#pragma unroll
        for (int kh = 0; kh < 2; kh++) {
            int sl = (kh * 4 + lq) ^ (row & 7);
            s16x8 av = *(const s16x8*)(Cs + row * 64 + sl * 8);
#pragma unroll
            for (int nj = 0; nj < 8; nj++) {
                int jr = nj * 16 + l15;
                int sl2 = (kh * 4 + lq) ^ (jr & 7);
                s16x8 bv = *(const s16x8*)(Bs + jr * 64 + sl2 * 8);
                acc_s[nj] = MFMA_BF16(av, bv, acc_s[nj]);
            }
        }
    }
    __syncthreads();   // B2

    if (tid < 128) {
        float asum = s_stot;
        sAc[tid] = ac_v;
        sDt[tid] = dt_v;
        sDs[tid] = __expf(asum - ac_v) * dt_v;
        acg[(size_t)bch * CHK + tid] = ac_v;
        if (tid == 0) decbuf[bch] = __expf(asum);
    }
    __syncthreads();   // B3

#pragma unroll
    for (int nj = 0; nj < 8; nj++) {
        int j = nj * 16 + l15;
        if (nj < w) {
            float acj = sAc[j], dtj = sDt[j];
#pragma unroll
            for (int r = 0; r < 4; r++) {
                int i = w * 16 + lq * 4 + r;
                float v = acc_s[nj][r] * __expf(sAc[i] - acj) * dtj;
                Mb[i * 128 + ((((i & 7) ^ (j >> 3)) << 3) | (j & 7))] = f2bf(v);
            }
        } else if (nj == w) {
            float acj = sAc[j], dtj = sDt[j];
#pragma unroll
            for (int r = 0; r < 4; r++) {
                int i = w * 16 + lq * 4 + r;
                float v = (j <= i) ? acc_s[nj][r] * __expf(sAc[i] - acj) * dtj : 0.0f;
                Mb[i * 128 + ((((i & 7) ^ (j >> 3)) << 3) | (j & 7))] = f2bf(v);
            }
        } else if (nj == w + 1) {
#pragma unroll
            for (int r = 0; r < 4; r++) {
                int i = w * 16 + lq * 4 + r;
                Mb[i * 128 + ((((i & 7) ^ (j >> 3)) << 3) | (j & 7))] = 0;
            }
        }
    }
    __syncthreads();   // B4

    int ph = w >> 2, iq = w & 3;
    f32x4 acc_y[2][2] = {};
    f32x4 acc_st[2] = {};
    int nn = iq * 16 + l15;
#pragma unroll
    for (int ks = 0; ks < 4; ks++) {
        int cj = ks * 4 + lq;
        int j0 = ks * 32 + lq * 8;
        s16x8 axh[2], axs[2];
#pragma unroll
        for (int m = 0; m < 2; m++) {
            int p = ph * 32 + m * 16 + l15;
            axh[m] = *(const s16x8*)(xhT + p * 136 + ((cj ^ (p & 7)) << 3));
            s16x8 r;
#pragma unroll
            for (int e = 0; e < 8; e++)
                r[e] = (short)f2bf(bf2f((ushort)axh[m][e]) * sDs[j0 + e]);
            axs[m] = r;
        }
        s16x8 bb = *(const s16x8*)(BmT + nn * 136 + ((cj ^ (nn & 7)) << 3));
#pragma unroll
        for (int m = 0; m < 2; m++)
            acc_st[m] = MFMA_BF16(axs[m], bb, acc_st[m]);
        if (ks <= iq) {
            s16x8 bm_[2];
#pragma unroll
            for (int n = 0; n < 2; n++) {
                int i = iq * 32 + n * 16 + l15;
                bm_[n] = *(const s16x8*)(Mb + i * 128 + ((cj ^ (i & 7)) << 3));
            }
#pragma unroll
            for (int m = 0; m < 2; m++)
#pragma unroll
                for (int n = 0; n < 2; n++)
                    acc_y[m][n] = MFMA_BF16(axh[m], bm_[n], acc_y[m][n]);
        }
    }

    float Dh = Dp[hh];
#pragma unroll
    for (int m = 0; m < 2; m++) {
        int p0 = ph * 32 + m * 16 + lq * 4;
#pragma unroll
        for (int n = 0; n < 2; n++) {
            int i = iq * 32 + n * 16 + l15;
            f32x4 v = acc_y[m][n];
#pragma unroll
            for (int r = 0; r < 4; r++) {
                int p = p0 + r;
                v[r] += Dh * bf2f(xhT[p * 136 + ((((p & 7) ^ (i >> 3)) << 3) | (i & 7))]);
            }
            *(f32x4*)&y[(size_t)(bc * CHK + i) * DI + hh * HD + p0] = v;
        }
#pragma unroll
        for (int r = 0; r < 4; r++)
            S[(size_t)bch * 4096 + (size_t)(p0 + r) * 64 + nn] = acc_st[m][r];
    }
}

// ---------------- sequential scan over chunks ----------------
__global__ void scan_kernel(const float* __restrict__ S, const float* __restrict__ decbuf,
                            float* __restrict__ hs) {
    int g = blockIdx.x * 256 + threadIdx.x;
    int n = g & 63, p = (g >> 6) & 63, hh = (g >> 12) & 15, b = g >> 16;
    float state = 0.0f;
#pragma unroll
    for (int c = 0; c < NCH; c++) {
        int bch = (b * NCH + c) * NH + hh;
        size_t idx = (size_t)bch * 4096 + p * 64 + n;
        hs[idx] = state;
        state = state * decbuf[bch] + S[idx];
    }
}

// ---------------- F2: y += exp(ac_i) * (C @ hs^T)  via MFMA, transposed output ------
__global__ __launch_bounds__(256) void ssd2_kernel(
    const ushort* __restrict__ xc, const float* __restrict__ hsg,
    const float* __restrict__ acg, float* __restrict__ y)
{
    __shared__ ushort Cs[128 * 64];
    __shared__ ushort Hs[64 * 64];
    __shared__ float sAc[128];
    int hh = blockIdx.x, bc = blockIdx.y;
    int tid = threadIdx.x, lane = tid & 63, wid = tid >> 6;
    int wr = wid >> 1, wc = wid & 1, l15 = lane & 15, lq = lane >> 4;
    int bch = bc * NH + hh;
    const size_t xbase = (size_t)(bc * CHK) * CONVD;
#pragma unroll
    for (int t = 0; t < 4; t++) {
        int cbase = t * 256 + wid * 64;
        int chunk = cbase + lane;
        int row = chunk >> 3, s = chunk & 7;
        int kc = s ^ (row & 7);
        GLOAD_LDS16(xc + xbase + (size_t)row * CONVD + DI + DSTATE + kc * 8, Cs + (size_t)cbase * 8);
    }
#pragma unroll
    for (int t = 0; t < 2; t++) {
        int chunk = t * 256 + tid;
        int p = chunk >> 3, s = chunk & 7;
        int kc = s ^ (p & 7);
        const float* src = hsg + (size_t)bch * 4096 + p * 64 + kc * 8;
        ushort* dst = Hs + p * 64 + s * 8;
#pragma unroll
        for (int e = 0; e < 8; e++) dst[e] = f2bf(src[e]);
    }
    if (tid < 128) sAc[tid] = acg[(size_t)bch * CHK + tid];
    __syncthreads();
    f32x4 acc[2][4] = {};
#pragma unroll
    for (int kh = 0; kh < 2; kh++) {
        s16x8 av[2], bv[4];
#pragma unroll
        for (int m = 0; m < 2; m++) {
            int p = wr * 32 + m * 16 + l15;
            int sl = (kh * 4 + lq) ^ (p & 7);
            av[m] = *(const s16x8*)(Hs + p * 64 + sl * 8);
        }
#pragma unroll
        for (int n = 0; n < 4; n++) {
            int i = wc * 64 + n * 16 + l15;
            int sl = (kh * 4 + lq) ^ (i & 7);
            bv[n] = *(const s16x8*)(Cs + i * 64 + sl * 8);
        }
#pragma unroll
        for (int m = 0; m < 2; m++)
#pragma unroll
            for (int n = 0; n < 4; n++)
                acc[m][n] = MFMA_BF16(av[m], bv[n], acc[m][n]);
    }
#pragma unroll
    for (int m = 0; m < 2; m++) {
        int p0 = wr * 32 + m * 16 + lq * 4;
#pragma unroll
        for (int n = 0; n < 4; n++) {
            int i = wc * 64 + n * 16 + l15;
            float e = __expf(sAc[i]);
            float* dst = &y[(size_t)(bc * CHK + i) * DI + hh * HD + p0];
            f32x4 v = *(f32x4*)dst;
#pragma unroll
            for (int r = 0; r < 4; r++) v[r] += e * acc[m][n][r];
            *(f32x4*)dst = v;
        }
    }
}

extern "C" void kernel_launch(void* const* d_in, const int* in_sizes, int n_in,
                              void* d_out, int out_size, void* d_ws, size_t ws_size,
                              hipStream_t stream) {
    const float* x        = (const float*)d_in[0];
    const float* W_embed  = (const float*)d_in[1];
    const float* rms_w    = (const float*)d_in[2];
    const float* in_w     = (const float*)d_in[3];
    const float* conv_w   = (const float*)d_in[4];
    const float* conv_b   = (const float*)d_in[5];
    const float* dt_bias  = (const float*)d_in[6];
    const float* A_log    = (const float*)d_in[7];
    const float* D_param  = (const float*)d_in[8];
    const float* gnorm_w  = (const float*)d_in[9];
    const float* out_w    = (const float*)d_in[10];
    const float* fnorm_w  = (const float*)d_in[11];
    const float* head_w   = (const float*)d_in[12];
    const float* head_b   = (const float*)d_in[13];
    float* out = (float*)d_out;

    char* p = (char*)d_ws;
    auto alloc = [&](size_t bytes) { char* r = p; p += (bytes + 255) & ~(size_t)255; return r; };

    float*  h_buf   = (float*)alloc((size_t)BL * DM * 4);
    float*  y_buf   = (float*)alloc((size_t)BL * DI * 4);
    float*  S_buf   = (float*)alloc((size_t)BSZ * NCH * NH * HD * DSTATE * 4);
    float*  hs_buf  = (float*)alloc((size_t)BSZ * NCH * NH * HD * DSTATE * 4);
    float*  ac_buf  = (float*)alloc((size_t)BSZ * NCH * NH * CHK * 4);
    float*  dec_buf = (float*)alloc((size_t)BSZ * NCH * NH * 4);
    float*  dtraw   = (float*)alloc((size_t)BL * 16 * 4);
    ushort* xn_bf   = (ushort*)alloc((size_t)BL * DM * 2);
    ushort* zx_bf   = (ushort*)alloc((size_t)BL * DIP * 2);
    ushort* xc_bf   = (ushort*)alloc((size_t)BL * CONVD * 2);
    ushort* y_bf    = (ushort*)alloc((size_t)BL * DI * 2);
    ushort* headT   = (ushort*)alloc((size_t)128 * DM * 2);

    size_t in_full  = (size_t)NLAYER * NPAD_IN * DM * 2;
    size_t out_full = (size_t)NLAYER * DM * DI * 2;
    size_t used = (size_t)(p - (char*)d_ws);
    bool full = (used + in_full + out_full + 4096) <= ws_size;
    ushort* inT  = (ushort*)alloc(full ? in_full  : (size_t)NPAD_IN * DM * 2);
    ushort* outT = (ushort*)alloc(full ? out_full : (size_t)DM * DI * 2);

    embed_kernel<<<BL, 256, 0, stream>>>(x, W_embed, h_buf);
    convT_kernel<<<dim3(2, DM / 64, 1), 256, 0, stream>>>(head_w, headT, DM, 30, 128);
    if (full) {
        convT_kernel<<<dim3(NPAD_IN / 64, DM / 64, NLAYER), 256, 0, stream>>>(
            in_w, inT, DM, DIP, NPAD_IN);
        convT_kernel<<<dim3(DM / 64, DI / 64, NLAYER), 256, 0, stream>>>(
            out_w, outT, DI, DM, DM);
    }

    for (int l = 0; l < NLAYER; l++) {
        const float* rw = rms_w + (size_t)l * DM;
        const float* cw = conv_w + (size_t)l * CONVD * 4;
        const float* cb = conv_b + (size_t)l * CONVD;
        const float* db = dt_bias + (size_t)l * NH;
        const float* al = A_log + (size_t)l * NH;
        const float* dp = D_param + (size_t)l * NH;
        const float* gw = gnorm_w + (size_t)l * DI;

        ushort* inT_l  = full ? inT  + (size_t)l * NPAD_IN * DM : inT;
        ushort* outT_l = full ? outT + (size_t)l * DM * DI      : outT;
        if (!full) {
            convT_kernel<<<dim3(NPAD_IN / 64, DM / 64, 1), 256, 0, stream>>>(
                in_w + (size_t)l * DM * DIP, inT_l, DM, DIP, NPAD_IN);
            convT_kernel<<<dim3(DM / 64, DI / 64, 1), 256, 0, stream>>>(
                out_w + (size_t)l * DI * DM, outT_l, DI, DM, DM);
        }

        rmsnorm512_bf_kernel<<<BL, 256, 0, stream>>>(h_buf, rw, xn_bf);
        gemm_bf16_kernel<0, 2><<<dim3(NPAD_IN / 128, BL / 64), 256, 0, stream>>>(
            xn_bf, inT_l, zx_bf, nullptr, dtraw, DIP, DIP, DM);
        conv_kernel<<<((BL / 4) * (CONVD / 8)) / 256, 256, 0, stream>>>(zx_bf, cw, cb, xc_bf);
        ssd1_kernel<<<dim3(NH, BSZ * NCH), 512, 0, stream>>>(xc_bf, dtraw, db, al, dp,
                                                             ac_buf, dec_buf, y_buf, S_buf);
        scan_kernel<<<(BSZ * NH * HD * DSTATE) / 256, 256, 0, stream>>>(S_buf, dec_buf,
                                                                        hs_buf);
        ssd2_kernel<<<dim3(NH, BSZ * NCH), 256, 0, stream>>>(xc_bf, hs_buf, ac_buf, y_buf);
        gatenorm_kernel<<<BL, 256, 0, stream>>>(y_buf, zx_bf, gw, y_bf);
        gemm_bf16_kernel<1, 1><<<dim3(DM / 128, BL / 32), 256, 0, stream>>>(
            y_bf, outT_l, nullptr, h_buf, nullptr, DM, DM, DI);
    }

    rmsnorm512_bf_kernel<<<BL, 256, 0, stream>>>(h_buf, fnorm_w, xn_bf);
    gemm_bf16_kernel<2, 4><<<dim3(1, BL / 128), 256, 0, stream>>>(
        xn_bf, headT, nullptr, out, (float*)head_b, 30, 30, DM);
}